// Round 1
// baseline (7768.731 us; speedup 1.0000x reference)
//
#include <hip/hip_runtime.h>
#include <math.h>

// ---------------------------------------------------------------------------
// GATv2 3-layer GNN, f32 correctness-first baseline.
// Segment ops via device-scope atomics (float max trick + atomicAdd).
// ---------------------------------------------------------------------------

__device__ __forceinline__ float lrelu(float x) { return x > 0.f ? x : 0.2f * x; }

// float atomic max: positive values via int max, negative via uint min.
__device__ __forceinline__ void atomicMaxF(float* addr, float v) {
    if (v >= 0.f) atomicMax((int*)addr, __float_as_int(v));
    else          atomicMin((unsigned int*)addr, __float_as_uint(v));
}

__global__ void fill_kernel(float* __restrict__ p, float v, int n) {
    int t = blockIdx.x * blockDim.x + threadIdx.x;
    if (t < n) p[t] = v;
}

// out[n,m] = maybe_relu(bias[m] + sum_k X[n,k] * W[k,m]);  blockDim.x == M
__global__ void gemm_row(const float* __restrict__ X, const float* __restrict__ W,
                         const float* __restrict__ bias, float* __restrict__ out,
                         int K, int M, int do_relu) {
    int n = blockIdx.x;
    int m = threadIdx.x;
    const float* xr = X + (size_t)n * K;
    float acc = bias ? bias[m] : 0.f;
#pragma unroll 8
    for (int k = 0; k < K; ++k) acc = fmaf(xr[k], W[(size_t)k * M + m], acc);
    if (do_relu) acc = fmaxf(acc, 0.f);
    out[(size_t)n * M + m] = acc;
}

// ---- 4-head, C=64 attention (layers 0 and 1): one wave per edge ----
__global__ void edge_logits4(const int* __restrict__ ei, int E, int N,
                             const float* __restrict__ XL, const float* __restrict__ XR,
                             const float* __restrict__ att,   // [4*64]
                             float* __restrict__ elog, float* __restrict__ Mmax) {
    int e = blockIdx.x * (blockDim.x >> 6) + (threadIdx.x >> 6);
    int lane = threadIdx.x & 63;
    int Et = E + N;
    if (e >= Et) return;
    int s, d;
    if (e < E) { s = ei[e]; d = ei[E + e]; } else { s = e - E; d = s; }
    float4 a = ((const float4*)(XL + (size_t)s * 256))[lane];
    float4 b = ((const float4*)(XR + (size_t)d * 256))[lane];
    float4 w = ((const float4*)att)[lane];
    float p = lrelu(a.x + b.x) * w.x + lrelu(a.y + b.y) * w.y
            + lrelu(a.z + b.z) * w.z + lrelu(a.w + b.w) * w.w;
    // reduce within each 16-lane head group
    p += __shfl_xor(p, 1, 64);
    p += __shfl_xor(p, 2, 64);
    p += __shfl_xor(p, 4, 64);
    p += __shfl_xor(p, 8, 64);
    int h = lane >> 4;
    if ((lane & 15) == 0) {
        elog[(size_t)e * 4 + h] = p;
        atomicMaxF(&Mmax[(size_t)d * 4 + h], p);
    }
}

__global__ void edge_exp4(const int* __restrict__ ei, int E, int N,
                          const float* __restrict__ Mmax,
                          float* __restrict__ elog, float* __restrict__ den) {
    int t = blockIdx.x * blockDim.x + threadIdx.x;
    int Et = E + N;
    if (t >= Et * 4) return;
    int e = t >> 2, h = t & 3;
    int d = (e < E) ? ei[E + e] : e - E;
    float ex = expf(elog[t] - Mmax[(size_t)d * 4 + h]);
    elog[t] = ex;
    atomicAdd(&den[(size_t)d * 4 + h], ex);
}

__global__ void edge_agg4(const int* __restrict__ ei, int E, int N,
                          const float* __restrict__ XL,
                          const float* __restrict__ elog, const float* __restrict__ den,
                          float* __restrict__ out) {
    int e = blockIdx.x * (blockDim.x >> 6) + (threadIdx.x >> 6);
    int lane = threadIdx.x & 63;
    int Et = E + N;
    if (e >= Et) return;
    int s, d;
    if (e < E) { s = ei[e]; d = ei[E + e]; } else { s = e - E; d = s; }
    int h = lane >> 4;
    float alpha = elog[(size_t)e * 4 + h] / den[(size_t)d * 4 + h];
    float4 x = ((const float4*)(XL + (size_t)s * 256))[lane];
    float* o = out + (size_t)d * 256 + lane * 4;
    atomicAdd(o + 0, alpha * x.x);
    atomicAdd(o + 1, alpha * x.y);
    atomicAdd(o + 2, alpha * x.z);
    atomicAdd(o + 3, alpha * x.w);
}

// h[t] = relu(bn(h[t] + bias)) (+ resid)
__global__ void post_bn_relu(float* __restrict__ h, const float* __restrict__ bias,
                             const float* __restrict__ gamma, const float* __restrict__ beta,
                             const float* __restrict__ mean, const float* __restrict__ var,
                             const float* __restrict__ resid, int total) {
    int t = blockIdx.x * blockDim.x + threadIdx.x;
    if (t >= total) return;
    int j = t & 255;
    float v = h[t] + bias[j];
    v = gamma[j] * (v - mean[j]) * rsqrtf(var[j] + 1e-5f) + beta[j];
    v = fmaxf(v, 0.f);
    if (resid) v += resid[t];
    h[t] = v;
}

// ---- layer 2: 1 head, C=2 ----
__global__ void gemm2(const float* __restrict__ X, const float* __restrict__ Wl,
                      const float* __restrict__ Wr, float* __restrict__ xl2,
                      float* __restrict__ xr2, int N) {
    int t = blockIdx.x * blockDim.x + threadIdx.x;
    if (t >= N * 4) return;
    int n = t >> 2, q = t & 3;
    const float* W = (q < 2) ? Wl : Wr;
    int col = q & 1;
    const float* x = X + (size_t)n * 256;
    float acc = 0.f;
#pragma unroll 8
    for (int k = 0; k < 256; ++k) acc = fmaf(x[k], W[k * 2 + col], acc);
    float* o = (q < 2) ? xl2 : xr2;
    o[n * 2 + col] = acc;
}

__global__ void edge_logits1(const int* __restrict__ ei, int E, int N,
                             const float* __restrict__ xl2, const float* __restrict__ xr2,
                             const float* __restrict__ att,
                             float* __restrict__ elog, float* __restrict__ Mmax) {
    int e = blockIdx.x * blockDim.x + threadIdx.x;
    int Et = E + N;
    if (e >= Et) return;
    int s, d;
    if (e < E) { s = ei[e]; d = ei[E + e]; } else { s = e - E; d = s; }
    float p = lrelu(xl2[s * 2]     + xr2[d * 2])     * att[0]
            + lrelu(xl2[s * 2 + 1] + xr2[d * 2 + 1]) * att[1];
    elog[e] = p;
    atomicMaxF(&Mmax[d], p);
}

__global__ void edge_exp1(const int* __restrict__ ei, int E, int N,
                          const float* __restrict__ Mmax,
                          float* __restrict__ elog, float* __restrict__ den) {
    int e = blockIdx.x * blockDim.x + threadIdx.x;
    int Et = E + N;
    if (e >= Et) return;
    int d = (e < E) ? ei[E + e] : e - E;
    float ex = expf(elog[e] - Mmax[d]);
    elog[e] = ex;
    atomicAdd(&den[d], ex);
}

__global__ void edge_agg1(const int* __restrict__ ei, int E, int N,
                          const float* __restrict__ xl2,
                          const float* __restrict__ elog, const float* __restrict__ den,
                          float* __restrict__ out) {
    int e = blockIdx.x * blockDim.x + threadIdx.x;
    int Et = E + N;
    if (e >= Et) return;
    int s, d;
    if (e < E) { s = ei[e]; d = ei[E + e]; } else { s = e - E; d = s; }
    float alpha = elog[e] / den[d];
    atomicAdd(&out[d * 2],     alpha * xl2[s * 2]);
    atomicAdd(&out[d * 2 + 1], alpha * xl2[s * 2 + 1]);
}

__global__ void final_logsoftmax(const float* __restrict__ agg, const float* __restrict__ bias,
                                 float* __restrict__ out, int N) {
    int n = blockIdx.x * blockDim.x + threadIdx.x;
    if (n >= N) return;
    float a = agg[n * 2]     + bias[0];
    float b = agg[n * 2 + 1] + bias[1];
    float m = fmaxf(a, b);
    float lse = m + logf(expf(a - m) + expf(b - m));
    out[n * 2]     = a - lse;
    out[n * 2 + 1] = b - lse;
}

extern "C" void kernel_launch(void* const* d_in, const int* in_sizes, int n_in,
                              void* d_out, int out_size, void* d_ws, size_t ws_size,
                              hipStream_t stream) {
    const float* x       = (const float*)d_in[0];
    const int*   ei      = (const int*)  d_in[1];
    const float* W_in    = (const float*)d_in[2];
    const float* b_in    = (const float*)d_in[3];
    const float* Wl0     = (const float*)d_in[4];
    const float* Wr0     = (const float*)d_in[5];
    const float* att0    = (const float*)d_in[6];
    const float* bias0   = (const float*)d_in[7];
    const float* Wl1     = (const float*)d_in[8];
    const float* Wr1     = (const float*)d_in[9];
    const float* att1    = (const float*)d_in[10];
    const float* bias1   = (const float*)d_in[11];
    const float* Wl2     = (const float*)d_in[12];
    const float* Wr2     = (const float*)d_in[13];
    const float* att2    = (const float*)d_in[14];
    const float* bias2   = (const float*)d_in[15];
    const float* bn_gamma= (const float*)d_in[16];
    const float* bn_beta = (const float*)d_in[17];
    const float* bn_mean = (const float*)d_in[18];
    const float* bn_var  = (const float*)d_in[19];

    const int N  = in_sizes[0] / 128;
    const int E  = in_sizes[1] / 2;
    const int Et = E + N;
    const int NC = N * 256;

    float* ws = (float*)d_ws;
    size_t off = 0;
    float* A    = ws + off; off += (size_t)N * 256;   // xl
    float* B    = ws + off; off += (size_t)N * 256;   // xr
    float* C    = ws + off; off += (size_t)N * 256;   // layer0 out / residual
    float* D    = ws + off; off += (size_t)N * 256;   // layer1 agg target (H0 aliases head)
    float* EBUF = ws + off; off += (size_t)Et * 4;    // edge logits -> exp
    float* M    = ws + off; off += (size_t)N * 4;
    float* DEN  = ws + off; off += (size_t)N * 4;
    float* XL2  = ws + off; off += (size_t)N * 2;
    float* XR2  = ws + off; off += (size_t)N * 2;
    float* AGG2 = ws + off; off += (size_t)N * 2;
    float* H0   = D;  // N*64; D not needed until layer-1 aggregation

    // h0 = relu(x @ W_in + b_in)
    gemm_row<<<N, 64, 0, stream>>>(x, W_in, b_in, H0, 128, 64, 1);

    // -------- layer 0 --------
    gemm_row<<<N, 256, 0, stream>>>(H0, Wl0, nullptr, A, 64, 256, 0);
    gemm_row<<<N, 256, 0, stream>>>(H0, Wr0, nullptr, B, 64, 256, 0);
    fill_kernel<<<(N * 4 + 255) / 256, 256, 0, stream>>>(M, -INFINITY, N * 4);
    fill_kernel<<<(N * 4 + 255) / 256, 256, 0, stream>>>(DEN, 0.f, N * 4);
    fill_kernel<<<(NC + 255) / 256, 256, 0, stream>>>(C, 0.f, NC);
    edge_logits4<<<(Et + 3) / 4, 256, 0, stream>>>(ei, E, N, A, B, att0, EBUF, M);
    edge_exp4<<<(Et * 4 + 255) / 256, 256, 0, stream>>>(ei, E, N, M, EBUF, DEN);
    edge_agg4<<<(Et + 3) / 4, 256, 0, stream>>>(ei, E, N, A, EBUF, DEN, C);
    post_bn_relu<<<(NC + 255) / 256, 256, 0, stream>>>(C, bias0, bn_gamma, bn_beta,
                                                       bn_mean, bn_var, nullptr, NC);

    // -------- layer 1 (residual) --------
    gemm_row<<<N, 256, 0, stream>>>(C, Wl1, nullptr, A, 256, 256, 0);
    gemm_row<<<N, 256, 0, stream>>>(C, Wr1, nullptr, B, 256, 256, 0);
    fill_kernel<<<(N * 4 + 255) / 256, 256, 0, stream>>>(M, -INFINITY, N * 4);
    fill_kernel<<<(N * 4 + 255) / 256, 256, 0, stream>>>(DEN, 0.f, N * 4);
    fill_kernel<<<(NC + 255) / 256, 256, 0, stream>>>(D, 0.f, NC);
    edge_logits4<<<(Et + 3) / 4, 256, 0, stream>>>(ei, E, N, A, B, att1, EBUF, M);
    edge_exp4<<<(Et * 4 + 255) / 256, 256, 0, stream>>>(ei, E, N, M, EBUF, DEN);
    edge_agg4<<<(Et + 3) / 4, 256, 0, stream>>>(ei, E, N, A, EBUF, DEN, D);
    post_bn_relu<<<(NC + 255) / 256, 256, 0, stream>>>(D, bias1, bn_gamma + 256, bn_beta + 256,
                                                       bn_mean + 256, bn_var + 256, C, NC);

    // -------- layer 2 (1 head, C=2) + log_softmax --------
    gemm2<<<(N * 4 + 255) / 256, 256, 0, stream>>>(D, Wl2, Wr2, XL2, XR2, N);
    fill_kernel<<<(N + 255) / 256, 256, 0, stream>>>(M, -INFINITY, N);
    fill_kernel<<<(N + 255) / 256, 256, 0, stream>>>(DEN, 0.f, N);
    fill_kernel<<<(N * 2 + 255) / 256, 256, 0, stream>>>(AGG2, 0.f, N * 2);
    edge_logits1<<<(Et + 255) / 256, 256, 0, stream>>>(ei, E, N, XL2, XR2, att2, EBUF, M);
    edge_exp1<<<(Et + 255) / 256, 256, 0, stream>>>(ei, E, N, M, EBUF, DEN);
    edge_agg1<<<(Et + 255) / 256, 256, 0, stream>>>(ei, E, N, XL2, EBUF, DEN, AGG2);
    final_logsoftmax<<<(N + 255) / 256, 256, 0, stream>>>(AGG2, bias2, (float*)d_out, N);
}

// Round 2
// 1224.652 us; speedup vs baseline: 6.3436x; 6.3436x over previous
//
#include <hip/hip_runtime.h>
#include <math.h>

// ---------------------------------------------------------------------------
// GATv2 3-layer GNN. CSR-by-dst built on-device each launch; fused
// flash-style (online-softmax) attention kernels, zero float atomics.
// ---------------------------------------------------------------------------

__device__ __forceinline__ float lrelu(float x) { return x > 0.f ? x : 0.2f * x; }

// ---------------- CSR build ----------------
__global__ void zero_int(int* __restrict__ p, int n) {
    int t = blockIdx.x * blockDim.x + threadIdx.x;
    if (t < n) p[t] = 0;
}

__global__ void hist_dst(const int* __restrict__ ei, int E, int* __restrict__ deg) {
    int e = blockIdx.x * blockDim.x + threadIdx.x;
    if (e < E) atomicAdd(&deg[ei[E + e]], 1);
}

// single-block exclusive scan of deg[N] -> rowstart, cursor
__global__ void scan_deg(const int* __restrict__ deg, int* __restrict__ rowstart,
                         int* __restrict__ cursor, int N) {
    __shared__ int sums[1024];
    int tid = threadIdx.x;
    int chunk = (N + 1023) >> 10;
    int b = tid * chunk, e = min(b + chunk, N);
    int s = 0;
    for (int i = b; i < e; ++i) s += deg[i];
    sums[tid] = s;
    __syncthreads();
    for (int off = 1; off < 1024; off <<= 1) {
        int v = (tid >= off) ? sums[tid - off] : 0;
        __syncthreads();
        sums[tid] += v;
        __syncthreads();
    }
    int run = sums[tid] - s;   // exclusive prefix
    for (int i = b; i < e; ++i) { rowstart[i] = run; cursor[i] = run; run += deg[i]; }
}

__global__ void scatter_src(const int* __restrict__ ei, int E,
                            int* __restrict__ cursor, int* __restrict__ csr_src) {
    int e = blockIdx.x * blockDim.x + threadIdx.x;
    if (e >= E) return;
    int d = ei[E + e];
    int pos = atomicAdd(&cursor[d], 1);
    csr_src[pos] = ei[e];
}

// ---------------- tiled GEMM: out[n,m] = maybe_relu(bias + X@W) ------------
// blockDim.x == M (64 or 256), 16 rows per block, dyn LDS = 16*K floats
__global__ void gemm_tiled(const float* __restrict__ X, const float* __restrict__ W,
                           const float* __restrict__ bias, float* __restrict__ out,
                           int N, int K, int M, int do_relu) {
    extern __shared__ float xs[];
    int m = threadIdx.x;
    int row0 = blockIdx.x * 16;
    for (int idx = m; idx < 16 * K; idx += M) {
        int r = idx / K, k = idx - r * K;
        int rr = row0 + r;
        xs[idx] = (rr < N) ? X[(size_t)rr * K + k] : 0.f;
    }
    __syncthreads();
    float acc[16];
    float bv = bias ? bias[m] : 0.f;
#pragma unroll
    for (int r = 0; r < 16; ++r) acc[r] = bv;
    for (int k = 0; k < K; k += 4) {
        float w0 = W[(size_t)(k + 0) * M + m];
        float w1 = W[(size_t)(k + 1) * M + m];
        float w2 = W[(size_t)(k + 2) * M + m];
        float w3 = W[(size_t)(k + 3) * M + m];
#pragma unroll
        for (int r = 0; r < 16; ++r) {
            float4 xv = *(const float4*)&xs[r * K + k];
            acc[r] = fmaf(xv.x, w0, fmaf(xv.y, w1, fmaf(xv.z, w2, fmaf(xv.w, w3, acc[r]))));
        }
    }
#pragma unroll
    for (int r = 0; r < 16; ++r) {
        if (row0 + r < N) {
            float v = acc[r];
            if (do_relu) v = fmaxf(v, 0.f);
            out[(size_t)(row0 + r) * M + m] = v;
        }
    }
}

// ------------- fused 4-head attention (logits+softmax+agg), wave/dst -------
__global__ void attn4_fused(int N, const float* __restrict__ XL, const float* __restrict__ XR,
                            const float* __restrict__ att,
                            const int* __restrict__ rowstart, const int* __restrict__ deg,
                            const int* __restrict__ csr_src, float* __restrict__ out) {
    int d = blockIdx.x * (blockDim.x >> 6) + (threadIdx.x >> 6);
    int lane = threadIdx.x & 63;
    if (d >= N) return;
    const float4* XL4 = (const float4*)XL;
    float4 b = ((const float4*)(XR + (size_t)d * 256))[lane];
    float4 w = ((const float4*)att)[lane];
    // self-loop initializes the online softmax state
    float4 a = XL4[(size_t)d * 64 + lane];
    float p = lrelu(a.x + b.x) * w.x + lrelu(a.y + b.y) * w.y
            + lrelu(a.z + b.z) * w.z + lrelu(a.w + b.w) * w.w;
    p += __shfl_xor(p, 1, 64); p += __shfl_xor(p, 2, 64);
    p += __shfl_xor(p, 4, 64); p += __shfl_xor(p, 8, 64);
    float m = p, l = 1.f;
    float4 acc = a;
    int start = rowstart[d], n = deg[d];
    float4 nx = {0.f, 0.f, 0.f, 0.f};
    if (n > 0) nx = XL4[(size_t)csr_src[start] * 64 + lane];
    for (int i = 0; i < n; ++i) {
        float4 xc = nx;
        if (i + 1 < n) nx = XL4[(size_t)csr_src[start + i + 1] * 64 + lane];  // prefetch
        float q = lrelu(xc.x + b.x) * w.x + lrelu(xc.y + b.y) * w.y
                + lrelu(xc.z + b.z) * w.z + lrelu(xc.w + b.w) * w.w;
        q += __shfl_xor(q, 1, 64); q += __shfl_xor(q, 2, 64);
        q += __shfl_xor(q, 4, 64); q += __shfl_xor(q, 8, 64);
        float mn = fmaxf(m, q);
        float sc = __expf(m - mn);
        float eq = __expf(q - mn);
        l = l * sc + eq;
        acc.x = acc.x * sc + eq * xc.x;
        acc.y = acc.y * sc + eq * xc.y;
        acc.z = acc.z * sc + eq * xc.z;
        acc.w = acc.w * sc + eq * xc.w;
        m = mn;
    }
    float inv = 1.f / l;
    float4 o = { acc.x * inv, acc.y * inv, acc.z * inv, acc.w * inv };
    ((float4*)(out + (size_t)d * 256))[lane] = o;
}

// h[t] = relu(bn(h[t]+bias)) (+resid)
__global__ void post_bn_relu(float* __restrict__ h, const float* __restrict__ bias,
                             const float* __restrict__ gamma, const float* __restrict__ beta,
                             const float* __restrict__ mean, const float* __restrict__ var,
                             const float* __restrict__ resid, int total) {
    int t = blockIdx.x * blockDim.x + threadIdx.x;
    if (t >= total) return;
    int j = t & 255;
    float v = h[t] + bias[j];
    v = gamma[j] * (v - mean[j]) * rsqrtf(var[j] + 1e-5f) + beta[j];
    v = fmaxf(v, 0.f);
    if (resid) v += resid[t];
    h[t] = v;
}

// ---- layer 2 projections: xl2/xr2 [N,2] ----
__global__ void gemm2(const float* __restrict__ X, const float* __restrict__ Wl,
                      const float* __restrict__ Wr, float* __restrict__ xl2,
                      float* __restrict__ xr2, int N) {
    int t = blockIdx.x * blockDim.x + threadIdx.x;
    if (t >= N * 4) return;
    int n = t >> 2, q = t & 3;
    const float* W = (q < 2) ? Wl : Wr;
    int col = q & 1;
    const float* x = X + (size_t)n * 256;
    float acc = 0.f;
#pragma unroll 8
    for (int k = 0; k < 256; ++k) acc = fmaf(x[k], W[k * 2 + col], acc);
    float* o = (q < 2) ? xl2 : xr2;
    o[n * 2 + col] = acc;
}

// ---- fused layer-2 attention (1 head, C=2) + log_softmax, thread/dst ----
__global__ void attn1_fused(int N, const float* __restrict__ xl2, const float* __restrict__ xr2,
                            const float* __restrict__ att, const float* __restrict__ bias,
                            const int* __restrict__ rowstart, const int* __restrict__ deg,
                            const int* __restrict__ csr_src, float* __restrict__ out) {
    int d = blockIdx.x * blockDim.x + threadIdx.x;
    if (d >= N) return;
    float a0 = att[0], a1 = att[1];
    float b0 = xr2[d * 2], b1 = xr2[d * 2 + 1];
    float s0 = xl2[d * 2], s1 = xl2[d * 2 + 1];
    float p = lrelu(s0 + b0) * a0 + lrelu(s1 + b1) * a1;
    float m = p, l = 1.f, ac0 = s0, ac1 = s1;
    int st = rowstart[d], n = deg[d];
    for (int i = 0; i < n; ++i) {
        int s = csr_src[st + i];
        float x0 = xl2[s * 2], x1 = xl2[s * 2 + 1];
        float q = lrelu(x0 + b0) * a0 + lrelu(x1 + b1) * a1;
        float mn = fmaxf(m, q);
        float sc = __expf(m - mn), eq = __expf(q - mn);
        l = l * sc + eq;
        ac0 = ac0 * sc + eq * x0;
        ac1 = ac1 * sc + eq * x1;
        m = mn;
    }
    float inv = 1.f / l;
    float v0 = ac0 * inv + bias[0];
    float v1 = ac1 * inv + bias[1];
    float mx = fmaxf(v0, v1);
    float lse = mx + logf(__expf(v0 - mx) + __expf(v1 - mx));
    out[d * 2] = v0 - lse;
    out[d * 2 + 1] = v1 - lse;
}

extern "C" void kernel_launch(void* const* d_in, const int* in_sizes, int n_in,
                              void* d_out, int out_size, void* d_ws, size_t ws_size,
                              hipStream_t stream) {
    const float* x        = (const float*)d_in[0];
    const int*   ei       = (const int*)  d_in[1];
    const float* W_in     = (const float*)d_in[2];
    const float* b_in     = (const float*)d_in[3];
    const float* Wl0      = (const float*)d_in[4];
    const float* Wr0      = (const float*)d_in[5];
    const float* att0     = (const float*)d_in[6];
    const float* bias0    = (const float*)d_in[7];
    const float* Wl1      = (const float*)d_in[8];
    const float* Wr1      = (const float*)d_in[9];
    const float* att1     = (const float*)d_in[10];
    const float* bias1    = (const float*)d_in[11];
    const float* Wl2      = (const float*)d_in[12];
    const float* Wr2      = (const float*)d_in[13];
    const float* att2     = (const float*)d_in[14];
    const float* bias2    = (const float*)d_in[15];
    const float* bn_gamma = (const float*)d_in[16];
    const float* bn_beta  = (const float*)d_in[17];
    const float* bn_mean  = (const float*)d_in[18];
    const float* bn_var   = (const float*)d_in[19];

    const int N  = in_sizes[0] / 128;
    const int E  = in_sizes[1] / 2;
    const int NC = N * 256;

    float* ws = (float*)d_ws;
    size_t off = 0;
    float* A    = ws + off; off += (size_t)N * 256;   // xl
    float* B    = ws + off; off += (size_t)N * 256;   // xr
    float* C    = ws + off; off += (size_t)N * 256;   // layer0 out / residual
    float* D    = ws + off; off += (size_t)N * 256;   // layer1 out (head aliases H0)
    float* XL2  = ws + off; off += (size_t)N * 2;
    float* XR2  = ws + off; off += (size_t)N * 2;
    int* ip = (int*)(ws + off);
    int* deg      = ip;              ip += N;
    int* rowstart = ip;              ip += N;
    int* cursor   = ip;              ip += N;
    int* csr_src  = ip;              ip += E;
    float* H0 = D;  // N*64 scratch; D not written until layer-1 attention

    // ---- CSR build (every launch: ws is re-poisoned) ----
    zero_int<<<(N + 255) / 256, 256, 0, stream>>>(deg, N);
    hist_dst<<<(E + 255) / 256, 256, 0, stream>>>(ei, E, deg);
    scan_deg<<<1, 1024, 0, stream>>>(deg, rowstart, cursor, N);
    scatter_src<<<(E + 255) / 256, 256, 0, stream>>>(ei, E, cursor, csr_src);

    const int GB = (N + 15) / 16;

    // h0 = relu(x @ W_in + b_in)
    gemm_tiled<<<GB, 64, 16 * 128 * 4, stream>>>(x, W_in, b_in, H0, N, 128, 64, 1);

    // -------- layer 0 --------
    gemm_tiled<<<GB, 256, 16 * 64 * 4, stream>>>(H0, Wl0, nullptr, A, N, 64, 256, 0);
    gemm_tiled<<<GB, 256, 16 * 64 * 4, stream>>>(H0, Wr0, nullptr, B, N, 64, 256, 0);
    attn4_fused<<<(N + 3) / 4, 256, 0, stream>>>(N, A, B, att0, rowstart, deg, csr_src, C);
    post_bn_relu<<<(NC + 255) / 256, 256, 0, stream>>>(C, bias0, bn_gamma, bn_beta,
                                                       bn_mean, bn_var, nullptr, NC);

    // -------- layer 1 (residual) --------
    gemm_tiled<<<GB, 256, 16 * 256 * 4, stream>>>(C, Wl1, nullptr, A, N, 256, 256, 0);
    gemm_tiled<<<GB, 256, 16 * 256 * 4, stream>>>(C, Wr1, nullptr, B, N, 256, 256, 0);
    attn4_fused<<<(N + 3) / 4, 256, 0, stream>>>(N, A, B, att1, rowstart, deg, csr_src, D);
    post_bn_relu<<<(NC + 255) / 256, 256, 0, stream>>>(D, bias1, bn_gamma + 256, bn_beta + 256,
                                                       bn_mean + 256, bn_var + 256, C, NC);

    // -------- layer 2 (1 head, C=2) + log_softmax --------
    gemm2<<<(N * 4 + 255) / 256, 256, 0, stream>>>(D, Wl2, Wr2, XL2, XR2, N);
    attn1_fused<<<(N + 255) / 256, 256, 0, stream>>>(N, XL2, XR2, att2, bias2,
                                                     rowstart, deg, csr_src, (float*)d_out);
}

// Round 4
// 975.300 us; speedup vs baseline: 7.9655x; 1.2557x over previous
//
#include <hip/hip_runtime.h>
#include <math.h>

// ---------------------------------------------------------------------------
// GATv2 3-layer GNN. CSR-by-dst built on-device; fused online-softmax
// attention; register-blocked f32 GEMMs (16 rows x NT*64 cols per wave).
// ---------------------------------------------------------------------------

__device__ __forceinline__ float lrelu(float x) { return x > 0.f ? x : 0.2f * x; }

// ---------------- CSR build ----------------
__global__ void zero_int(int* __restrict__ p, int n) {
    int t = blockIdx.x * blockDim.x + threadIdx.x;
    if (t < n) p[t] = 0;
}

__global__ void hist_dst(const int* __restrict__ ei, int E, int* __restrict__ deg) {
    int e = blockIdx.x * blockDim.x + threadIdx.x;
    if (e < E) atomicAdd(&deg[ei[E + e]], 1);
}

// single-block exclusive scan of deg[N] -> rowstart, cursor
__global__ void scan_deg(const int* __restrict__ deg, int* __restrict__ rowstart,
                         int* __restrict__ cursor, int N) {
    __shared__ int sums[1024];
    int tid = threadIdx.x;
    int chunk = (N + 1023) >> 10;
    int b = tid * chunk, e = min(b + chunk, N);
    int s = 0;
    for (int i = b; i < e; ++i) s += deg[i];
    sums[tid] = s;
    __syncthreads();
    for (int off = 1; off < 1024; off <<= 1) {
        int v = (tid >= off) ? sums[tid - off] : 0;
        __syncthreads();
        sums[tid] += v;
        __syncthreads();
    }
    int run = sums[tid] - s;   // exclusive prefix
    for (int i = b; i < e; ++i) { rowstart[i] = run; cursor[i] = run; run += deg[i]; }
}

__global__ void scatter_src(const int* __restrict__ ei, int E,
                            int* __restrict__ cursor, int* __restrict__ csr_src) {
    int e = blockIdx.x * blockDim.x + threadIdx.x;
    if (e >= E) return;
    int d = ei[E + e];
    int pos = atomicAdd(&cursor[d], 1);
    csr_src[pos] = ei[e];
}

// --------- register-blocked GEMM: 1 wave/block, 16 rows x NT*64 cols -------
// out[n,m] = maybe_relu(bias[m] + sum_k X[n,k]*W[k,m]); K multiple of 64.
template<int NT>
__global__ __launch_bounds__(64) void gemm_rb(const float* __restrict__ X,
        const float* __restrict__ W, const float* __restrict__ bias,
        float* __restrict__ out, int N, int K, int do_relu) {
    constexpr int M = NT * 64;
    __shared__ float xs[16 * 64];
    const int lane = threadIdx.x;
    const int row0 = blockIdx.x * 16;
    float acc[16][NT];
#pragma unroll
    for (int r = 0; r < 16; ++r)
#pragma unroll
        for (int c = 0; c < NT; ++c) acc[r][c] = 0.f;

    for (int kc = 0; kc < K; kc += 64) {
        __syncthreads();
#pragma unroll
        for (int i = 0; i < 4; ++i) {
            int idx = i * 64 + lane;          // float4 slot 0..255
            int r = idx >> 4, f4 = idx & 15;
            int rr = row0 + r;
            float4 v = make_float4(0.f, 0.f, 0.f, 0.f);
            if (rr < N) v = *(const float4*)&X[(size_t)rr * K + kc + f4 * 4];
            *(float4*)&xs[r * 64 + f4 * 4] = v;
        }
        __syncthreads();
        const float* Wp = W + (size_t)kc * M + lane;
        for (int kk = 0; kk < 64; kk += 4) {
            float w[4][NT];
#pragma unroll
            for (int j = 0; j < 4; ++j)
#pragma unroll
                for (int c = 0; c < NT; ++c)
                    w[j][c] = Wp[(size_t)(kk + j) * M + c * 64];
#pragma unroll
            for (int r = 0; r < 16; ++r) {
                float4 xv = *(const float4*)&xs[r * 64 + kk];
#pragma unroll
                for (int c = 0; c < NT; ++c) {
                    acc[r][c] = fmaf(xv.x, w[0][c], acc[r][c]);
                    acc[r][c] = fmaf(xv.y, w[1][c], acc[r][c]);
                    acc[r][c] = fmaf(xv.z, w[2][c], acc[r][c]);
                    acc[r][c] = fmaf(xv.w, w[3][c], acc[r][c]);
                }
            }
        }
    }
#pragma unroll
    for (int r = 0; r < 16; ++r) {
        int rr = row0 + r;
        if (rr >= N) continue;
#pragma unroll
        for (int c = 0; c < NT; ++c) {
            float v = acc[r][c] + (bias ? bias[lane + c * 64] : 0.f);
            if (do_relu) v = fmaxf(v, 0.f);
            out[(size_t)rr * M + lane + c * 64] = v;
        }
    }
}

// ------------- fused 4-head attention (logits+softmax+agg), wave/dst -------
__global__ void attn4_fused(int N, const float* __restrict__ XL, const float* __restrict__ XR,
                            const float* __restrict__ att,
                            const int* __restrict__ rowstart, const int* __restrict__ deg,
                            const int* __restrict__ csr_src, float* __restrict__ out) {
    int d = blockIdx.x * (blockDim.x >> 6) + (threadIdx.x >> 6);
    int lane = threadIdx.x & 63;
    if (d >= N) return;
    const float4* XL4 = (const float4*)XL;
    float4 b = ((const float4*)(XR + (size_t)d * 256))[lane];
    float4 w = ((const float4*)att)[lane];
    // self-loop initializes the online softmax state
    float4 a = XL4[(size_t)d * 64 + lane];
    float p = lrelu(a.x + b.x) * w.x + lrelu(a.y + b.y) * w.y
            + lrelu(a.z + b.z) * w.z + lrelu(a.w + b.w) * w.w;
    p += __shfl_xor(p, 1, 64); p += __shfl_xor(p, 2, 64);
    p += __shfl_xor(p, 4, 64); p += __shfl_xor(p, 8, 64);
    float m = p, l = 1.f;
    float4 acc = a;
    int start = rowstart[d], n = deg[d];
    float4 nx = {0.f, 0.f, 0.f, 0.f};
    if (n > 0) nx = XL4[(size_t)csr_src[start] * 64 + lane];
    for (int i = 0; i < n; ++i) {
        float4 xc = nx;
        if (i + 1 < n) nx = XL4[(size_t)csr_src[start + i + 1] * 64 + lane];  // prefetch
        float q = lrelu(xc.x + b.x) * w.x + lrelu(xc.y + b.y) * w.y
                + lrelu(xc.z + b.z) * w.z + lrelu(xc.w + b.w) * w.w;
        q += __shfl_xor(q, 1, 64); q += __shfl_xor(q, 2, 64);
        q += __shfl_xor(q, 4, 64); q += __shfl_xor(q, 8, 64);
        float mn = fmaxf(m, q);
        float sc = __expf(m - mn);
        float eq = __expf(q - mn);
        l = l * sc + eq;
        acc.x = acc.x * sc + eq * xc.x;
        acc.y = acc.y * sc + eq * xc.y;
        acc.z = acc.z * sc + eq * xc.z;
        acc.w = acc.w * sc + eq * xc.w;
        m = mn;
    }
    float inv = 1.f / l;
    float4 o = { acc.x * inv, acc.y * inv, acc.z * inv, acc.w * inv };
    ((float4*)(out + (size_t)d * 256))[lane] = o;
}

// h[t] = relu(bn(h[t]+bias)) (+resid)
__global__ void post_bn_relu(float* __restrict__ h, const float* __restrict__ bias,
                             const float* __restrict__ gamma, const float* __restrict__ beta,
                             const float* __restrict__ mean, const float* __restrict__ var,
                             const float* __restrict__ resid, int total) {
    int t = blockIdx.x * blockDim.x + threadIdx.x;
    if (t >= total) return;
    int j = t & 255;
    float v = h[t] + bias[j];
    v = gamma[j] * (v - mean[j]) * rsqrtf(var[j] + 1e-5f) + beta[j];
    v = fmaxf(v, 0.f);
    if (resid) v += resid[t];
    h[t] = v;
}

// ---- layer 2 projections: 16 lanes per node; each lane covers 16 of K=256 ----
__global__ void gemm2_wave(const float* __restrict__ X, const float* __restrict__ Wl,
                           const float* __restrict__ Wr, float* __restrict__ xl2,
                           float* __restrict__ xr2, int N) {
    int t = blockIdx.x * blockDim.x + threadIdx.x;
    int n = t >> 4;             // node
    int sl = t & 15;            // lane within node group
    if (n >= N) return;
    const float4* Xr = (const float4*)(X + (size_t)n * 256);  // 64 float4s
    const float4* Wl4 = (const float4*)Wl;   // [256][2]: Wl4[i] = rows 2i,2i+1
    const float4* Wr4 = (const float4*)Wr;
    float l0 = 0.f, l1 = 0.f, r0 = 0.f, r1 = 0.f;
#pragma unroll
    for (int j = 0; j < 4; ++j) {
        int idx = sl + j * 16;            // float4 index 0..63 (rows 4idx..4idx+3)
        float4 xv = Xr[idx];
        float4 wa = Wl4[idx * 2];         // rows 4idx,4idx+1: (r0c0,r0c1,r1c0,r1c1)
        float4 wb = Wl4[idx * 2 + 1];     // rows 4idx+2,4idx+3
        l0 += xv.x * wa.x + xv.y * wa.z + xv.z * wb.x + xv.w * wb.z;
        l1 += xv.x * wa.y + xv.y * wa.w + xv.z * wb.y + xv.w * wb.w;
        wa = Wr4[idx * 2]; wb = Wr4[idx * 2 + 1];
        r0 += xv.x * wa.x + xv.y * wa.z + xv.z * wb.x + xv.w * wb.z;
        r1 += xv.x * wa.y + xv.y * wa.w + xv.z * wb.y + xv.w * wb.w;
    }
#pragma unroll
    for (int off = 1; off < 16; off <<= 1) {
        l0 += __shfl_xor(l0, off, 64);
        l1 += __shfl_xor(l1, off, 64);
        r0 += __shfl_xor(r0, off, 64);
        r1 += __shfl_xor(r1, off, 64);
    }
    if (sl == 0) {
        xl2[n * 2] = l0; xl2[n * 2 + 1] = l1;
        xr2[n * 2] = r0; xr2[n * 2 + 1] = r1;
    }
}

// ---- fused layer-2 attention (1 head, C=2) + log_softmax, thread/dst ----
__global__ void attn1_fused(int N, const float* __restrict__ xl2, const float* __restrict__ xr2,
                            const float* __restrict__ att, const float* __restrict__ bias,
                            const int* __restrict__ rowstart, const int* __restrict__ deg,
                            const int* __restrict__ csr_src, float* __restrict__ out) {
    int d = blockIdx.x * blockDim.x + threadIdx.x;
    if (d >= N) return;
    float a0 = att[0], a1 = att[1];
    float b0 = xr2[d * 2], b1 = xr2[d * 2 + 1];
    float s0 = xl2[d * 2], s1 = xl2[d * 2 + 1];
    float p = lrelu(s0 + b0) * a0 + lrelu(s1 + b1) * a1;
    float m = p, l = 1.f, ac0 = s0, ac1 = s1;
    int st = rowstart[d], n = deg[d];
    for (int i = 0; i < n; ++i) {
        int s = csr_src[st + i];
        float x0 = xl2[s * 2], x1 = xl2[s * 2 + 1];
        float q = lrelu(x0 + b0) * a0 + lrelu(x1 + b1) * a1;
        float mn = fmaxf(m, q);
        float sc = __expf(m - mn), eq = __expf(q - mn);
        l = l * sc + eq;
        ac0 = ac0 * sc + eq * x0;
        ac1 = ac1 * sc + eq * x1;
        m = mn;
    }
    float inv = 1.f / l;
    float v0 = ac0 * inv + bias[0];
    float v1 = ac1 * inv + bias[1];
    float mx = fmaxf(v0, v1);
    float lse = mx + logf(__expf(v0 - mx) + __expf(v1 - mx));
    out[d * 2] = v0 - lse;
    out[d * 2 + 1] = v1 - lse;
}

extern "C" void kernel_launch(void* const* d_in, const int* in_sizes, int n_in,
                              void* d_out, int out_size, void* d_ws, size_t ws_size,
                              hipStream_t stream) {
    const float* x        = (const float*)d_in[0];
    const int*   ei       = (const int*)  d_in[1];
    const float* W_in     = (const float*)d_in[2];
    const float* b_in     = (const float*)d_in[3];
    const float* Wl0      = (const float*)d_in[4];
    const float* Wr0      = (const float*)d_in[5];
    const float* att0     = (const float*)d_in[6];
    const float* bias0    = (const float*)d_in[7];
    const float* Wl1      = (const float*)d_in[8];
    const float* Wr1      = (const float*)d_in[9];
    const float* att1     = (const float*)d_in[10];
    const float* bias1    = (const float*)d_in[11];
    const float* Wl2      = (const float*)d_in[12];
    const float* Wr2      = (const float*)d_in[13];
    const float* att2     = (const float*)d_in[14];
    const float* bias2    = (const float*)d_in[15];
    const float* bn_gamma = (const float*)d_in[16];
    const float* bn_beta  = (const float*)d_in[17];
    const float* bn_mean  = (const float*)d_in[18];
    const float* bn_var   = (const float*)d_in[19];

    const int N  = in_sizes[0] / 128;
    const int E  = in_sizes[1] / 2;
    const int NC = N * 256;

    float* ws = (float*)d_ws;
    size_t off = 0;
    float* A    = ws + off; off += (size_t)N * 256;   // xl
    float* B    = ws + off; off += (size_t)N * 256;   // xr
    float* C    = ws + off; off += (size_t)N * 256;   // layer0 out / residual
    float* D    = ws + off; off += (size_t)N * 256;   // layer1 out (head aliases H0)
    float* XL2  = ws + off; off += (size_t)N * 2;
    float* XR2  = ws + off; off += (size_t)N * 2;
    int* ip = (int*)(ws + off);
    int* deg      = ip;              ip += N;
    int* rowstart = ip;              ip += N;
    int* cursor   = ip;              ip += N;
    int* csr_src  = ip;              ip += E;
    float* H0 = D;  // N*64 scratch; D not written until layer-1 attention

    // ---- CSR build (every launch: ws is re-poisoned) ----
    zero_int<<<(N + 255) / 256, 256, 0, stream>>>(deg, N);
    hist_dst<<<(E + 255) / 256, 256, 0, stream>>>(ei, E, deg);
    scan_deg<<<1, 1024, 0, stream>>>(deg, rowstart, cursor, N);
    scatter_src<<<(E + 255) / 256, 256, 0, stream>>>(ei, E, cursor, csr_src);

    const int GB = (N + 15) / 16;

    // h0 = relu(x @ W_in + b_in)
    gemm_rb<1><<<GB, 64, 0, stream>>>(x, W_in, b_in, H0, N, 128, 1);

    // -------- layer 0 --------
    gemm_rb<4><<<GB, 64, 0, stream>>>(H0, Wl0, nullptr, A, N, 64, 0);
    gemm_rb<4><<<GB, 64, 0, stream>>>(H0, Wr0, nullptr, B, N, 64, 0);
    attn4_fused<<<(N + 3) / 4, 256, 0, stream>>>(N, A, B, att0, rowstart, deg, csr_src, C);
    post_bn_relu<<<(NC + 255) / 256, 256, 0, stream>>>(C, bias0, bn_gamma, bn_beta,
                                                       bn_mean, bn_var, nullptr, NC);

    // -------- layer 1 (residual) --------
    gemm_rb<4><<<GB, 64, 0, stream>>>(C, Wl1, nullptr, A, N, 256, 0);
    gemm_rb<4><<<GB, 64, 0, stream>>>(C, Wr1, nullptr, B, N, 256, 0);
    attn4_fused<<<(N + 3) / 4, 256, 0, stream>>>(N, A, B, att1, rowstart, deg, csr_src, D);
    post_bn_relu<<<(NC + 255) / 256, 256, 0, stream>>>(D, bias1, bn_gamma + 256, bn_beta + 256,
                                                       bn_mean + 256, bn_var + 256, C, NC);

    // -------- layer 2 (1 head, C=2) + log_softmax --------
    gemm2_wave<<<(N * 16 + 255) / 256, 256, 0, stream>>>(D, Wl2, Wr2, XL2, XR2, N);
    attn1_fused<<<(N + 255) / 256, 256, 0, stream>>>(N, XL2, XR2, att2, bias2,
                                                     rowstart, deg, csr_src, (float*)d_out);
}

// Round 5
// 792.925 us; speedup vs baseline: 9.7976x; 1.2300x over previous
//
#include <hip/hip_runtime.h>
#include <hip/hip_bf16.h>
#include <math.h>

// ---------------------------------------------------------------------------
// GATv2 3-layer GNN. CSR-by-dst on-device; bf16 attention operands (halves
// the random-gather traffic); fused online-softmax attention with BN/ReLU/
// residual epilogue; register-blocked f32 GEMMs writing bf16.
// ---------------------------------------------------------------------------

__device__ __forceinline__ float lrelu(float x) { return x > 0.f ? x : 0.2f * x; }

__device__ __forceinline__ unsigned short f2bf(float f) {
    __hip_bfloat16 h = __float2bfloat16(f);   // RNE
    return *reinterpret_cast<unsigned short*>(&h);
}
__device__ __forceinline__ float4 bf4_to_f4(ushort4 u) {
    float4 r;
    r.x = __uint_as_float((unsigned int)u.x << 16);
    r.y = __uint_as_float((unsigned int)u.y << 16);
    r.z = __uint_as_float((unsigned int)u.z << 16);
    r.w = __uint_as_float((unsigned int)u.w << 16);
    return r;
}

// ---------------- CSR build ----------------
__global__ void zero_int(int* __restrict__ p, int n) {
    int t = blockIdx.x * blockDim.x + threadIdx.x;
    if (t < n) p[t] = 0;
}

__global__ void hist_dst(const int* __restrict__ ei, int E, int* __restrict__ deg) {
    int e = blockIdx.x * blockDim.x + threadIdx.x;
    if (e < E) atomicAdd(&deg[ei[E + e]], 1);
}

__global__ void scan_deg(const int* __restrict__ deg, int* __restrict__ rowstart,
                         int* __restrict__ cursor, int N) {
    __shared__ int sums[1024];
    int tid = threadIdx.x;
    int chunk = (N + 1023) >> 10;
    int b = tid * chunk, e = min(b + chunk, N);
    int s = 0;
    for (int i = b; i < e; ++i) s += deg[i];
    sums[tid] = s;
    __syncthreads();
    for (int off = 1; off < 1024; off <<= 1) {
        int v = (tid >= off) ? sums[tid - off] : 0;
        __syncthreads();
        sums[tid] += v;
        __syncthreads();
    }
    int run = sums[tid] - s;
    for (int i = b; i < e; ++i) { rowstart[i] = run; cursor[i] = run; run += deg[i]; }
}

__global__ void scatter_src(const int* __restrict__ ei, int E,
                            int* __restrict__ cursor, int* __restrict__ csr_src) {
    int e = blockIdx.x * blockDim.x + threadIdx.x;
    if (e >= E) return;
    int d = ei[E + e];
    int pos = atomicAdd(&cursor[d], 1);
    csr_src[pos] = ei[e];
}

// --------- f32 GEMM (input projection): 16 rows x 64 cols per wave ---------
__global__ __launch_bounds__(64) void gemm_rb1(const float* __restrict__ X,
        const float* __restrict__ W, const float* __restrict__ bias,
        float* __restrict__ out, int N, int K) {
    constexpr int M = 64;
    __shared__ float xs[16 * 64];
    const int lane = threadIdx.x;
    const int row0 = blockIdx.x * 16;
    float acc[16];
#pragma unroll
    for (int r = 0; r < 16; ++r) acc[r] = 0.f;
    for (int kc = 0; kc < K; kc += 64) {
        __syncthreads();
#pragma unroll
        for (int i = 0; i < 4; ++i) {
            int idx = i * 64 + lane;
            int r = idx >> 4, f4 = idx & 15;
            int rr = row0 + r;
            float4 v = make_float4(0.f, 0.f, 0.f, 0.f);
            if (rr < N) v = *(const float4*)&X[(size_t)rr * K + kc + f4 * 4];
            *(float4*)&xs[r * 64 + f4 * 4] = v;
        }
        __syncthreads();
        const float* Wp = W + (size_t)kc * M + lane;
        for (int kk = 0; kk < 64; kk += 4) {
            float w0 = Wp[(size_t)(kk + 0) * M];
            float w1 = Wp[(size_t)(kk + 1) * M];
            float w2 = Wp[(size_t)(kk + 2) * M];
            float w3 = Wp[(size_t)(kk + 3) * M];
#pragma unroll
            for (int r = 0; r < 16; ++r) {
                float4 xv = *(const float4*)&xs[r * 64 + kk];
                acc[r] = fmaf(xv.x, w0, fmaf(xv.y, w1, fmaf(xv.z, w2, fmaf(xv.w, w3, acc[r]))));
            }
        }
    }
    float bv = bias[lane];
#pragma unroll
    for (int r = 0; r < 16; ++r) {
        int rr = row0 + r;
        if (rr < N) out[(size_t)rr * M + lane] = fmaxf(acc[r] + bv, 0.f);
    }
}

// ----- dual GEMM -> bf16: computes X@W0 and X@W1, 16 rows x 128 cols/block -----
// blockIdx.y in [0, 2*M/128): y<ncs -> W0 slice, else W1 slice.
__global__ __launch_bounds__(64) void gemm_dual_bf16(const float* __restrict__ X,
        const float* __restrict__ W0, const float* __restrict__ W1,
        unsigned short* __restrict__ out0, unsigned short* __restrict__ out1,
        int N, int K, int M) {
    constexpr int NT = 2, MC = NT * 64;
    __shared__ float xs[16 * 64];
    const int lane = threadIdx.x;
    const int row0 = blockIdx.x * 16;
    const int ncs = M / MC;
    const int y = blockIdx.y;
    const float* W = (y < ncs) ? W0 : W1;
    unsigned short* out = (y < ncs) ? out0 : out1;
    const int cb = ((y < ncs) ? y : y - ncs) * MC;
    float acc[16][NT];
#pragma unroll
    for (int r = 0; r < 16; ++r)
#pragma unroll
        for (int c = 0; c < NT; ++c) acc[r][c] = 0.f;

    for (int kc = 0; kc < K; kc += 64) {
        __syncthreads();
#pragma unroll
        for (int i = 0; i < 4; ++i) {
            int idx = i * 64 + lane;
            int r = idx >> 4, f4 = idx & 15;
            int rr = row0 + r;
            float4 v = make_float4(0.f, 0.f, 0.f, 0.f);
            if (rr < N) v = *(const float4*)&X[(size_t)rr * K + kc + f4 * 4];
            *(float4*)&xs[r * 64 + f4 * 4] = v;
        }
        __syncthreads();
        const float* Wp = W + (size_t)kc * M + cb + lane;
        for (int kk = 0; kk < 64; kk += 4) {
            float w[4][NT];
#pragma unroll
            for (int j = 0; j < 4; ++j)
#pragma unroll
                for (int c = 0; c < NT; ++c)
                    w[j][c] = Wp[(size_t)(kk + j) * M + c * 64];
#pragma unroll
            for (int r = 0; r < 16; ++r) {
                float4 xv = *(const float4*)&xs[r * 64 + kk];
#pragma unroll
                for (int c = 0; c < NT; ++c) {
                    acc[r][c] = fmaf(xv.x, w[0][c], acc[r][c]);
                    acc[r][c] = fmaf(xv.y, w[1][c], acc[r][c]);
                    acc[r][c] = fmaf(xv.z, w[2][c], acc[r][c]);
                    acc[r][c] = fmaf(xv.w, w[3][c], acc[r][c]);
                }
            }
        }
    }
#pragma unroll
    for (int r = 0; r < 16; ++r) {
        int rr = row0 + r;
        if (rr >= N) continue;
#pragma unroll
        for (int c = 0; c < NT; ++c)
            out[(size_t)rr * M + cb + lane + c * 64] = f2bf(acc[r][c]);
    }
}

// ---- fused 4-head attention + BN + ReLU (+residual), wave/dst, bf16 in ----
__global__ void attn4_bn(int N, const unsigned short* __restrict__ XL,
                         const unsigned short* __restrict__ XR,
                         const float* __restrict__ att,
                         const int* __restrict__ rowstart, const int* __restrict__ deg,
                         const int* __restrict__ csr_src,
                         const float* __restrict__ gamma, const float* __restrict__ beta,
                         const float* __restrict__ mean, const float* __restrict__ var,
                         const float* __restrict__ bias, const float* __restrict__ resid,
                         float* __restrict__ out) {
    int d = blockIdx.x * (blockDim.x >> 6) + (threadIdx.x >> 6);
    int lane = threadIdx.x & 63;
    if (d >= N) return;
    float4 b = bf4_to_f4(*(const ushort4*)(XR + (size_t)d * 256 + lane * 4));
    float4 w = ((const float4*)att)[lane];
    // self-loop initializes the online softmax state
    float4 a = bf4_to_f4(*(const ushort4*)(XL + (size_t)d * 256 + lane * 4));
    float p = lrelu(a.x + b.x) * w.x + lrelu(a.y + b.y) * w.y
            + lrelu(a.z + b.z) * w.z + lrelu(a.w + b.w) * w.w;
    p += __shfl_xor(p, 1, 64); p += __shfl_xor(p, 2, 64);
    p += __shfl_xor(p, 4, 64); p += __shfl_xor(p, 8, 64);
    float m = p, l = 1.f;
    float4 acc = a;
    int start = rowstart[d], n = deg[d];
    ushort4 nx = {0, 0, 0, 0};
    if (n > 0) nx = *(const ushort4*)(XL + (size_t)csr_src[start] * 256 + lane * 4);
    for (int i = 0; i < n; ++i) {
        float4 xc = bf4_to_f4(nx);
        if (i + 1 < n) nx = *(const ushort4*)(XL + (size_t)csr_src[start + i + 1] * 256 + lane * 4);
        float q = lrelu(xc.x + b.x) * w.x + lrelu(xc.y + b.y) * w.y
                + lrelu(xc.z + b.z) * w.z + lrelu(xc.w + b.w) * w.w;
        q += __shfl_xor(q, 1, 64); q += __shfl_xor(q, 2, 64);
        q += __shfl_xor(q, 4, 64); q += __shfl_xor(q, 8, 64);
        float mn = fmaxf(m, q);
        float sc = __expf(m - mn);
        float eq = __expf(q - mn);
        l = l * sc + eq;
        acc.x = acc.x * sc + eq * xc.x;
        acc.y = acc.y * sc + eq * xc.y;
        acc.z = acc.z * sc + eq * xc.z;
        acc.w = acc.w * sc + eq * xc.w;
        m = mn;
    }
    float inv = 1.f / l;
    // BN(gamma,beta,mean,var) on (h + bias), then ReLU, then + resid
    float4 g  = ((const float4*)gamma)[lane];
    float4 be = ((const float4*)beta)[lane];
    float4 mu = ((const float4*)mean)[lane];
    float4 va = ((const float4*)var)[lane];
    float4 bi = ((const float4*)bias)[lane];
    float4 sc4, sh4;
    sc4.x = g.x * rsqrtf(va.x + 1e-5f); sh4.x = (bi.x - mu.x) * sc4.x + be.x;
    sc4.y = g.y * rsqrtf(va.y + 1e-5f); sh4.y = (bi.y - mu.y) * sc4.y + be.y;
    sc4.z = g.z * rsqrtf(va.z + 1e-5f); sh4.z = (bi.z - mu.z) * sc4.z + be.z;
    sc4.w = g.w * rsqrtf(va.w + 1e-5f); sh4.w = (bi.w - mu.w) * sc4.w + be.w;
    float4 o;
    o.x = fmaxf(acc.x * inv * sc4.x + sh4.x, 0.f);
    o.y = fmaxf(acc.y * inv * sc4.y + sh4.y, 0.f);
    o.z = fmaxf(acc.z * inv * sc4.z + sh4.z, 0.f);
    o.w = fmaxf(acc.w * inv * sc4.w + sh4.w, 0.f);
    if (resid) {
        float4 rv = *(const float4*)(resid + (size_t)d * 256 + lane * 4);
        o.x += rv.x; o.y += rv.y; o.z += rv.z; o.w += rv.w;
    }
    *(float4*)(out + (size_t)d * 256 + lane * 4) = o;
}

// ---- layer 2 projections: 16 lanes per node; each lane covers 16 of K=256 ----
__global__ void gemm2_wave(const float* __restrict__ X, const float* __restrict__ Wl,
                           const float* __restrict__ Wr, float* __restrict__ xl2,
                           float* __restrict__ xr2, int N) {
    int t = blockIdx.x * blockDim.x + threadIdx.x;
    int n = t >> 4;
    int sl = t & 15;
    if (n >= N) return;
    const float4* Xr = (const float4*)(X + (size_t)n * 256);
    const float4* Wl4 = (const float4*)Wl;
    const float4* Wr4 = (const float4*)Wr;
    float l0 = 0.f, l1 = 0.f, r0 = 0.f, r1 = 0.f;
#pragma unroll
    for (int j = 0; j < 4; ++j) {
        int idx = sl + j * 16;
        float4 xv = Xr[idx];
        float4 wa = Wl4[idx * 2];
        float4 wb = Wl4[idx * 2 + 1];
        l0 += xv.x * wa.x + xv.y * wa.z + xv.z * wb.x + xv.w * wb.z;
        l1 += xv.x * wa.y + xv.y * wa.w + xv.z * wb.y + xv.w * wb.w;
        wa = Wr4[idx * 2]; wb = Wr4[idx * 2 + 1];
        r0 += xv.x * wa.x + xv.y * wa.z + xv.z * wb.x + xv.w * wb.z;
        r1 += xv.x * wa.y + xv.y * wa.w + xv.z * wb.y + xv.w * wb.w;
    }
#pragma unroll
    for (int off = 1; off < 16; off <<= 1) {
        l0 += __shfl_xor(l0, off, 64);
        l1 += __shfl_xor(l1, off, 64);
        r0 += __shfl_xor(r0, off, 64);
        r1 += __shfl_xor(r1, off, 64);
    }
    if (sl == 0) {
        xl2[n * 2] = l0; xl2[n * 2 + 1] = l1;
        xr2[n * 2] = r0; xr2[n * 2 + 1] = r1;
    }
}

// ---- fused layer-2 attention (1 head, C=2) + log_softmax, thread/dst ----
__global__ void attn1_fused(int N, const float* __restrict__ xl2, const float* __restrict__ xr2,
                            const float* __restrict__ att, const float* __restrict__ bias,
                            const int* __restrict__ rowstart, const int* __restrict__ deg,
                            const int* __restrict__ csr_src, float* __restrict__ out) {
    int d = blockIdx.x * blockDim.x + threadIdx.x;
    if (d >= N) return;
    float a0 = att[0], a1 = att[1];
    float b0 = xr2[d * 2], b1 = xr2[d * 2 + 1];
    float s0 = xl2[d * 2], s1 = xl2[d * 2 + 1];
    float p = lrelu(s0 + b0) * a0 + lrelu(s1 + b1) * a1;
    float m = p, l = 1.f, ac0 = s0, ac1 = s1;
    int st = rowstart[d], n = deg[d];
    for (int i = 0; i < n; ++i) {
        int s = csr_src[st + i];
        float x0 = xl2[s * 2], x1 = xl2[s * 2 + 1];
        float q = lrelu(x0 + b0) * a0 + lrelu(x1 + b1) * a1;
        float mn = fmaxf(m, q);
        float sc = __expf(m - mn), eq = __expf(q - mn);
        l = l * sc + eq;
        ac0 = ac0 * sc + eq * x0;
        ac1 = ac1 * sc + eq * x1;
        m = mn;
    }
    float inv = 1.f / l;
    float v0 = ac0 * inv + bias[0];
    float v1 = ac1 * inv + bias[1];
    float mx = fmaxf(v0, v1);
    float lse = mx + logf(__expf(v0 - mx) + __expf(v1 - mx));
    out[d * 2] = v0 - lse;
    out[d * 2 + 1] = v1 - lse;
}

extern "C" void kernel_launch(void* const* d_in, const int* in_sizes, int n_in,
                              void* d_out, int out_size, void* d_ws, size_t ws_size,
                              hipStream_t stream) {
    const float* x        = (const float*)d_in[0];
    const int*   ei       = (const int*)  d_in[1];
    const float* W_in     = (const float*)d_in[2];
    const float* b_in     = (const float*)d_in[3];
    const float* Wl0      = (const float*)d_in[4];
    const float* Wr0      = (const float*)d_in[5];
    const float* att0     = (const float*)d_in[6];
    const float* bias0    = (const float*)d_in[7];
    const float* Wl1      = (const float*)d_in[8];
    const float* Wr1      = (const float*)d_in[9];
    const float* att1     = (const float*)d_in[10];
    const float* bias1    = (const float*)d_in[11];
    const float* Wl2      = (const float*)d_in[12];
    const float* Wr2      = (const float*)d_in[13];
    const float* att2     = (const float*)d_in[14];
    const float* bias2    = (const float*)d_in[15];
    const float* bn_gamma = (const float*)d_in[16];
    const float* bn_beta  = (const float*)d_in[17];
    const float* bn_mean  = (const float*)d_in[18];
    const float* bn_var   = (const float*)d_in[19];

    const int N  = in_sizes[0] / 128;
    const int E  = in_sizes[1] / 2;

    float* ws = (float*)d_ws;
    size_t off = 0;
    float* C    = ws + off; off += (size_t)N * 256;     // layer0 out / residual (f32)
    float* D    = ws + off; off += (size_t)N * 256;     // layer1 out (f32); head aliases H0
    float* XL2  = ws + off; off += (size_t)N * 2;
    float* XR2  = ws + off; off += (size_t)N * 2;
    unsigned short* Ab = (unsigned short*)(ws + off); off += (size_t)N * 128;  // bf16 xl
    unsigned short* Bb = (unsigned short*)(ws + off); off += (size_t)N * 128;  // bf16 xr
    int* ip = (int*)(ws + off);
    int* deg      = ip;              ip += N;
    int* rowstart = ip;              ip += N;
    int* cursor   = ip;              ip += N;
    int* csr_src  = ip;              ip += E;
    float* H0 = D;  // N*64 f32 scratch; D not written until layer-1 attention

    // ---- CSR build (every launch: ws is re-poisoned) ----
    zero_int<<<(N + 255) / 256, 256, 0, stream>>>(deg, N);
    hist_dst<<<(E + 255) / 256, 256, 0, stream>>>(ei, E, deg);
    scan_deg<<<1, 1024, 0, stream>>>(deg, rowstart, cursor, N);
    scatter_src<<<(E + 255) / 256, 256, 0, stream>>>(ei, E, cursor, csr_src);

    const int GB = (N + 15) / 16;

    // h0 = relu(x @ W_in + b_in)
    gemm_rb1<<<GB, 64, 0, stream>>>(x, W_in, b_in, H0, N, 128);

    // -------- layer 0 --------
    gemm_dual_bf16<<<dim3(GB, 4), 64, 0, stream>>>(H0, Wl0, Wr0, Ab, Bb, N, 64, 256);
    attn4_bn<<<(N + 3) / 4, 256, 0, stream>>>(N, Ab, Bb, att0, rowstart, deg, csr_src,
                                              bn_gamma, bn_beta, bn_mean, bn_var,
                                              bias0, nullptr, C);

    // -------- layer 1 (residual) --------
    gemm_dual_bf16<<<dim3(GB, 4), 64, 0, stream>>>(C, Wl1, Wr1, Ab, Bb, N, 256, 256);
    attn4_bn<<<(N + 3) / 4, 256, 0, stream>>>(N, Ab, Bb, att1, rowstart, deg, csr_src,
                                              bn_gamma + 256, bn_beta + 256, bn_mean + 256,
                                              bn_var + 256, bias1, C, D);

    // -------- layer 2 (1 head, C=2) + log_softmax --------
    gemm2_wave<<<(N * 16 + 255) / 256, 256, 0, stream>>>(D, Wl2, Wr2, XL2, XR2, N);
    attn1_fused<<<(N + 255) / 256, 256, 0, stream>>>(N, XL2, XR2, att2, bias2,
                                                     rowstart, deg, csr_src, (float*)d_out);
}

// Round 6
// 718.595 us; speedup vs baseline: 10.8110x; 1.1034x over previous
//
#include <hip/hip_runtime.h>
#include <hip/hip_bf16.h>
#include <math.h>

// ---------------------------------------------------------------------------
// GATv2 3-layer GNN. CSR-by-dst on-device; bf16 MFMA GEMMs (f32 accumulate);
// fused online-softmax attention (bf16 gathers) with BN/ReLU/residual epilogue.
// ---------------------------------------------------------------------------

using short8  = __attribute__((ext_vector_type(8))) short;
using floatx4 = __attribute__((ext_vector_type(4))) float;

__device__ __forceinline__ float lrelu(float x) { return x > 0.f ? x : 0.2f * x; }

__device__ __forceinline__ unsigned short f2bf(float f) {
    __hip_bfloat16 h = __float2bfloat16(f);   // RNE
    return *reinterpret_cast<unsigned short*>(&h);
}
__device__ __forceinline__ float4 bf4_to_f4(ushort4 u) {
    float4 r;
    r.x = __uint_as_float((unsigned int)u.x << 16);
    r.y = __uint_as_float((unsigned int)u.y << 16);
    r.z = __uint_as_float((unsigned int)u.z << 16);
    r.w = __uint_as_float((unsigned int)u.w << 16);
    return r;
}

// ---------------- CSR build ----------------
__global__ void zero_int(int* __restrict__ p, int n) {
    int t = blockIdx.x * blockDim.x + threadIdx.x;
    if (t < n) p[t] = 0;
}

__global__ void hist_dst(const int* __restrict__ ei, int E, int* __restrict__ deg) {
    int e = blockIdx.x * blockDim.x + threadIdx.x;
    if (e < E) atomicAdd(&deg[ei[E + e]], 1);
}

__global__ void scan_deg(const int* __restrict__ deg, int* __restrict__ rowstart,
                         int* __restrict__ cursor, int N) {
    __shared__ int sums[1024];
    int tid = threadIdx.x;
    int chunk = (N + 1023) >> 10;
    int b = tid * chunk, e = min(b + chunk, N);
    int s = 0;
    for (int i = b; i < e; ++i) s += deg[i];
    sums[tid] = s;
    __syncthreads();
    for (int off = 1; off < 1024; off <<= 1) {
        int v = (tid >= off) ? sums[tid - off] : 0;
        __syncthreads();
        sums[tid] += v;
        __syncthreads();
    }
    int run = sums[tid] - s;
    for (int i = b; i < e; ++i) { rowstart[i] = run; cursor[i] = run; run += deg[i]; }
}

__global__ void scatter_src(const int* __restrict__ ei, int E,
                            int* __restrict__ cursor, int* __restrict__ csr_src) {
    int e = blockIdx.x * blockDim.x + threadIdx.x;
    if (e >= E) return;
    int d = ei[E + e];
    int pos = atomicAdd(&cursor[d], 1);
    csr_src[pos] = ei[e];
}

// ---------------- f32 -> bf16 conversions / weight packing ----------------
__global__ void f32_to_bf16_v(const float4* __restrict__ in, ushort4* __restrict__ out, int n4) {
    int t = blockIdx.x * blockDim.x + threadIdx.x;
    if (t >= n4) return;
    float4 v = in[t];
    ushort4 o; o.x = f2bf(v.x); o.y = f2bf(v.y); o.z = f2bf(v.z); o.w = f2bf(v.w);
    out[t] = o;
}

// Pack W [K][NC] (row-major f32) into MFMA B-fragment order (bf16):
// Wp[((nt*KC + kc)*64 + lane)*8 + j] = W[kc*32 + (lane>>4)*8 + j][nt*16 + (lane&15)]
__global__ void pack_w(const float* __restrict__ W, unsigned short* __restrict__ Wp,
                       int K, int NC) {
    int t = blockIdx.x * blockDim.x + threadIdx.x;
    int total = K * NC;
    if (t >= total) return;
    int j = t & 7;
    int l = (t >> 3) & 63;
    int rest = t >> 9;
    int KC = K >> 5;
    int kc = rest % KC;
    int nt = rest / KC;
    int row = kc * 32 + (l >> 4) * 8 + j;
    int col = nt * 16 + (l & 15);
    Wp[t] = f2bf(W[(size_t)row * NC + col]);
}

// ---------------- MFMA GEMM: out[M][ldo] = maybe_relu(bias + Xb @ W) -------
// Xb bf16 [M][K] row-major; Wp packed B-fragments; out bf16.
// 256-thread blocks = 4 waves; wave w handles rows blockIdx.x*64 + w*16,
// cols 0 .. NTILES*16-1 (ldo == NTILES*16).
template<int KC, int NTILES, bool RELU>
__global__ __launch_bounds__(256) void gemm_mfma(
        const unsigned short* __restrict__ Xb, const unsigned short* __restrict__ Wp,
        const float* __restrict__ bias, unsigned short* __restrict__ out, int M) {
    constexpr int K = KC * 32;
    constexpr int ldo = NTILES * 16;
    const int wid  = threadIdx.x >> 6;
    const int lane = threadIdx.x & 63;
    const int quad = lane >> 4, li = lane & 15;
    const int r0 = blockIdx.x * 64 + wid * 16;
    int arow = r0 + li; if (arow >= M) arow = M - 1;      // clamp (stores guarded)
    const short8* A8 = (const short8*)Xb + (size_t)arow * (K / 8) + quad;
    const short8* W8 = (const short8*)Wp;
    floatx4 acc[NTILES];
#pragma unroll
    for (int t = 0; t < NTILES; ++t) acc[t] = (floatx4){0.f, 0.f, 0.f, 0.f};
#pragma unroll
    for (int kc = 0; kc < KC; ++kc) {
        short8 a = A8[kc * 4];
#pragma unroll
        for (int nt = 0; nt < NTILES; ++nt) {
            short8 b = W8[(size_t)(nt * KC + kc) * 64 + lane];
            acc[nt] = __builtin_amdgcn_mfma_f32_16x16x32_bf16(a, b, acc[nt], 0, 0, 0);
        }
    }
#pragma unroll
    for (int nt = 0; nt < NTILES; ++nt) {
#pragma unroll
        for (int reg = 0; reg < 4; ++reg) {
            int rr = r0 + quad * 4 + reg;
            if (rr >= M) continue;
            float v = acc[nt][reg];
            if (RELU) v = fmaxf(v + bias[nt * 16 + li], 0.f);
            out[(size_t)rr * ldo + nt * 16 + li] = f2bf(v);
        }
    }
}

// ---- fused 4-head attention + BN + ReLU (+residual), wave/dst, bf16 in ----
__global__ void attn4_bn(int N, const unsigned short* __restrict__ XL,
                         const unsigned short* __restrict__ XR,
                         const float* __restrict__ att,
                         const int* __restrict__ rowstart, const int* __restrict__ deg,
                         const int* __restrict__ csr_src,
                         const float* __restrict__ gamma, const float* __restrict__ beta,
                         const float* __restrict__ mean, const float* __restrict__ var,
                         const float* __restrict__ bias, const float* __restrict__ resid,
                         float* __restrict__ out, unsigned short* __restrict__ outb) {
    int d = blockIdx.x * (blockDim.x >> 6) + (threadIdx.x >> 6);
    int lane = threadIdx.x & 63;
    if (d >= N) return;
    float4 b = bf4_to_f4(*(const ushort4*)(XR + (size_t)d * 256 + lane * 4));
    float4 w = ((const float4*)att)[lane];
    float4 a = bf4_to_f4(*(const ushort4*)(XL + (size_t)d * 256 + lane * 4));
    float p = lrelu(a.x + b.x) * w.x + lrelu(a.y + b.y) * w.y
            + lrelu(a.z + b.z) * w.z + lrelu(a.w + b.w) * w.w;
    p += __shfl_xor(p, 1, 64); p += __shfl_xor(p, 2, 64);
    p += __shfl_xor(p, 4, 64); p += __shfl_xor(p, 8, 64);
    float m = p, l = 1.f;
    float4 acc = a;
    int start = rowstart[d], n = deg[d];
    ushort4 nx = {0, 0, 0, 0};
    if (n > 0) nx = *(const ushort4*)(XL + (size_t)csr_src[start] * 256 + lane * 4);
    for (int i = 0; i < n; ++i) {
        float4 xc = bf4_to_f4(nx);
        if (i + 1 < n) nx = *(const ushort4*)(XL + (size_t)csr_src[start + i + 1] * 256 + lane * 4);
        float q = lrelu(xc.x + b.x) * w.x + lrelu(xc.y + b.y) * w.y
                + lrelu(xc.z + b.z) * w.z + lrelu(xc.w + b.w) * w.w;
        q += __shfl_xor(q, 1, 64); q += __shfl_xor(q, 2, 64);
        q += __shfl_xor(q, 4, 64); q += __shfl_xor(q, 8, 64);
        float mn = fmaxf(m, q);
        float sc = __expf(m - mn);
        float eq = __expf(q - mn);
        l = l * sc + eq;
        acc.x = acc.x * sc + eq * xc.x;
        acc.y = acc.y * sc + eq * xc.y;
        acc.z = acc.z * sc + eq * xc.z;
        acc.w = acc.w * sc + eq * xc.w;
        m = mn;
    }
    float inv = 1.f / l;
    float4 g  = ((const float4*)gamma)[lane];
    float4 be = ((const float4*)beta)[lane];
    float4 mu = ((const float4*)mean)[lane];
    float4 va = ((const float4*)var)[lane];
    float4 bi = ((const float4*)bias)[lane];
    float4 sc4, sh4;
    sc4.x = g.x * rsqrtf(va.x + 1e-5f); sh4.x = (bi.x - mu.x) * sc4.x + be.x;
    sc4.y = g.y * rsqrtf(va.y + 1e-5f); sh4.y = (bi.y - mu.y) * sc4.y + be.y;
    sc4.z = g.z * rsqrtf(va.z + 1e-5f); sh4.z = (bi.z - mu.z) * sc4.z + be.z;
    sc4.w = g.w * rsqrtf(va.w + 1e-5f); sh4.w = (bi.w - mu.w) * sc4.w + be.w;
    float4 o;
    o.x = fmaxf(acc.x * inv * sc4.x + sh4.x, 0.f);
    o.y = fmaxf(acc.y * inv * sc4.y + sh4.y, 0.f);
    o.z = fmaxf(acc.z * inv * sc4.z + sh4.z, 0.f);
    o.w = fmaxf(acc.w * inv * sc4.w + sh4.w, 0.f);
    if (resid) {
        float4 rv = *(const float4*)(resid + (size_t)d * 256 + lane * 4);
        o.x += rv.x; o.y += rv.y; o.z += rv.z; o.w += rv.w;
    }
    *(float4*)(out + (size_t)d * 256 + lane * 4) = o;
    if (outb) {
        ushort4 ob; ob.x = f2bf(o.x); ob.y = f2bf(o.y); ob.z = f2bf(o.z); ob.w = f2bf(o.w);
        *(ushort4*)(outb + (size_t)d * 256 + lane * 4) = ob;
    }
}

// ---- layer 2 projections: 16 lanes per node; each lane covers 16 of K=256 ----
__global__ void gemm2_wave(const float* __restrict__ X, const float* __restrict__ Wl,
                           const float* __restrict__ Wr, float* __restrict__ xl2,
                           float* __restrict__ xr2, int N) {
    int t = blockIdx.x * blockDim.x + threadIdx.x;
    int n = t >> 4;
    int sl = t & 15;
    if (n >= N) return;
    const float4* Xr = (const float4*)(X + (size_t)n * 256);
    const float4* Wl4 = (const float4*)Wl;
    const float4* Wr4 = (const float4*)Wr;
    float l0 = 0.f, l1 = 0.f, r0 = 0.f, r1 = 0.f;
#pragma unroll
    for (int j = 0; j < 4; ++j) {
        int idx = sl + j * 16;
        float4 xv = Xr[idx];
        float4 wa = Wl4[idx * 2];
        float4 wb = Wl4[idx * 2 + 1];
        l0 += xv.x * wa.x + xv.y * wa.z + xv.z * wb.x + xv.w * wb.z;
        l1 += xv.x * wa.y + xv.y * wa.w + xv.z * wb.y + xv.w * wb.w;
        wa = Wr4[idx * 2]; wb = Wr4[idx * 2 + 1];
        r0 += xv.x * wa.x + xv.y * wa.z + xv.z * wb.x + xv.w * wb.z;
        r1 += xv.x * wa.y + xv.y * wa.w + xv.z * wb.y + xv.w * wb.w;
    }
#pragma unroll
    for (int off = 1; off < 16; off <<= 1) {
        l0 += __shfl_xor(l0, off, 64);
        l1 += __shfl_xor(l1, off, 64);
        r0 += __shfl_xor(r0, off, 64);
        r1 += __shfl_xor(r1, off, 64);
    }
    if (sl == 0) {
        xl2[n * 2] = l0; xl2[n * 2 + 1] = l1;
        xr2[n * 2] = r0; xr2[n * 2 + 1] = r1;
    }
}

// ---- fused layer-2 attention (1 head, C=2) + log_softmax, thread/dst ----
__global__ void attn1_fused(int N, const float* __restrict__ xl2, const float* __restrict__ xr2,
                            const float* __restrict__ att, const float* __restrict__ bias,
                            const int* __restrict__ rowstart, const int* __restrict__ deg,
                            const int* __restrict__ csr_src, float* __restrict__ out) {
    int d = blockIdx.x * blockDim.x + threadIdx.x;
    if (d >= N) return;
    float a0 = att[0], a1 = att[1];
    float b0 = xr2[d * 2], b1 = xr2[d * 2 + 1];
    float s0 = xl2[d * 2], s1 = xl2[d * 2 + 1];
    float p = lrelu(s0 + b0) * a0 + lrelu(s1 + b1) * a1;
    float m = p, l = 1.f, ac0 = s0, ac1 = s1;
    int st = rowstart[d], n = deg[d];
    for (int i = 0; i < n; ++i) {
        int s = csr_src[st + i];
        float x0 = xl2[s * 2], x1 = xl2[s * 2 + 1];
        float q = lrelu(x0 + b0) * a0 + lrelu(x1 + b1) * a1;
        float mn = fmaxf(m, q);
        float sc = __expf(m - mn), eq = __expf(q - mn);
        l = l * sc + eq;
        ac0 = ac0 * sc + eq * x0;
        ac1 = ac1 * sc + eq * x1;
        m = mn;
    }
    float inv = 1.f / l;
    float v0 = ac0 * inv + bias[0];
    float v1 = ac1 * inv + bias[1];
    float mx = fmaxf(v0, v1);
    float lse = mx + logf(__expf(v0 - mx) + __expf(v1 - mx));
    out[d * 2] = v0 - lse;
    out[d * 2 + 1] = v1 - lse;
}

extern "C" void kernel_launch(void* const* d_in, const int* in_sizes, int n_in,
                              void* d_out, int out_size, void* d_ws, size_t ws_size,
                              hipStream_t stream) {
    const float* x        = (const float*)d_in[0];
    const int*   ei       = (const int*)  d_in[1];
    const float* W_in     = (const float*)d_in[2];
    const float* b_in     = (const float*)d_in[3];
    const float* Wl0      = (const float*)d_in[4];
    const float* Wr0      = (const float*)d_in[5];
    const float* att0     = (const float*)d_in[6];
    const float* bias0    = (const float*)d_in[7];
    const float* Wl1      = (const float*)d_in[8];
    const float* Wr1      = (const float*)d_in[9];
    const float* att1     = (const float*)d_in[10];
    const float* bias1    = (const float*)d_in[11];
    const float* Wl2      = (const float*)d_in[12];
    const float* Wr2      = (const float*)d_in[13];
    const float* att2     = (const float*)d_in[14];
    const float* bias2    = (const float*)d_in[15];
    const float* bn_gamma = (const float*)d_in[16];
    const float* bn_beta  = (const float*)d_in[17];
    const float* bn_mean  = (const float*)d_in[18];
    const float* bn_var   = (const float*)d_in[19];

    const int N  = in_sizes[0] / 128;
    const int E  = in_sizes[1] / 2;

    float* ws = (float*)d_ws;
    size_t off = 0;
    float* C    = ws + off; off += (size_t)N * 256;     // layer0 out / residual (f32)
    float* D    = ws + off; off += (size_t)N * 256;     // layer1 out (f32)
    float* XL2  = ws + off; off += (size_t)N * 2;
    float* XR2  = ws + off; off += (size_t)N * 2;
    unsigned short* Ab   = (unsigned short*)(ws + off); off += (size_t)N * 128;  // bf16 xl [N,256]
    unsigned short* Bb   = (unsigned short*)(ws + off); off += (size_t)N * 128;  // bf16 xr [N,256]
    unsigned short* Cb   = (unsigned short*)(ws + off); off += (size_t)N * 128;  // bf16 copy of C
    unsigned short* H0b  = (unsigned short*)(ws + off); off += (size_t)N * 32;   // bf16 h0 [N,64]
    unsigned short* xb   = (unsigned short*)(ws + off); off += (size_t)N * 64;   // bf16 x  [N,128]
    unsigned short* Wp_in = (unsigned short*)(ws + off); off += 4096;    // 128*64
    unsigned short* Wp_l0 = (unsigned short*)(ws + off); off += 8192;    // 64*256
    unsigned short* Wp_r0 = (unsigned short*)(ws + off); off += 8192;
    unsigned short* Wp_l1 = (unsigned short*)(ws + off); off += 32768;   // 256*256
    unsigned short* Wp_r1 = (unsigned short*)(ws + off); off += 32768;
    int* ip = (int*)(ws + off);
    int* deg      = ip;              ip += N;
    int* rowstart = ip;              ip += N;
    int* cursor   = ip;              ip += N;
    int* csr_src  = ip;              ip += E;

    // ---- CSR build ----
    zero_int<<<(N + 255) / 256, 256, 0, stream>>>(deg, N);
    hist_dst<<<(E + 255) / 256, 256, 0, stream>>>(ei, E, deg);
    scan_deg<<<1, 1024, 0, stream>>>(deg, rowstart, cursor, N);
    scatter_src<<<(E + 255) / 256, 256, 0, stream>>>(ei, E, cursor, csr_src);

    // ---- conversions & weight packing ----
    f32_to_bf16_v<<<(N * 32 + 255) / 256, 256, 0, stream>>>((const float4*)x, (ushort4*)xb, N * 32);
    pack_w<<<(128 * 64 + 255) / 256, 256, 0, stream>>>(W_in, Wp_in, 128, 64);
    pack_w<<<(64 * 256 + 255) / 256, 256, 0, stream>>>(Wl0, Wp_l0, 64, 256);
    pack_w<<<(64 * 256 + 255) / 256, 256, 0, stream>>>(Wr0, Wp_r0, 64, 256);
    pack_w<<<(256 * 256 + 255) / 256, 256, 0, stream>>>(Wl1, Wp_l1, 256, 256);
    pack_w<<<(256 * 256 + 255) / 256, 256, 0, stream>>>(Wr1, Wp_r1, 256, 256);

    const int GBM = (N + 63) / 64;

    // h0 = relu(x @ W_in + b_in)  -> bf16
    gemm_mfma<4, 4, true><<<GBM, 256, 0, stream>>>(xb, Wp_in, b_in, H0b, N);

    // -------- layer 0 --------
    gemm_mfma<2, 16, false><<<GBM, 256, 0, stream>>>(H0b, Wp_l0, nullptr, Ab, N);
    gemm_mfma<2, 16, false><<<GBM, 256, 0, stream>>>(H0b, Wp_r0, nullptr, Bb, N);
    attn4_bn<<<(N + 3) / 4, 256, 0, stream>>>(N, Ab, Bb, att0, rowstart, deg, csr_src,
                                              bn_gamma, bn_beta, bn_mean, bn_var,
                                              bias0, nullptr, C, Cb);

    // -------- layer 1 (residual) --------
    gemm_mfma<8, 16, false><<<GBM, 256, 0, stream>>>(Cb, Wp_l1, nullptr, Ab, N);
    gemm_mfma<8, 16, false><<<GBM, 256, 0, stream>>>(Cb, Wp_r1, nullptr, Bb, N);
    attn4_bn<<<(N + 3) / 4, 256, 0, stream>>>(N, Ab, Bb, att1, rowstart, deg, csr_src,
                                              bn_gamma + 256, bn_beta + 256, bn_mean + 256,
                                              bn_var + 256, bias1, C, D, nullptr);

    // -------- layer 2 (1 head, C=2) + log_softmax --------
    gemm2_wave<<<(N * 16 + 255) / 256, 256, 0, stream>>>(D, Wl2, Wr2, XL2, XR2, N);
    attn1_fused<<<(N + 255) / 256, 256, 0, stream>>>(N, XL2, XR2, att2, bias2,
                                                     rowstart, deg, csr_src, (float*)d_out);
}

// Round 7
// 601.962 us; speedup vs baseline: 12.9057x; 1.1938x over previous
//
#include <hip/hip_runtime.h>
#include <hip/hip_bf16.h>
#include <math.h>

// ---------------------------------------------------------------------------
// GATv2 3-layer GNN. CSR-by-dst on-device (parallel 3-kernel scan); bf16 MFMA
// GEMMs (f32 accumulate); fused online-softmax attention (bf16 gathers) with
// BN/ReLU/residual epilogue.
// ---------------------------------------------------------------------------

using short8  = __attribute__((ext_vector_type(8))) short;
using floatx4 = __attribute__((ext_vector_type(4))) float;

__device__ __forceinline__ float lrelu(float x) { return x > 0.f ? x : 0.2f * x; }

__device__ __forceinline__ unsigned short f2bf(float f) {
    __hip_bfloat16 h = __float2bfloat16(f);   // RNE
    return *reinterpret_cast<unsigned short*>(&h);
}
__device__ __forceinline__ float4 bf4_to_f4(ushort4 u) {
    float4 r;
    r.x = __uint_as_float((unsigned int)u.x << 16);
    r.y = __uint_as_float((unsigned int)u.y << 16);
    r.z = __uint_as_float((unsigned int)u.z << 16);
    r.w = __uint_as_float((unsigned int)u.w << 16);
    return r;
}

// ---------------- CSR build ----------------
__global__ void zero_int(int* __restrict__ p, int n) {
    int t = blockIdx.x * blockDim.x + threadIdx.x;
    if (t < n) p[t] = 0;
}

__global__ void hist_dst(const int* __restrict__ ei, int E, int* __restrict__ deg) {
    int e = blockIdx.x * blockDim.x + threadIdx.x;
    if (e < E) atomicAdd(&deg[ei[E + e]], 1);
}

// per-block scan: rowstart[t] = exclusive prefix within block; bsum[b] = block total
__global__ __launch_bounds__(256) void scan_blk(const int* __restrict__ deg,
                                                int* __restrict__ rowstart,
                                                int* __restrict__ bsum, int N) {
    int t = blockIdx.x * 256 + threadIdx.x;
    int lane = threadIdx.x & 63, wid = threadIdx.x >> 6;
    int v = (t < N) ? deg[t] : 0;
    int x = v;
#pragma unroll
    for (int off = 1; off < 64; off <<= 1) {
        int y = __shfl_up(x, off, 64);
        if (lane >= off) x += y;
    }
    __shared__ int wsum[4];
    if (lane == 63) wsum[wid] = x;
    __syncthreads();
    int add = 0;
#pragma unroll
    for (int w = 0; w < 4; ++w) if (w < wid) add += wsum[w];
    int incl = x + add;
    if (t < N) rowstart[t] = incl - v;
    if (threadIdx.x == 255) bsum[blockIdx.x] = incl;
}

// single block: exclusive scan of bsum[NB] in place (NB <= 256)
__global__ __launch_bounds__(256) void scan_off(int* __restrict__ bsum, int NB) {
    int t = threadIdx.x;
    int lane = t & 63, wid = t >> 6;
    int v = (t < NB) ? bsum[t] : 0;
    int x = v;
#pragma unroll
    for (int off = 1; off < 64; off <<= 1) {
        int y = __shfl_up(x, off, 64);
        if (lane >= off) x += y;
    }
    __shared__ int wsum[4];
    if (lane == 63) wsum[wid] = x;
    __syncthreads();
    int add = 0;
#pragma unroll
    for (int w = 0; w < 4; ++w) if (w < wid) add += wsum[w];
    if (t < NB) bsum[t] = x + add - v;
}

__global__ void add_off(const int* __restrict__ bsum, int* __restrict__ rowstart,
                        int* __restrict__ cursor, int N) {
    int t = blockIdx.x * 256 + threadIdx.x;
    if (t >= N) return;
    int r = rowstart[t] + bsum[blockIdx.x];
    rowstart[t] = r;
    cursor[t] = r;
}

__global__ void scatter_src(const int* __restrict__ ei, int E,
                            int* __restrict__ cursor, int* __restrict__ csr_src) {
    int e = blockIdx.x * blockDim.x + threadIdx.x;
    if (e >= E) return;
    int d = ei[E + e];
    int pos = atomicAdd(&cursor[d], 1);
    csr_src[pos] = ei[e];
}

// ---------------- f32 -> bf16 conversions / weight packing ----------------
__global__ void f32_to_bf16_v(const float4* __restrict__ in, ushort4* __restrict__ out, int n4) {
    int t = blockIdx.x * blockDim.x + threadIdx.x;
    if (t >= n4) return;
    float4 v = in[t];
    ushort4 o; o.x = f2bf(v.x); o.y = f2bf(v.y); o.z = f2bf(v.z); o.w = f2bf(v.w);
    out[t] = o;
}

// Pack element t of W [K][NC] into MFMA B-fragment order (bf16):
// Wp[((nt*KC + kc)*64 + l)*8 + j] = W[kc*32 + (l>>4)*8 + j][nt*16 + (l&15)]
__device__ __forceinline__ void pack_one(const float* __restrict__ W,
                                         unsigned short* __restrict__ Wp,
                                         int t, int K, int NC) {
    int j = t & 7;
    int l = (t >> 3) & 63;
    int rest = t >> 9;
    int KC = K >> 5;
    int kc = rest % KC;
    int nt = rest / KC;
    int row = kc * 32 + (l >> 4) * 8 + j;
    int col = nt * 16 + (l & 15);
    Wp[t] = f2bf(W[(size_t)row * NC + col]);
}

// all 5 weight matrices in one launch (sizes fixed by the model)
__global__ void pack_all(const float* __restrict__ W_in,
                         const float* __restrict__ Wl0, const float* __restrict__ Wr0,
                         const float* __restrict__ Wl1, const float* __restrict__ Wr1,
                         unsigned short* __restrict__ P_in,
                         unsigned short* __restrict__ P_l0, unsigned short* __restrict__ P_r0,
                         unsigned short* __restrict__ P_l1, unsigned short* __restrict__ P_r1) {
    int t = blockIdx.x * blockDim.x + threadIdx.x;
    if (t < 8192)        pack_one(W_in, P_in, t, 128, 64);
    else if (t < 24576)  pack_one(Wl0, P_l0, t - 8192, 64, 256);
    else if (t < 40960)  pack_one(Wr0, P_r0, t - 24576, 64, 256);
    else if (t < 106496) pack_one(Wl1, P_l1, t - 40960, 256, 256);
    else if (t < 172032) pack_one(Wr1, P_r1, t - 106496, 256, 256);
}

// ---------------- MFMA GEMM: out[M][ldo] = maybe_relu(bias + Xb @ W) -------
template<int KC, int NTILES, bool RELU>
__global__ __launch_bounds__(256) void gemm_mfma(
        const unsigned short* __restrict__ Xb, const unsigned short* __restrict__ Wp,
        const float* __restrict__ bias, unsigned short* __restrict__ out, int M) {
    constexpr int K = KC * 32;
    constexpr int ldo = NTILES * 16;
    const int wid  = threadIdx.x >> 6;
    const int lane = threadIdx.x & 63;
    const int quad = lane >> 4, li = lane & 15;
    const int r0 = blockIdx.x * 64 + wid * 16;
    int arow = r0 + li; if (arow >= M) arow = M - 1;      // clamp (stores guarded)
    const short8* A8 = (const short8*)Xb + (size_t)arow * (K / 8) + quad;
    const short8* W8 = (const short8*)Wp;
    floatx4 acc[NTILES];
#pragma unroll
    for (int t = 0; t < NTILES; ++t) acc[t] = (floatx4){0.f, 0.f, 0.f, 0.f};
#pragma unroll
    for (int kc = 0; kc < KC; ++kc) {
        short8 a = A8[kc * 4];
#pragma unroll
        for (int nt = 0; nt < NTILES; ++nt) {
            short8 b = W8[(size_t)(nt * KC + kc) * 64 + lane];
            acc[nt] = __builtin_amdgcn_mfma_f32_16x16x32_bf16(a, b, acc[nt], 0, 0, 0);
        }
    }
#pragma unroll
    for (int nt = 0; nt < NTILES; ++nt) {
#pragma unroll
        for (int reg = 0; reg < 4; ++reg) {
            int rr = r0 + quad * 4 + reg;
            if (rr >= M) continue;
            float v = acc[nt][reg];
            if (RELU) v = fmaxf(v + bias[nt * 16 + li], 0.f);
            out[(size_t)rr * ldo + nt * 16 + li] = f2bf(v);
        }
    }
}

// ---- fused 4-head attention + BN + ReLU (+residual), wave/dst, bf16 in ----
__global__ void attn4_bn(int N, const unsigned short* __restrict__ XL,
                         const unsigned short* __restrict__ XR,
                         const float* __restrict__ att,
                         const int* __restrict__ rowstart, const int* __restrict__ deg,
                         const int* __restrict__ csr_src,
                         const float* __restrict__ gamma, const float* __restrict__ beta,
                         const float* __restrict__ mean, const float* __restrict__ var,
                         const float* __restrict__ bias, const float* __restrict__ resid,
                         float* __restrict__ out, unsigned short* __restrict__ outb) {
    int d = blockIdx.x * (blockDim.x >> 6) + (threadIdx.x >> 6);
    int lane = threadIdx.x & 63;
    if (d >= N) return;
    float4 b = bf4_to_f4(*(const ushort4*)(XR + (size_t)d * 256 + lane * 4));
    float4 w = ((const float4*)att)[lane];
    float4 a = bf4_to_f4(*(const ushort4*)(XL + (size_t)d * 256 + lane * 4));
    float p = lrelu(a.x + b.x) * w.x + lrelu(a.y + b.y) * w.y
            + lrelu(a.z + b.z) * w.z + lrelu(a.w + b.w) * w.w;
    p += __shfl_xor(p, 1, 64); p += __shfl_xor(p, 2, 64);
    p += __shfl_xor(p, 4, 64); p += __shfl_xor(p, 8, 64);
    float m = p, l = 1.f;
    float4 acc = a;
    int start = rowstart[d], n = deg[d];
    ushort4 nx = {0, 0, 0, 0};
    if (n > 0) nx = *(const ushort4*)(XL + (size_t)csr_src[start] * 256 + lane * 4);
    for (int i = 0; i < n; ++i) {
        float4 xc = bf4_to_f4(nx);
        if (i + 1 < n) nx = *(const ushort4*)(XL + (size_t)csr_src[start + i + 1] * 256 + lane * 4);
        float q = lrelu(xc.x + b.x) * w.x + lrelu(xc.y + b.y) * w.y
                + lrelu(xc.z + b.z) * w.z + lrelu(xc.w + b.w) * w.w;
        q += __shfl_xor(q, 1, 64); q += __shfl_xor(q, 2, 64);
        q += __shfl_xor(q, 4, 64); q += __shfl_xor(q, 8, 64);
        float mn = fmaxf(m, q);
        float sc = __expf(m - mn);
        float eq = __expf(q - mn);
        l = l * sc + eq;
        acc.x = acc.x * sc + eq * xc.x;
        acc.y = acc.y * sc + eq * xc.y;
        acc.z = acc.z * sc + eq * xc.z;
        acc.w = acc.w * sc + eq * xc.w;
        m = mn;
    }
    float inv = 1.f / l;
    float4 g  = ((const float4*)gamma)[lane];
    float4 be = ((const float4*)beta)[lane];
    float4 mu = ((const float4*)mean)[lane];
    float4 va = ((const float4*)var)[lane];
    float4 bi = ((const float4*)bias)[lane];
    float4 sc4, sh4;
    sc4.x = g.x * rsqrtf(va.x + 1e-5f); sh4.x = (bi.x - mu.x) * sc4.x + be.x;
    sc4.y = g.y * rsqrtf(va.y + 1e-5f); sh4.y = (bi.y - mu.y) * sc4.y + be.y;
    sc4.z = g.z * rsqrtf(va.z + 1e-5f); sh4.z = (bi.z - mu.z) * sc4.z + be.z;
    sc4.w = g.w * rsqrtf(va.w + 1e-5f); sh4.w = (bi.w - mu.w) * sc4.w + be.w;
    float4 o;
    o.x = fmaxf(acc.x * inv * sc4.x + sh4.x, 0.f);
    o.y = fmaxf(acc.y * inv * sc4.y + sh4.y, 0.f);
    o.z = fmaxf(acc.z * inv * sc4.z + sh4.z, 0.f);
    o.w = fmaxf(acc.w * inv * sc4.w + sh4.w, 0.f);
    if (resid) {
        float4 rv = *(const float4*)(resid + (size_t)d * 256 + lane * 4);
        o.x += rv.x; o.y += rv.y; o.z += rv.z; o.w += rv.w;
    }
    *(float4*)(out + (size_t)d * 256 + lane * 4) = o;
    if (outb) {
        ushort4 ob; ob.x = f2bf(o.x); ob.y = f2bf(o.y); ob.z = f2bf(o.z); ob.w = f2bf(o.w);
        *(ushort4*)(outb + (size_t)d * 256 + lane * 4) = ob;
    }
}

// ---- layer 2 projections: 16 lanes per node; each lane covers 16 of K=256 ----
__global__ void gemm2_wave(const float* __restrict__ X, const float* __restrict__ Wl,
                           const float* __restrict__ Wr, float* __restrict__ xl2,
                           float* __restrict__ xr2, int N) {
    int t = blockIdx.x * blockDim.x + threadIdx.x;
    int n = t >> 4;
    int sl = t & 15;
    if (n >= N) return;
    const float4* Xr = (const float4*)(X + (size_t)n * 256);
    const float4* Wl4 = (const float4*)Wl;
    const float4* Wr4 = (const float4*)Wr;
    float l0 = 0.f, l1 = 0.f, r0 = 0.f, r1 = 0.f;
#pragma unroll
    for (int j = 0; j < 4; ++j) {
        int idx = sl + j * 16;
        float4 xv = Xr[idx];
        float4 wa = Wl4[idx * 2];
        float4 wb = Wl4[idx * 2 + 1];
        l0 += xv.x * wa.x + xv.y * wa.z + xv.z * wb.x + xv.w * wb.z;
        l1 += xv.x * wa.y + xv.y * wa.w + xv.z * wb.y + xv.w * wb.w;
        wa = Wr4[idx * 2]; wb = Wr4[idx * 2 + 1];
        r0 += xv.x * wa.x + xv.y * wa.z + xv.z * wb.x + xv.w * wb.z;
        r1 += xv.x * wa.y + xv.y * wa.w + xv.z * wb.y + xv.w * wb.w;
    }
#pragma unroll
    for (int off = 1; off < 16; off <<= 1) {
        l0 += __shfl_xor(l0, off, 64);
        l1 += __shfl_xor(l1, off, 64);
        r0 += __shfl_xor(r0, off, 64);
        r1 += __shfl_xor(r1, off, 64);
    }
    if (sl == 0) {
        xl2[n * 2] = l0; xl2[n * 2 + 1] = l1;
        xr2[n * 2] = r0; xr2[n * 2 + 1] = r1;
    }
}

// ---- fused layer-2 attention (1 head, C=2) + log_softmax, thread/dst ----
__global__ void attn1_fused(int N, const float* __restrict__ xl2, const float* __restrict__ xr2,
                            const float* __restrict__ att, const float* __restrict__ bias,
                            const int* __restrict__ rowstart, const int* __restrict__ deg,
                            const int* __restrict__ csr_src, float* __restrict__ out) {
    int d = blockIdx.x * blockDim.x + threadIdx.x;
    if (d >= N) return;
    float a0 = att[0], a1 = att[1];
    float b0 = xr2[d * 2], b1 = xr2[d * 2 + 1];
    float s0 = xl2[d * 2], s1 = xl2[d * 2 + 1];
    float p = lrelu(s0 + b0) * a0 + lrelu(s1 + b1) * a1;
    float m = p, l = 1.f, ac0 = s0, ac1 = s1;
    int st = rowstart[d], n = deg[d];
    for (int i = 0; i < n; ++i) {
        int s = csr_src[st + i];
        float x0 = xl2[s * 2], x1 = xl2[s * 2 + 1];
        float q = lrelu(x0 + b0) * a0 + lrelu(x1 + b1) * a1;
        float mn = fmaxf(m, q);
        float sc = __expf(m - mn), eq = __expf(q - mn);
        l = l * sc + eq;
        ac0 = ac0 * sc + eq * x0;
        ac1 = ac1 * sc + eq * x1;
        m = mn;
    }
    float inv = 1.f / l;
    float v0 = ac0 * inv + bias[0];
    float v1 = ac1 * inv + bias[1];
    float mx = fmaxf(v0, v1);
    float lse = mx + logf(__expf(v0 - mx) + __expf(v1 - mx));
    out[d * 2] = v0 - lse;
    out[d * 2 + 1] = v1 - lse;
}

extern "C" void kernel_launch(void* const* d_in, const int* in_sizes, int n_in,
                              void* d_out, int out_size, void* d_ws, size_t ws_size,
                              hipStream_t stream) {
    const float* x        = (const float*)d_in[0];
    const int*   ei       = (const int*)  d_in[1];
    const float* W_in     = (const float*)d_in[2];
    const float* b_in     = (const float*)d_in[3];
    const float* Wl0      = (const float*)d_in[4];
    const float* Wr0      = (const float*)d_in[5];
    const float* att0     = (const float*)d_in[6];
    const float* bias0    = (const float*)d_in[7];
    const float* Wl1      = (const float*)d_in[8];
    const float* Wr1      = (const float*)d_in[9];
    const float* att1     = (const float*)d_in[10];
    const float* bias1    = (const float*)d_in[11];
    const float* Wl2      = (const float*)d_in[12];
    const float* Wr2      = (const float*)d_in[13];
    const float* att2     = (const float*)d_in[14];
    const float* bias2    = (const float*)d_in[15];
    const float* bn_gamma = (const float*)d_in[16];
    const float* bn_beta  = (const float*)d_in[17];
    const float* bn_mean  = (const float*)d_in[18];
    const float* bn_var   = (const float*)d_in[19];

    const int N  = in_sizes[0] / 128;
    const int E  = in_sizes[1] / 2;
    const int NB = (N + 255) / 256;

    float* ws = (float*)d_ws;
    size_t off = 0;
    float* C    = ws + off; off += (size_t)N * 256;     // layer0 out / residual (f32)
    float* D    = ws + off; off += (size_t)N * 256;     // layer1 out (f32)
    float* XL2  = ws + off; off += (size_t)N * 2;
    float* XR2  = ws + off; off += (size_t)N * 2;
    unsigned short* Ab   = (unsigned short*)(ws + off); off += (size_t)N * 128;  // bf16 xl [N,256]
    unsigned short* Bb   = (unsigned short*)(ws + off); off += (size_t)N * 128;  // bf16 xr [N,256]
    unsigned short* Cb   = (unsigned short*)(ws + off); off += (size_t)N * 128;  // bf16 copy of C
    unsigned short* H0b  = (unsigned short*)(ws + off); off += (size_t)N * 32;   // bf16 h0 [N,64]
    unsigned short* xb   = (unsigned short*)(ws + off); off += (size_t)N * 64;   // bf16 x  [N,128]
    unsigned short* Wp_in = (unsigned short*)(ws + off); off += 4096;    // 128*64
    unsigned short* Wp_l0 = (unsigned short*)(ws + off); off += 8192;    // 64*256
    unsigned short* Wp_r0 = (unsigned short*)(ws + off); off += 8192;
    unsigned short* Wp_l1 = (unsigned short*)(ws + off); off += 32768;   // 256*256
    unsigned short* Wp_r1 = (unsigned short*)(ws + off); off += 32768;
    int* ip = (int*)(ws + off);
    int* deg      = ip;              ip += N;
    int* rowstart = ip;              ip += N;
    int* cursor   = ip;              ip += N;
    int* bsum     = ip;              ip += NB;
    int* csr_src  = ip;              ip += E;

    // ---- CSR build (parallel scan) ----
    zero_int<<<(N + 255) / 256, 256, 0, stream>>>(deg, N);
    hist_dst<<<(E + 255) / 256, 256, 0, stream>>>(ei, E, deg);
    scan_blk<<<NB, 256, 0, stream>>>(deg, rowstart, bsum, N);
    scan_off<<<1, 256, 0, stream>>>(bsum, NB);
    add_off<<<NB, 256, 0, stream>>>(bsum, rowstart, cursor, N);
    scatter_src<<<(E + 255) / 256, 256, 0, stream>>>(ei, E, cursor, csr_src);

    // ---- conversions & weight packing ----
    f32_to_bf16_v<<<(N * 32 + 255) / 256, 256, 0, stream>>>((const float4*)x, (ushort4*)xb, N * 32);
    pack_all<<<(172032 + 255) / 256, 256, 0, stream>>>(W_in, Wl0, Wr0, Wl1, Wr1,
                                                       Wp_in, Wp_l0, Wp_r0, Wp_l1, Wp_r1);

    const int GBM = (N + 63) / 64;

    // h0 = relu(x @ W_in + b_in)  -> bf16
    gemm_mfma<4, 4, true><<<GBM, 256, 0, stream>>>(xb, Wp_in, b_in, H0b, N);

    // -------- layer 0 --------
    gemm_mfma<2, 16, false><<<GBM, 256, 0, stream>>>(H0b, Wp_l0, nullptr, Ab, N);
    gemm_mfma<2, 16, false><<<GBM, 256, 0, stream>>>(H0b, Wp_r0, nullptr, Bb, N);
    attn4_bn<<<(N + 3) / 4, 256, 0, stream>>>(N, Ab, Bb, att0, rowstart, deg, csr_src,
                                              bn_gamma, bn_beta, bn_mean, bn_var,
                                              bias0, nullptr, C, Cb);

    // -------- layer 1 (residual) --------
    gemm_mfma<8, 16, false><<<GBM, 256, 0, stream>>>(Cb, Wp_l1, nullptr, Ab, N);
    gemm_mfma<8, 16, false><<<GBM, 256, 0, stream>>>(Cb, Wp_r1, nullptr, Bb, N);
    attn4_bn<<<(N + 3) / 4, 256, 0, stream>>>(N, Ab, Bb, att1, rowstart, deg, csr_src,
                                              bn_gamma + 256, bn_beta + 256, bn_mean + 256,
                                              bn_var + 256, bias1, C, D, nullptr);

    // -------- layer 2 (1 head, C=2) + log_softmax --------
    gemm2_wave<<<(N * 16 + 255) / 256, 256, 0, stream>>>(D, Wl2, Wr2, XL2, XR2, N);
    attn1_fused<<<(N + 255) / 256, 256, 0, stream>>>(N, XL2, XR2, att2, bias2,
                                                     rowstart, deg, csr_src, (float*)d_out);
}

// Round 8
// 596.241 us; speedup vs baseline: 13.0295x; 1.0096x over previous
//
#include <hip/hip_runtime.h>
#include <hip/hip_bf16.h>
#include <math.h>

// ---------------------------------------------------------------------------
// GATv2 3-layer GNN. CSR-by-dst on-device (parallel scan); f16 MFMA GEMMs
// (f32 accumulate); fused online-softmax attention with packed-f16 logit
// pipeline and BN/ReLU/residual epilogue.
// ---------------------------------------------------------------------------

using h16     = _Float16;
using half2v  = __attribute__((ext_vector_type(2))) h16;
using half4v  = __attribute__((ext_vector_type(4))) h16;
using half8   = __attribute__((ext_vector_type(8))) h16;
using floatx4 = __attribute__((ext_vector_type(4))) float;

__device__ __forceinline__ float lrelu(float x) { return x > 0.f ? x : 0.2f * x; }

// ---------------- CSR build ----------------
__global__ void zero_int(int* __restrict__ p, int n) {
    int t = blockIdx.x * blockDim.x + threadIdx.x;
    if (t < n) p[t] = 0;
}

__global__ void hist_dst(const int* __restrict__ ei, int E, int* __restrict__ deg) {
    int e = blockIdx.x * blockDim.x + threadIdx.x;
    if (e < E) atomicAdd(&deg[ei[E + e]], 1);
}

__global__ __launch_bounds__(256) void scan_blk(const int* __restrict__ deg,
                                                int* __restrict__ rowstart,
                                                int* __restrict__ bsum, int N) {
    int t = blockIdx.x * 256 + threadIdx.x;
    int lane = threadIdx.x & 63, wid = threadIdx.x >> 6;
    int v = (t < N) ? deg[t] : 0;
    int x = v;
#pragma unroll
    for (int off = 1; off < 64; off <<= 1) {
        int y = __shfl_up(x, off, 64);
        if (lane >= off) x += y;
    }
    __shared__ int wsum[4];
    if (lane == 63) wsum[wid] = x;
    __syncthreads();
    int add = 0;
#pragma unroll
    for (int w = 0; w < 4; ++w) if (w < wid) add += wsum[w];
    int incl = x + add;
    if (t < N) rowstart[t] = incl - v;
    if (threadIdx.x == 255) bsum[blockIdx.x] = incl;
}

__global__ __launch_bounds__(256) void scan_off(int* __restrict__ bsum, int NB) {
    int t = threadIdx.x;
    int lane = t & 63, wid = t >> 6;
    int v = (t < NB) ? bsum[t] : 0;
    int x = v;
#pragma unroll
    for (int off = 1; off < 64; off <<= 1) {
        int y = __shfl_up(x, off, 64);
        if (lane >= off) x += y;
    }
    __shared__ int wsum[4];
    if (lane == 63) wsum[wid] = x;
    __syncthreads();
    int add = 0;
#pragma unroll
    for (int w = 0; w < 4; ++w) if (w < wid) add += wsum[w];
    if (t < NB) bsum[t] = x + add - v;
}

__global__ void add_off(const int* __restrict__ bsum, int* __restrict__ rowstart,
                        int* __restrict__ cursor, int N) {
    int t = blockIdx.x * 256 + threadIdx.x;
    if (t >= N) return;
    int r = rowstart[t] + bsum[blockIdx.x];
    rowstart[t] = r;
    cursor[t] = r;
}

__global__ void scatter_src(const int* __restrict__ ei, int E,
                            int* __restrict__ cursor, int* __restrict__ csr_src) {
    int e = blockIdx.x * blockDim.x + threadIdx.x;
    if (e >= E) return;
    int d = ei[E + e];
    int pos = atomicAdd(&cursor[d], 1);
    csr_src[pos] = ei[e];
}

// ---------------- f32 -> f16 conversions / weight packing ----------------
__global__ void f32_to_f16_v(const float4* __restrict__ in, half4v* __restrict__ out, int n4) {
    int t = blockIdx.x * blockDim.x + threadIdx.x;
    if (t >= n4) return;
    float4 v = in[t];
    half4v o = { (h16)v.x, (h16)v.y, (h16)v.z, (h16)v.w };
    out[t] = o;
}

// Pack element t of W [K][NC] into MFMA B-fragment order (f16):
// Wp[((nt*KC + kc)*64 + l)*8 + j] = W[kc*32 + (l>>4)*8 + j][nt*16 + (l&15)]
__device__ __forceinline__ void pack_one(const float* __restrict__ W,
                                         h16* __restrict__ Wp,
                                         int t, int K, int NC) {
    int j = t & 7;
    int l = (t >> 3) & 63;
    int rest = t >> 9;
    int KC = K >> 5;
    int kc = rest % KC;
    int nt = rest / KC;
    int row = kc * 32 + (l >> 4) * 8 + j;
    int col = nt * 16 + (l & 15);
    Wp[t] = (h16)W[(size_t)row * NC + col];
}

__global__ void pack_all(const float* __restrict__ W_in,
                         const float* __restrict__ Wl0, const float* __restrict__ Wr0,
                         const float* __restrict__ Wl1, const float* __restrict__ Wr1,
                         h16* __restrict__ P_in,
                         h16* __restrict__ P_l0, h16* __restrict__ P_r0,
                         h16* __restrict__ P_l1, h16* __restrict__ P_r1) {
    int t = blockIdx.x * blockDim.x + threadIdx.x;
    if (t < 8192)        pack_one(W_in, P_in, t, 128, 64);
    else if (t < 24576)  pack_one(Wl0, P_l0, t - 8192, 64, 256);
    else if (t < 40960)  pack_one(Wr0, P_r0, t - 24576, 64, 256);
    else if (t < 106496) pack_one(Wl1, P_l1, t - 40960, 256, 256);
    else if (t < 172032) pack_one(Wr1, P_r1, t - 106496, 256, 256);
}

// ---------------- MFMA GEMM: out[M][ldo] = maybe_relu(bias + Xh @ W) -------
template<int KC, int NTILES, bool RELU>
__global__ __launch_bounds__(256) void gemm_mfma(
        const h16* __restrict__ Xh, const h16* __restrict__ Wp,
        const float* __restrict__ bias, h16* __restrict__ out, int M) {
    constexpr int K = KC * 32;
    constexpr int ldo = NTILES * 16;
    const int wid  = threadIdx.x >> 6;
    const int lane = threadIdx.x & 63;
    const int quad = lane >> 4, li = lane & 15;
    const int r0 = blockIdx.x * 64 + wid * 16;
    int arow = r0 + li; if (arow >= M) arow = M - 1;      // clamp (stores guarded)
    const half8* A8 = (const half8*)Xh + (size_t)arow * (K / 8) + quad;
    const half8* W8 = (const half8*)Wp;
    floatx4 acc[NTILES];
#pragma unroll
    for (int t = 0; t < NTILES; ++t) acc[t] = (floatx4){0.f, 0.f, 0.f, 0.f};
#pragma unroll
    for (int kc = 0; kc < KC; ++kc) {
        half8 a = A8[kc * 4];
#pragma unroll
        for (int nt = 0; nt < NTILES; ++nt) {
            half8 b = W8[(size_t)(nt * KC + kc) * 64 + lane];
            acc[nt] = __builtin_amdgcn_mfma_f32_16x16x32_f16(a, b, acc[nt], 0, 0, 0);
        }
    }
#pragma unroll
    for (int nt = 0; nt < NTILES; ++nt) {
#pragma unroll
        for (int reg = 0; reg < 4; ++reg) {
            int rr = r0 + quad * 4 + reg;
            if (rr >= M) continue;
            float v = acc[nt][reg];
            if (RELU) v = fmaxf(v + bias[nt * 16 + li], 0.f);
            out[(size_t)rr * ldo + nt * 16 + li] = (h16)v;
        }
    }
}

// ---- fused 4-head attention + BN + ReLU (+residual), wave/dst, f16 in ----
__global__ void attn4_bn(int N, const h16* __restrict__ XL, const h16* __restrict__ XR,
                         const float* __restrict__ att,
                         const int* __restrict__ rowstart, const int* __restrict__ deg,
                         const int* __restrict__ csr_src,
                         const float* __restrict__ gamma, const float* __restrict__ beta,
                         const float* __restrict__ mean, const float* __restrict__ var,
                         const float* __restrict__ bias, const float* __restrict__ resid,
                         float* __restrict__ out, h16* __restrict__ outb) {
    int d = blockIdx.x * (blockDim.x >> 6) + (threadIdx.x >> 6);
    int lane = threadIdx.x & 63;
    if (d >= N) return;
    half4v bv = *(const half4v*)(XR + (size_t)d * 256 + lane * 4);
    float4 wf = ((const float4*)att)[lane];
    half2v b0 = bv.xy, b1 = bv.zw;
    half2v w0 = { (h16)wf.x, (h16)wf.y };
    half2v w1 = { (h16)wf.z, (h16)wf.w };
    const h16 k02 = (h16)0.2f;

    auto edge_logit = [&](half4v xv) -> float {
        half2v e0 = xv.xy + b0, e1 = xv.zw + b1;
        half2v l0 = __builtin_elementwise_max(e0, e0 * k02);
        half2v l1 = __builtin_elementwise_max(e1, e1 * k02);
        half2v qd = l0 * w0 + l1 * w1;          // v_pk_mul + v_pk_fma
        float q = (float)qd.x + (float)qd.y;
        q += __shfl_xor(q, 1, 64); q += __shfl_xor(q, 2, 64);
        q += __shfl_xor(q, 4, 64); q += __shfl_xor(q, 8, 64);
        return q;
    };

    // self-loop initializes the online softmax state
    half4v av = *(const half4v*)(XL + (size_t)d * 256 + lane * 4);
    float m = edge_logit(av), l = 1.f;
    float4 acc = { (float)av.x, (float)av.y, (float)av.z, (float)av.w };

    int start = rowstart[d], n = deg[d];
    half4v nx = {0, 0, 0, 0};
    if (n > 0) nx = *(const half4v*)(XL + (size_t)csr_src[start] * 256 + lane * 4);
    for (int i = 0; i < n; ++i) {
        half4v xc = nx;
        if (i + 1 < n) nx = *(const half4v*)(XL + (size_t)csr_src[start + i + 1] * 256 + lane * 4);
        float q = edge_logit(xc);
        float mn = fmaxf(m, q);
        float sc = __expf(m - mn);
        float eq = __expf(q - mn);
        l = l * sc + eq;
        acc.x = acc.x * sc + eq * (float)xc.x;
        acc.y = acc.y * sc + eq * (float)xc.y;
        acc.z = acc.z * sc + eq * (float)xc.z;
        acc.w = acc.w * sc + eq * (float)xc.w;
        m = mn;
    }
    float inv = 1.f / l;
    float4 g  = ((const float4*)gamma)[lane];
    float4 be = ((const float4*)beta)[lane];
    float4 mu = ((const float4*)mean)[lane];
    float4 va = ((const float4*)var)[lane];
    float4 bi = ((const float4*)bias)[lane];
    float4 sc4, sh4;
    sc4.x = g.x * rsqrtf(va.x + 1e-5f); sh4.x = (bi.x - mu.x) * sc4.x + be.x;
    sc4.y = g.y * rsqrtf(va.y + 1e-5f); sh4.y = (bi.y - mu.y) * sc4.y + be.y;
    sc4.z = g.z * rsqrtf(va.z + 1e-5f); sh4.z = (bi.z - mu.z) * sc4.z + be.z;
    sc4.w = g.w * rsqrtf(va.w + 1e-5f); sh4.w = (bi.w - mu.w) * sc4.w + be.w;
    float4 o;
    o.x = fmaxf(acc.x * inv * sc4.x + sh4.x, 0.f);
    o.y = fmaxf(acc.y * inv * sc4.y + sh4.y, 0.f);
    o.z = fmaxf(acc.z * inv * sc4.z + sh4.z, 0.f);
    o.w = fmaxf(acc.w * inv * sc4.w + sh4.w, 0.f);
    if (resid) {
        float4 rv = *(const float4*)(resid + (size_t)d * 256 + lane * 4);
        o.x += rv.x; o.y += rv.y; o.z += rv.z; o.w += rv.w;
    }
    *(float4*)(out + (size_t)d * 256 + lane * 4) = o;
    if (outb) {
        half4v ob = { (h16)o.x, (h16)o.y, (h16)o.z, (h16)o.w };
        *(half4v*)(outb + (size_t)d * 256 + lane * 4) = ob;
    }
}

// ---- layer 2 projections: 16 lanes per node; each lane covers 16 of K=256 ----
__global__ void gemm2_wave(const float* __restrict__ X, const float* __restrict__ Wl,
                           const float* __restrict__ Wr, float* __restrict__ xl2,
                           float* __restrict__ xr2, int N) {
    int t = blockIdx.x * blockDim.x + threadIdx.x;
    int n = t >> 4;
    int sl = t & 15;
    if (n >= N) return;
    const float4* Xr = (const float4*)(X + (size_t)n * 256);
    const float4* Wl4 = (const float4*)Wl;
    const float4* Wr4 = (const float4*)Wr;
    float l0 = 0.f, l1 = 0.f, r0 = 0.f, r1 = 0.f;
#pragma unroll
    for (int j = 0; j < 4; ++j) {
        int idx = sl + j * 16;
        float4 xv = Xr[idx];
        float4 wa = Wl4[idx * 2];
        float4 wb = Wl4[idx * 2 + 1];
        l0 += xv.x * wa.x + xv.y * wa.z + xv.z * wb.x + xv.w * wb.z;
        l1 += xv.x * wa.y + xv.y * wa.w + xv.z * wb.y + xv.w * wb.w;
        wa = Wr4[idx * 2]; wb = Wr4[idx * 2 + 1];
        r0 += xv.x * wa.x + xv.y * wa.z + xv.z * wb.x + xv.w * wb.z;
        r1 += xv.x * wa.y + xv.y * wa.w + xv.z * wb.y + xv.w * wb.w;
    }
#pragma unroll
    for (int off = 1; off < 16; off <<= 1) {
        l0 += __shfl_xor(l0, off, 64);
        l1 += __shfl_xor(l1, off, 64);
        r0 += __shfl_xor(r0, off, 64);
        r1 += __shfl_xor(r1, off, 64);
    }
    if (sl == 0) {
        xl2[n * 2] = l0; xl2[n * 2 + 1] = l1;
        xr2[n * 2] = r0; xr2[n * 2 + 1] = r1;
    }
}

// ---- fused layer-2 attention (1 head, C=2) + log_softmax, thread/dst ----
__global__ void attn1_fused(int N, const float* __restrict__ xl2, const float* __restrict__ xr2,
                            const float* __restrict__ att, const float* __restrict__ bias,
                            const int* __restrict__ rowstart, const int* __restrict__ deg,
                            const int* __restrict__ csr_src, float* __restrict__ out) {
    int d = blockIdx.x * blockDim.x + threadIdx.x;
    if (d >= N) return;
    float a0 = att[0], a1 = att[1];
    float b0 = xr2[d * 2], b1 = xr2[d * 2 + 1];
    float s0 = xl2[d * 2], s1 = xl2[d * 2 + 1];
    float p = lrelu(s0 + b0) * a0 + lrelu(s1 + b1) * a1;
    float m = p, l = 1.f, ac0 = s0, ac1 = s1;
    int st = rowstart[d], n = deg[d];
    float nx0 = 0.f, nx1 = 0.f;
    if (n > 0) {
        int s = csr_src[st];
        nx0 = xl2[s * 2]; nx1 = xl2[s * 2 + 1];
    }
    for (int i = 0; i < n; ++i) {
        float x0 = nx0, x1 = nx1;
        if (i + 1 < n) {
            int s = csr_src[st + i + 1];
            nx0 = xl2[s * 2]; nx1 = xl2[s * 2 + 1];
        }
        float q = lrelu(x0 + b0) * a0 + lrelu(x1 + b1) * a1;
        float mn = fmaxf(m, q);
        float sc = __expf(m - mn), eq = __expf(q - mn);
        l = l * sc + eq;
        ac0 = ac0 * sc + eq * x0;
        ac1 = ac1 * sc + eq * x1;
        m = mn;
    }
    float inv = 1.f / l;
    float v0 = ac0 * inv + bias[0];
    float v1 = ac1 * inv + bias[1];
    float mx = fmaxf(v0, v1);
    float lse = mx + logf(__expf(v0 - mx) + __expf(v1 - mx));
    out[d * 2] = v0 - lse;
    out[d * 2 + 1] = v1 - lse;
}

extern "C" void kernel_launch(void* const* d_in, const int* in_sizes, int n_in,
                              void* d_out, int out_size, void* d_ws, size_t ws_size,
                              hipStream_t stream) {
    const float* x        = (const float*)d_in[0];
    const int*   ei       = (const int*)  d_in[1];
    const float* W_in     = (const float*)d_in[2];
    const float* b_in     = (const float*)d_in[3];
    const float* Wl0      = (const float*)d_in[4];
    const float* Wr0      = (const float*)d_in[5];
    const float* att0     = (const float*)d_in[6];
    const float* bias0    = (const float*)d_in[7];
    const float* Wl1      = (const float*)d_in[8];
    const float* Wr1      = (const float*)d_in[9];
    const float* att1     = (const float*)d_in[10];
    const float* bias1    = (const float*)d_in[11];
    const float* Wl2      = (const float*)d_in[12];
    const float* Wr2      = (const float*)d_in[13];
    const float* att2     = (const float*)d_in[14];
    const float* bias2    = (const float*)d_in[15];
    const float* bn_gamma = (const float*)d_in[16];
    const float* bn_beta  = (const float*)d_in[17];
    const float* bn_mean  = (const float*)d_in[18];
    const float* bn_var   = (const float*)d_in[19];

    const int N  = in_sizes[0] / 128;
    const int E  = in_sizes[1] / 2;
    const int NB = (N + 255) / 256;

    float* ws = (float*)d_ws;
    size_t off = 0;
    float* C    = ws + off; off += (size_t)N * 256;     // layer0 out / residual (f32)
    float* D    = ws + off; off += (size_t)N * 256;     // layer1 out (f32)
    float* XL2  = ws + off; off += (size_t)N * 2;
    float* XR2  = ws + off; off += (size_t)N * 2;
    h16* Ah   = (h16*)(ws + off); off += (size_t)N * 128;  // f16 xl [N,256]
    h16* Bh   = (h16*)(ws + off); off += (size_t)N * 128;  // f16 xr [N,256]
    h16* Ch   = (h16*)(ws + off); off += (size_t)N * 128;  // f16 copy of C
    h16* H0h  = (h16*)(ws + off); off += (size_t)N * 32;   // f16 h0 [N,64]
    h16* xh   = (h16*)(ws + off); off += (size_t)N * 64;   // f16 x  [N,128]
    h16* Wp_in = (h16*)(ws + off); off += 4096;    // 128*64
    h16* Wp_l0 = (h16*)(ws + off); off += 8192;    // 64*256
    h16* Wp_r0 = (h16*)(ws + off); off += 8192;
    h16* Wp_l1 = (h16*)(ws + off); off += 32768;   // 256*256
    h16* Wp_r1 = (h16*)(ws + off); off += 32768;
    int* ip = (int*)(ws + off);
    int* deg      = ip;              ip += N;
    int* rowstart = ip;              ip += N;
    int* cursor   = ip;              ip += N;
    int* bsum     = ip;              ip += NB;
    int* csr_src  = ip;              ip += E;

    // ---- CSR build (parallel scan) ----
    zero_int<<<(N + 255) / 256, 256, 0, stream>>>(deg, N);
    hist_dst<<<(E + 255) / 256, 256, 0, stream>>>(ei, E, deg);
    scan_blk<<<NB, 256, 0, stream>>>(deg, rowstart, bsum, N);
    scan_off<<<1, 256, 0, stream>>>(bsum, NB);
    add_off<<<NB, 256, 0, stream>>>(bsum, rowstart, cursor, N);
    scatter_src<<<(E + 255) / 256, 256, 0, stream>>>(ei, E, cursor, csr_src);

    // ---- conversions & weight packing ----
    f32_to_f16_v<<<(N * 32 + 255) / 256, 256, 0, stream>>>((const float4*)x, (half4v*)xh, N * 32);
    pack_all<<<(172032 + 255) / 256, 256, 0, stream>>>(W_in, Wl0, Wr0, Wl1, Wr1,
                                                       Wp_in, Wp_l0, Wp_r0, Wp_l1, Wp_r1);

    const int GBM = (N + 63) / 64;

    // h0 = relu(x @ W_in + b_in)  -> f16
    gemm_mfma<4, 4, true><<<GBM, 256, 0, stream>>>(xh, Wp_in, b_in, H0h, N);

    // -------- layer 0 --------
    gemm_mfma<2, 16, false><<<GBM, 256, 0, stream>>>(H0h, Wp_l0, nullptr, Ah, N);
    gemm_mfma<2, 16, false><<<GBM, 256, 0, stream>>>(H0h, Wp_r0, nullptr, Bh, N);
    attn4_bn<<<(N + 3) / 4, 256, 0, stream>>>(N, Ah, Bh, att0, rowstart, deg, csr_src,
                                              bn_gamma, bn_beta, bn_mean, bn_var,
                                              bias0, nullptr, C, Ch);

    // -------- layer 1 (residual) --------
    gemm_mfma<8, 16, false><<<GBM, 256, 0, stream>>>(Ch, Wp_l1, nullptr, Ah, N);
    gemm_mfma<8, 16, false><<<GBM, 256, 0, stream>>>(Ch, Wp_r1, nullptr, Bh, N);
    attn4_bn<<<(N + 3) / 4, 256, 0, stream>>>(N, Ah, Bh, att1, rowstart, deg, csr_src,
                                              bn_gamma + 256, bn_beta + 256, bn_mean + 256,
                                              bn_var + 256, bias1, C, D, nullptr);

    // -------- layer 2 (1 head, C=2) + log_softmax --------
    gemm2_wave<<<(N * 16 + 255) / 256, 256, 0, stream>>>(D, Wl2, Wr2, XL2, XR2, N);
    attn1_fused<<<(N + 255) / 256, 256, 0, stream>>>(N, XL2, XR2, att2, bias2,
                                                     rowstart, deg, csr_src, (float*)d_out);
}

// Round 9
// 550.756 us; speedup vs baseline: 14.1056x; 1.0826x over previous
//
#include <hip/hip_runtime.h>
#include <hip/hip_bf16.h>
#include <math.h>

// ---------------------------------------------------------------------------
// GATv2 3-layer GNN. CSR-by-dst on-device (parallel scan); f16 MFMA GEMMs
// (f32 accumulate); fused online-softmax attention, 4-edge-batched to break
// the serial dependence chain; BN/ReLU/residual epilogue fused.
// ---------------------------------------------------------------------------

using h16     = _Float16;
using half2v  = __attribute__((ext_vector_type(2))) h16;
using half4v  = __attribute__((ext_vector_type(4))) h16;
using half8   = __attribute__((ext_vector_type(8))) h16;
using floatx4 = __attribute__((ext_vector_type(4))) float;

__device__ __forceinline__ float lrelu(float x) { return x > 0.f ? x : 0.2f * x; }

// ---------------- CSR build ----------------
__global__ void zero_int(int* __restrict__ p, int n) {
    int t = blockIdx.x * blockDim.x + threadIdx.x;
    if (t < n) p[t] = 0;
}

__global__ void hist_dst(const int* __restrict__ ei, int E, int* __restrict__ deg) {
    int e = blockIdx.x * blockDim.x + threadIdx.x;
    if (e < E) atomicAdd(&deg[ei[E + e]], 1);
}

__global__ __launch_bounds__(256) void scan_blk(const int* __restrict__ deg,
                                                int* __restrict__ rowstart,
                                                int* __restrict__ bsum, int N) {
    int t = blockIdx.x * 256 + threadIdx.x;
    int lane = threadIdx.x & 63, wid = threadIdx.x >> 6;
    int v = (t < N) ? deg[t] : 0;
    int x = v;
#pragma unroll
    for (int off = 1; off < 64; off <<= 1) {
        int y = __shfl_up(x, off, 64);
        if (lane >= off) x += y;
    }
    __shared__ int wsum[4];
    if (lane == 63) wsum[wid] = x;
    __syncthreads();
    int add = 0;
#pragma unroll
    for (int w = 0; w < 4; ++w) if (w < wid) add += wsum[w];
    int incl = x + add;
    if (t < N) rowstart[t] = incl - v;
    if (threadIdx.x == 255) bsum[blockIdx.x] = incl;
}

__global__ __launch_bounds__(256) void scan_off(int* __restrict__ bsum, int NB) {
    int t = threadIdx.x;
    int lane = t & 63, wid = t >> 6;
    int v = (t < NB) ? bsum[t] : 0;
    int x = v;
#pragma unroll
    for (int off = 1; off < 64; off <<= 1) {
        int y = __shfl_up(x, off, 64);
        if (lane >= off) x += y;
    }
    __shared__ int wsum[4];
    if (lane == 63) wsum[wid] = x;
    __syncthreads();
    int add = 0;
#pragma unroll
    for (int w = 0; w < 4; ++w) if (w < wid) add += wsum[w];
    if (t < NB) bsum[t] = x + add - v;
}

__global__ void add_off(const int* __restrict__ bsum, int* __restrict__ rowstart,
                        int* __restrict__ cursor, int N) {
    int t = blockIdx.x * 256 + threadIdx.x;
    if (t >= N) return;
    int r = rowstart[t] + bsum[blockIdx.x];
    rowstart[t] = r;
    cursor[t] = r;
}

__global__ void scatter_src(const int* __restrict__ ei, int E,
                            int* __restrict__ cursor, int* __restrict__ csr_src) {
    int e = blockIdx.x * blockDim.x + threadIdx.x;
    if (e >= E) return;
    int d = ei[E + e];
    int pos = atomicAdd(&cursor[d], 1);
    csr_src[pos] = ei[e];
}

// ---------------- f32 -> f16 conversions / weight packing ----------------
__global__ void f32_to_f16_v(const float4* __restrict__ in, half4v* __restrict__ out, int n4) {
    int t = blockIdx.x * blockDim.x + threadIdx.x;
    if (t >= n4) return;
    float4 v = in[t];
    half4v o = { (h16)v.x, (h16)v.y, (h16)v.z, (h16)v.w };
    out[t] = o;
}

// Pack element t of W [K][NC] into MFMA B-fragment order (f16)
__device__ __forceinline__ void pack_one(const float* __restrict__ W,
                                         h16* __restrict__ Wp,
                                         int t, int K, int NC) {
    int j = t & 7;
    int l = (t >> 3) & 63;
    int rest = t >> 9;
    int KC = K >> 5;
    int kc = rest % KC;
    int nt = rest / KC;
    int row = kc * 32 + (l >> 4) * 8 + j;
    int col = nt * 16 + (l & 15);
    Wp[t] = (h16)W[(size_t)row * NC + col];
}

__global__ void pack_all(const float* __restrict__ W_in,
                         const float* __restrict__ Wl0, const float* __restrict__ Wr0,
                         const float* __restrict__ Wl1, const float* __restrict__ Wr1,
                         h16* __restrict__ P_in,
                         h16* __restrict__ P_l0, h16* __restrict__ P_r0,
                         h16* __restrict__ P_l1, h16* __restrict__ P_r1) {
    int t = blockIdx.x * blockDim.x + threadIdx.x;
    if (t < 8192)        pack_one(W_in, P_in, t, 128, 64);
    else if (t < 24576)  pack_one(Wl0, P_l0, t - 8192, 64, 256);
    else if (t < 40960)  pack_one(Wr0, P_r0, t - 24576, 64, 256);
    else if (t < 106496) pack_one(Wl1, P_l1, t - 40960, 256, 256);
    else if (t < 172032) pack_one(Wr1, P_r1, t - 106496, 256, 256);
}

// ---------------- MFMA GEMM: out[M][ldo] = maybe_relu(bias + Xh @ W) -------
template<int KC, int NTILES, bool RELU>
__global__ __launch_bounds__(256) void gemm_mfma(
        const h16* __restrict__ Xh, const h16* __restrict__ Wp,
        const float* __restrict__ bias, h16* __restrict__ out, int M) {
    constexpr int K = KC * 32;
    constexpr int ldo = NTILES * 16;
    const int wid  = threadIdx.x >> 6;
    const int lane = threadIdx.x & 63;
    const int quad = lane >> 4, li = lane & 15;
    const int r0 = blockIdx.x * 64 + wid * 16;
    int arow = r0 + li; if (arow >= M) arow = M - 1;      // clamp (stores guarded)
    const half8* A8 = (const half8*)Xh + (size_t)arow * (K / 8) + quad;
    const half8* W8 = (const half8*)Wp;
    floatx4 acc[NTILES];
#pragma unroll
    for (int t = 0; t < NTILES; ++t) acc[t] = (floatx4){0.f, 0.f, 0.f, 0.f};
#pragma unroll
    for (int kc = 0; kc < KC; ++kc) {
        half8 a = A8[kc * 4];
#pragma unroll
        for (int nt = 0; nt < NTILES; ++nt) {
            half8 b = W8[(size_t)(nt * KC + kc) * 64 + lane];
            acc[nt] = __builtin_amdgcn_mfma_f32_16x16x32_f16(a, b, acc[nt], 0, 0, 0);
        }
    }
#pragma unroll
    for (int nt = 0; nt < NTILES; ++nt) {
#pragma unroll
        for (int reg = 0; reg < 4; ++reg) {
            int rr = r0 + quad * 4 + reg;
            if (rr >= M) continue;
            float v = acc[nt][reg];
            if (RELU) v = fmaxf(v + bias[nt * 16 + li], 0.f);
            out[(size_t)rr * ldo + nt * 16 + li] = (h16)v;
        }
    }
}

// ---- fused 4-head attention + BN + ReLU (+residual), wave/dst, f16 in ----
// Inner loop batches 4 edges to break the online-softmax dependence chain.
__global__ void attn4_bn(int N, const h16* __restrict__ XL, const h16* __restrict__ XR,
                         const float* __restrict__ att,
                         const int* __restrict__ rowstart, const int* __restrict__ deg,
                         const int* __restrict__ csr_src,
                         const float* __restrict__ gamma, const float* __restrict__ beta,
                         const float* __restrict__ mean, const float* __restrict__ var,
                         const float* __restrict__ bias, const float* __restrict__ resid,
                         float* __restrict__ out, h16* __restrict__ outb) {
    int d = blockIdx.x * (blockDim.x >> 6) + (threadIdx.x >> 6);
    int lane = threadIdx.x & 63;
    if (d >= N) return;
    half4v bv = *(const half4v*)(XR + (size_t)d * 256 + lane * 4);
    float4 wf = ((const float4*)att)[lane];
    half2v b0 = bv.xy, b1 = bv.zw;
    half2v w0 = { (h16)wf.x, (h16)wf.y };
    half2v w1 = { (h16)wf.z, (h16)wf.w };
    const h16 k02 = (h16)0.2f;

    auto edge_logit = [&](half4v xv) -> float {
        half2v e0 = xv.xy + b0, e1 = xv.zw + b1;
        half2v l0 = __builtin_elementwise_max(e0, e0 * k02);
        half2v l1 = __builtin_elementwise_max(e1, e1 * k02);
        half2v qd = l0 * w0 + l1 * w1;
        float q = (float)qd.x + (float)qd.y;
        q += __shfl_xor(q, 1, 64); q += __shfl_xor(q, 2, 64);
        q += __shfl_xor(q, 4, 64); q += __shfl_xor(q, 8, 64);
        return q;
    };

    // self-loop initializes the online softmax state
    half4v av = *(const half4v*)(XL + (size_t)d * 256 + lane * 4);
    float m = edge_logit(av), l = 1.f;
    float4 acc = { (float)av.x, (float)av.y, (float)av.z, (float)av.w };

    int start = rowstart[d], n = deg[d];
    for (int i = 0; i < n; i += 4) {
        int nm1 = n - 1;
        int s0 = csr_src[start + i];
        int s1 = csr_src[start + min(i + 1, nm1)];
        int s2 = csr_src[start + min(i + 2, nm1)];
        int s3 = csr_src[start + min(i + 3, nm1)];
        half4v x0 = *(const half4v*)(XL + (size_t)s0 * 256 + lane * 4);
        half4v x1 = *(const half4v*)(XL + (size_t)s1 * 256 + lane * 4);
        half4v x2 = *(const half4v*)(XL + (size_t)s2 * 256 + lane * 4);
        half4v x3 = *(const half4v*)(XL + (size_t)s3 * 256 + lane * 4);
        float q0 = edge_logit(x0);
        float q1 = edge_logit(x1);
        float q2 = edge_logit(x2);
        float q3 = edge_logit(x3);
        int rem = n - i;
        if (rem < 2) q1 = -INFINITY;
        if (rem < 3) q2 = -INFINITY;
        if (rem < 4) q3 = -INFINITY;
        float mn = fmaxf(fmaxf(fmaxf(q0, q1), fmaxf(q2, q3)), m);
        float sc = __expf(m - mn);
        float e0 = __expf(q0 - mn);
        float e1 = __expf(q1 - mn);
        float e2 = __expf(q2 - mn);
        float e3 = __expf(q3 - mn);
        l = l * sc + ((e0 + e1) + (e2 + e3));
        acc.x = acc.x * sc + e0 * (float)x0.x + e1 * (float)x1.x + e2 * (float)x2.x + e3 * (float)x3.x;
        acc.y = acc.y * sc + e0 * (float)x0.y + e1 * (float)x1.y + e2 * (float)x2.y + e3 * (float)x3.y;
        acc.z = acc.z * sc + e0 * (float)x0.z + e1 * (float)x1.z + e2 * (float)x2.z + e3 * (float)x3.z;
        acc.w = acc.w * sc + e0 * (float)x0.w + e1 * (float)x1.w + e2 * (float)x2.w + e3 * (float)x3.w;
        m = mn;
    }
    float inv = 1.f / l;
    float4 g  = ((const float4*)gamma)[lane];
    float4 be = ((const float4*)beta)[lane];
    float4 mu = ((const float4*)mean)[lane];
    float4 va = ((const float4*)var)[lane];
    float4 bi = ((const float4*)bias)[lane];
    float4 sc4, sh4;
    sc4.x = g.x * rsqrtf(va.x + 1e-5f); sh4.x = (bi.x - mu.x) * sc4.x + be.x;
    sc4.y = g.y * rsqrtf(va.y + 1e-5f); sh4.y = (bi.y - mu.y) * sc4.y + be.y;
    sc4.z = g.z * rsqrtf(va.z + 1e-5f); sh4.z = (bi.z - mu.z) * sc4.z + be.z;
    sc4.w = g.w * rsqrtf(va.w + 1e-5f); sh4.w = (bi.w - mu.w) * sc4.w + be.w;
    float4 o;
    o.x = fmaxf(acc.x * inv * sc4.x + sh4.x, 0.f);
    o.y = fmaxf(acc.y * inv * sc4.y + sh4.y, 0.f);
    o.z = fmaxf(acc.z * inv * sc4.z + sh4.z, 0.f);
    o.w = fmaxf(acc.w * inv * sc4.w + sh4.w, 0.f);
    if (resid) {
        float4 rv = *(const float4*)(resid + (size_t)d * 256 + lane * 4);
        o.x += rv.x; o.y += rv.y; o.z += rv.z; o.w += rv.w;
    }
    *(float4*)(out + (size_t)d * 256 + lane * 4) = o;
    if (outb) {
        half4v ob = { (h16)o.x, (h16)o.y, (h16)o.z, (h16)o.w };
        *(half4v*)(outb + (size_t)d * 256 + lane * 4) = ob;
    }
}

// ---- layer 2 projections: 16 lanes per node; each lane covers 16 of K=256 ----
__global__ void gemm2_wave(const float* __restrict__ X, const float* __restrict__ Wl,
                           const float* __restrict__ Wr, float* __restrict__ xl2,
                           float* __restrict__ xr2, int N) {
    int t = blockIdx.x * blockDim.x + threadIdx.x;
    int n = t >> 4;
    int sl = t & 15;
    if (n >= N) return;
    const float4* Xr = (const float4*)(X + (size_t)n * 256);
    const float4* Wl4 = (const float4*)Wl;
    const float4* Wr4 = (const float4*)Wr;
    float l0 = 0.f, l1 = 0.f, r0 = 0.f, r1 = 0.f;
#pragma unroll
    for (int j = 0; j < 4; ++j) {
        int idx = sl + j * 16;
        float4 xv = Xr[idx];
        float4 wa = Wl4[idx * 2];
        float4 wb = Wl4[idx * 2 + 1];
        l0 += xv.x * wa.x + xv.y * wa.z + xv.z * wb.x + xv.w * wb.z;
        l1 += xv.x * wa.y + xv.y * wa.w + xv.z * wb.y + xv.w * wb.w;
        wa = Wr4[idx * 2]; wb = Wr4[idx * 2 + 1];
        r0 += xv.x * wa.x + xv.y * wa.z + xv.z * wb.x + xv.w * wb.z;
        r1 += xv.x * wa.y + xv.y * wa.w + xv.z * wb.y + xv.w * wb.w;
    }
#pragma unroll
    for (int off = 1; off < 16; off <<= 1) {
        l0 += __shfl_xor(l0, off, 64);
        l1 += __shfl_xor(l1, off, 64);
        r0 += __shfl_xor(r0, off, 64);
        r1 += __shfl_xor(r1, off, 64);
    }
    if (sl == 0) {
        xl2[n * 2] = l0; xl2[n * 2 + 1] = l1;
        xr2[n * 2] = r0; xr2[n * 2 + 1] = r1;
    }
}

// ---- fused layer-2 attention (1 head, C=2) + log_softmax, thread/dst ----
// 4-edge batched like attn4_bn.
__global__ void attn1_fused(int N, const float* __restrict__ xl2, const float* __restrict__ xr2,
                            const float* __restrict__ att, const float* __restrict__ bias,
                            const int* __restrict__ rowstart, const int* __restrict__ deg,
                            const int* __restrict__ csr_src, float* __restrict__ out) {
    int d = blockIdx.x * blockDim.x + threadIdx.x;
    if (d >= N) return;
    float a0 = att[0], a1 = att[1];
    float b0 = xr2[d * 2], b1 = xr2[d * 2 + 1];
    float s0 = xl2[d * 2], s1 = xl2[d * 2 + 1];
    float p = lrelu(s0 + b0) * a0 + lrelu(s1 + b1) * a1;
    float m = p, l = 1.f, ac0 = s0, ac1 = s1;
    int st = rowstart[d], n = deg[d];
    for (int i = 0; i < n; i += 4) {
        int nm1 = n - 1;
        int e0i = csr_src[st + i];
        int e1i = csr_src[st + min(i + 1, nm1)];
        int e2i = csr_src[st + min(i + 2, nm1)];
        int e3i = csr_src[st + min(i + 3, nm1)];
        float x00 = xl2[e0i * 2], x01 = xl2[e0i * 2 + 1];
        float x10 = xl2[e1i * 2], x11 = xl2[e1i * 2 + 1];
        float x20 = xl2[e2i * 2], x21 = xl2[e2i * 2 + 1];
        float x30 = xl2[e3i * 2], x31 = xl2[e3i * 2 + 1];
        float q0 = lrelu(x00 + b0) * a0 + lrelu(x01 + b1) * a1;
        float q1 = lrelu(x10 + b0) * a0 + lrelu(x11 + b1) * a1;
        float q2 = lrelu(x20 + b0) * a0 + lrelu(x21 + b1) * a1;
        float q3 = lrelu(x30 + b0) * a0 + lrelu(x31 + b1) * a1;
        int rem = n - i;
        if (rem < 2) q1 = -INFINITY;
        if (rem < 3) q2 = -INFINITY;
        if (rem < 4) q3 = -INFINITY;
        float mn = fmaxf(fmaxf(fmaxf(q0, q1), fmaxf(q2, q3)), m);
        float sc = __expf(m - mn);
        float e0 = __expf(q0 - mn), e1 = __expf(q1 - mn);
        float e2 = __expf(q2 - mn), e3 = __expf(q3 - mn);
        l = l * sc + ((e0 + e1) + (e2 + e3));
        ac0 = ac0 * sc + e0 * x00 + e1 * x10 + e2 * x20 + e3 * x30;
        ac1 = ac1 * sc + e0 * x01 + e1 * x11 + e2 * x21 + e3 * x31;
        m = mn;
    }
    float inv = 1.f / l;
    float v0 = ac0 * inv + bias[0];
    float v1 = ac1 * inv + bias[1];
    float mx = fmaxf(v0, v1);
    float lse = mx + logf(__expf(v0 - mx) + __expf(v1 - mx));
    out[d * 2] = v0 - lse;
    out[d * 2 + 1] = v1 - lse;
}

extern "C" void kernel_launch(void* const* d_in, const int* in_sizes, int n_in,
                              void* d_out, int out_size, void* d_ws, size_t ws_size,
                              hipStream_t stream) {
    const float* x        = (const float*)d_in[0];
    const int*   ei       = (const int*)  d_in[1];
    const float* W_in     = (const float*)d_in[2];
    const float* b_in     = (const float*)d_in[3];
    const float* Wl0      = (const float*)d_in[4];
    const float* Wr0      = (const float*)d_in[5];
    const float* att0     = (const float*)d_in[6];
    const float* bias0    = (const float*)d_in[7];
    const float* Wl1      = (const float*)d_in[8];
    const float* Wr1      = (const float*)d_in[9];
    const float* att1     = (const float*)d_in[10];
    const float* bias1    = (const float*)d_in[11];
    const float* Wl2      = (const float*)d_in[12];
    const float* Wr2      = (const float*)d_in[13];
    const float* att2     = (const float*)d_in[14];
    const float* bias2    = (const float*)d_in[15];
    const float* bn_gamma = (const float*)d_in[16];
    const float* bn_beta  = (const float*)d_in[17];
    const float* bn_mean  = (const float*)d_in[18];
    const float* bn_var   = (const float*)d_in[19];

    const int N  = in_sizes[0] / 128;
    const int E  = in_sizes[1] / 2;
    const int NB = (N + 255) / 256;

    float* ws = (float*)d_ws;
    size_t off = 0;
    float* C    = ws + off; off += (size_t)N * 256;     // layer0 out / residual (f32)
    float* D    = ws + off; off += (size_t)N * 256;     // layer1 out (f32)
    float* XL2  = ws + off; off += (size_t)N * 2;
    float* XR2  = ws + off; off += (size_t)N * 2;
    h16* Ah   = (h16*)(ws + off); off += (size_t)N * 128;  // f16 xl [N,256]
    h16* Bh   = (h16*)(ws + off); off += (size_t)N * 128;  // f16 xr [N,256]
    h16* Ch   = (h16*)(ws + off); off += (size_t)N * 128;  // f16 copy of C
    h16* H0h  = (h16*)(ws + off); off += (size_t)N * 32;   // f16 h0 [N,64]
    h16* xh   = (h16*)(ws + off); off += (size_t)N * 64;   // f16 x  [N,128]
    h16* Wp_in = (h16*)(ws + off); off += 4096;    // 128*64
    h16* Wp_l0 = (h16*)(ws + off); off += 8192;    // 64*256
    h16* Wp_r0 = (h16*)(ws + off); off += 8192;
    h16* Wp_l1 = (h16*)(ws + off); off += 32768;   // 256*256
    h16* Wp_r1 = (h16*)(ws + off); off += 32768;
    int* ip = (int*)(ws + off);
    int* deg      = ip;              ip += N;
    int* rowstart = ip;              ip += N;
    int* cursor   = ip;              ip += N;
    int* bsum     = ip;              ip += NB;
    int* csr_src  = ip;              ip += E;

    // ---- CSR build (parallel scan) ----
    zero_int<<<(N + 255) / 256, 256, 0, stream>>>(deg, N);
    hist_dst<<<(E + 255) / 256, 256, 0, stream>>>(ei, E, deg);
    scan_blk<<<NB, 256, 0, stream>>>(deg, rowstart, bsum, N);
    scan_off<<<1, 256, 0, stream>>>(bsum, NB);
    add_off<<<NB, 256, 0, stream>>>(bsum, rowstart, cursor, N);
    scatter_src<<<(E + 255) / 256, 256, 0, stream>>>(ei, E, cursor, csr_src);

    // ---- conversions & weight packing ----
    f32_to_f16_v<<<(N * 32 + 255) / 256, 256, 0, stream>>>((const float4*)x, (half4v*)xh, N * 32);
    pack_all<<<(172032 + 255) / 256, 256, 0, stream>>>(W_in, Wl0, Wr0, Wl1, Wr1,
                                                       Wp_in, Wp_l0, Wp_r0, Wp_l1, Wp_r1);

    const int GBM = (N + 63) / 64;

    // h0 = relu(x @ W_in + b_in)  -> f16
    gemm_mfma<4, 4, true><<<GBM, 256, 0, stream>>>(xh, Wp_in, b_in, H0h, N);

    // -------- layer 0 --------
    gemm_mfma<2, 16, false><<<GBM, 256, 0, stream>>>(H0h, Wp_l0, nullptr, Ah, N);
    gemm_mfma<2, 16, false><<<GBM, 256, 0, stream>>>(H0h, Wp_r0, nullptr, Bh, N);
    attn4_bn<<<(N + 3) / 4, 256, 0, stream>>>(N, Ah, Bh, att0, rowstart, deg, csr_src,
                                              bn_gamma, bn_beta, bn_mean, bn_var,
                                              bias0, nullptr, C, Ch);

    // -------- layer 1 (residual) --------
    gemm_mfma<8, 16, false><<<GBM, 256, 0, stream>>>(Ch, Wp_l1, nullptr, Ah, N);
    gemm_mfma<8, 16, false><<<GBM, 256, 0, stream>>>(Ch, Wp_r1, nullptr, Bh, N);
    attn4_bn<<<(N + 3) / 4, 256, 0, stream>>>(N, Ah, Bh, att1, rowstart, deg, csr_src,
                                              bn_gamma + 256, bn_beta + 256, bn_mean + 256,
                                              bn_var + 256, bias1, C, D, nullptr);

    // -------- layer 2 (1 head, C=2) + log_softmax --------
    gemm2_wave<<<(N * 16 + 255) / 256, 256, 0, stream>>>(D, Wl2, Wr2, XL2, XR2, N);
    attn1_fused<<<(N + 255) / 256, 256, 0, stream>>>(N, XL2, XR2, att2, bias2,
                                                     rowstart, deg, csr_src, (float*)d_out);
}

// Round 10
// 528.876 us; speedup vs baseline: 14.6891x; 1.0414x over previous
//
#include <hip/hip_runtime.h>
#include <hip/hip_bf16.h>
#include <math.h>

// ---------------------------------------------------------------------------
// GATv2 3-layer GNN. CSR-by-dst on-device (parallel scan); f16 MFMA GEMMs
// (f32 accumulate, Wl/Wr fused per dispatch); fused max-free-softmax
// attention (logits provably tiny; softmax shift-invariant), 4-edge batched,
// packed-f16 pair shuffles; BN/ReLU/residual epilogue fused.
// ---------------------------------------------------------------------------

using h16     = _Float16;
using half2v  = __attribute__((ext_vector_type(2))) h16;
using half4v  = __attribute__((ext_vector_type(4))) h16;
using half8   = __attribute__((ext_vector_type(8))) h16;
using floatx4 = __attribute__((ext_vector_type(4))) float;

__device__ __forceinline__ float lrelu(float x) { return x > 0.f ? x : 0.2f * x; }

__device__ __forceinline__ half2v shfl_xor_h2(half2v v, int mask) {
    float f = __builtin_bit_cast(float, v);
    f = __shfl_xor(f, mask, 64);
    return __builtin_bit_cast(half2v, f);
}

// ---------------- CSR build ----------------
__global__ void zero_int(int* __restrict__ p, int n) {
    int t = blockIdx.x * blockDim.x + threadIdx.x;
    if (t < n) p[t] = 0;
}

__global__ void hist_dst(const int* __restrict__ ei, int E, int* __restrict__ deg) {
    int e = blockIdx.x * blockDim.x + threadIdx.x;
    if (e < E) atomicAdd(&deg[ei[E + e]], 1);
}

__global__ __launch_bounds__(256) void scan_blk(const int* __restrict__ deg,
                                                int* __restrict__ rowstart,
                                                int* __restrict__ bsum, int N) {
    int t = blockIdx.x * 256 + threadIdx.x;
    int lane = threadIdx.x & 63, wid = threadIdx.x >> 6;
    int v = (t < N) ? deg[t] : 0;
    int x = v;
#pragma unroll
    for (int off = 1; off < 64; off <<= 1) {
        int y = __shfl_up(x, off, 64);
        if (lane >= off) x += y;
    }
    __shared__ int wsum[4];
    if (lane == 63) wsum[wid] = x;
    __syncthreads();
    int add = 0;
#pragma unroll
    for (int w = 0; w < 4; ++w) if (w < wid) add += wsum[w];
    int incl = x + add;
    if (t < N) rowstart[t] = incl - v;
    if (threadIdx.x == 255) bsum[blockIdx.x] = incl;
}

__global__ __launch_bounds__(256) void scan_off(int* __restrict__ bsum, int NB) {
    int t = threadIdx.x;
    int lane = t & 63, wid = t >> 6;
    int v = (t < NB) ? bsum[t] : 0;
    int x = v;
#pragma unroll
    for (int off = 1; off < 64; off <<= 1) {
        int y = __shfl_up(x, off, 64);
        if (lane >= off) x += y;
    }
    __shared__ int wsum[4];
    if (lane == 63) wsum[wid] = x;
    __syncthreads();
    int add = 0;
#pragma unroll
    for (int w = 0; w < 4; ++w) if (w < wid) add += wsum[w];
    if (t < NB) bsum[t] = x + add - v;
}

__global__ void add_off(const int* __restrict__ bsum, int* __restrict__ rowstart,
                        int* __restrict__ cursor, int N) {
    int t = blockIdx.x * 256 + threadIdx.x;
    if (t >= N) return;
    int r = rowstart[t] + bsum[blockIdx.x];
    rowstart[t] = r;
    cursor[t] = r;
}

__global__ void scatter_src(const int* __restrict__ ei, int E,
                            int* __restrict__ cursor, int* __restrict__ csr_src) {
    int e = blockIdx.x * blockDim.x + threadIdx.x;
    if (e >= E) return;
    int d = ei[E + e];
    int pos = atomicAdd(&cursor[d], 1);
    csr_src[pos] = ei[e];
}

// ---------------- weight packing + x conversion (one launch) ----------------
__device__ __forceinline__ void pack_one(const float* __restrict__ W,
                                         h16* __restrict__ Wp,
                                         int t, int K, int NC) {
    int j = t & 7;
    int l = (t >> 3) & 63;
    int rest = t >> 9;
    int KC = K >> 5;
    int kc = rest % KC;
    int nt = rest / KC;
    int row = kc * 32 + (l >> 4) * 8 + j;
    int col = nt * 16 + (l & 15);
    Wp[t] = (h16)W[(size_t)row * NC + col];
}

__global__ void pack_all(const float* __restrict__ W_in,
                         const float* __restrict__ Wl0, const float* __restrict__ Wr0,
                         const float* __restrict__ Wl1, const float* __restrict__ Wr1,
                         h16* __restrict__ P_in,
                         h16* __restrict__ P_l0, h16* __restrict__ P_r0,
                         h16* __restrict__ P_l1, h16* __restrict__ P_r1,
                         const float4* __restrict__ x, half4v* __restrict__ xh, int n4) {
    int t = blockIdx.x * blockDim.x + threadIdx.x;
    if (t < 8192)        pack_one(W_in, P_in, t, 128, 64);
    else if (t < 24576)  pack_one(Wl0, P_l0, t - 8192, 64, 256);
    else if (t < 40960)  pack_one(Wr0, P_r0, t - 24576, 64, 256);
    else if (t < 106496) pack_one(Wl1, P_l1, t - 40960, 256, 256);
    else if (t < 172032) pack_one(Wr1, P_r1, t - 106496, 256, 256);
    else {
        int u = t - 172032;
        if (u < n4) {
            float4 v = x[u];
            half4v o = { (h16)v.x, (h16)v.y, (h16)v.z, (h16)v.w };
            xh[u] = o;
        }
    }
}

// ---------------- MFMA GEMM (single): out = relu(bias + Xh @ W) ------------
template<int KC, int NTILES, bool RELU>
__global__ __launch_bounds__(256) void gemm_mfma(
        const h16* __restrict__ Xh, const h16* __restrict__ Wp,
        const float* __restrict__ bias, h16* __restrict__ out, int M) {
    constexpr int K = KC * 32;
    constexpr int ldo = NTILES * 16;
    const int wid  = threadIdx.x >> 6;
    const int lane = threadIdx.x & 63;
    const int quad = lane >> 4, li = lane & 15;
    const int r0 = blockIdx.x * 64 + wid * 16;
    int arow = r0 + li; if (arow >= M) arow = M - 1;
    const half8* A8 = (const half8*)Xh + (size_t)arow * (K / 8) + quad;
    const half8* W8 = (const half8*)Wp;
    floatx4 acc[NTILES];
#pragma unroll
    for (int t = 0; t < NTILES; ++t) acc[t] = (floatx4){0.f, 0.f, 0.f, 0.f};
#pragma unroll
    for (int kc = 0; kc < KC; ++kc) {
        half8 a = A8[kc * 4];
#pragma unroll
        for (int nt = 0; nt < NTILES; ++nt) {
            half8 b = W8[(size_t)(nt * KC + kc) * 64 + lane];
            acc[nt] = __builtin_amdgcn_mfma_f32_16x16x32_f16(a, b, acc[nt], 0, 0, 0);
        }
    }
#pragma unroll
    for (int nt = 0; nt < NTILES; ++nt) {
#pragma unroll
        for (int reg = 0; reg < 4; ++reg) {
            int rr = r0 + quad * 4 + reg;
            if (rr >= M) continue;
            float v = acc[nt][reg];
            if (RELU) v = fmaxf(v + bias[nt * 16 + li], 0.f);
            out[(size_t)rr * ldo + nt * 16 + li] = (h16)v;
        }
    }
}

// ---------------- MFMA GEMM (dual): blockIdx.y picks Wl/Wr -----------------
template<int KC, int NTILES>
__global__ __launch_bounds__(256) void gemm_mfma2(
        const h16* __restrict__ Xh, const h16* __restrict__ Wp0, const h16* __restrict__ Wp1,
        h16* __restrict__ out0, h16* __restrict__ out1, int M) {
    constexpr int K = KC * 32;
    constexpr int ldo = NTILES * 16;
    const h16* Wp = blockIdx.y ? Wp1 : Wp0;
    h16* out = blockIdx.y ? out1 : out0;
    const int wid  = threadIdx.x >> 6;
    const int lane = threadIdx.x & 63;
    const int quad = lane >> 4, li = lane & 15;
    const int r0 = blockIdx.x * 64 + wid * 16;
    int arow = r0 + li; if (arow >= M) arow = M - 1;
    const half8* A8 = (const half8*)Xh + (size_t)arow * (K / 8) + quad;
    const half8* W8 = (const half8*)Wp;
    floatx4 acc[NTILES];
#pragma unroll
    for (int t = 0; t < NTILES; ++t) acc[t] = (floatx4){0.f, 0.f, 0.f, 0.f};
#pragma unroll
    for (int kc = 0; kc < KC; ++kc) {
        half8 a = A8[kc * 4];
#pragma unroll
        for (int nt = 0; nt < NTILES; ++nt) {
            half8 b = W8[(size_t)(nt * KC + kc) * 64 + lane];
            acc[nt] = __builtin_amdgcn_mfma_f32_16x16x32_f16(a, b, acc[nt], 0, 0, 0);
        }
    }
#pragma unroll
    for (int nt = 0; nt < NTILES; ++nt) {
#pragma unroll
        for (int reg = 0; reg < 4; ++reg) {
            int rr = r0 + quad * 4 + reg;
            if (rr >= M) continue;
            out[(size_t)rr * ldo + nt * 16 + li] = (h16)acc[nt][reg];
        }
    }
}

// ---- fused 4-head attention + BN + ReLU (+residual), wave/dst, f16 in -----
// Max-free softmax (logits are O(0.5) by construction; softmax is shift-
// invariant and f32 exp is safe); 4-edge batch; packed-f16 pair shuffles.
__global__ void attn4_bn(int N, const h16* __restrict__ XL, const h16* __restrict__ XR,
                         const float* __restrict__ att,
                         const int* __restrict__ rowstart, const int* __restrict__ deg,
                         const int* __restrict__ csr_src,
                         const float* __restrict__ gamma, const float* __restrict__ beta,
                         const float* __restrict__ mean, const float* __restrict__ var,
                         const float* __restrict__ bias, const float* __restrict__ resid,
                         float* __restrict__ out, h16* __restrict__ outb) {
    int d = blockIdx.x * (blockDim.x >> 6) + (threadIdx.x >> 6);
    int lane = threadIdx.x & 63;
    if (d >= N) return;
    half4v bv = *(const half4v*)(XR + (size_t)d * 256 + lane * 4);
    float4 wf = ((const float4*)att)[lane];
    half2v b0 = bv.xy, b1 = bv.zw;
    half2v w0 = { (h16)wf.x, (h16)wf.y };
    half2v w1 = { (h16)wf.z, (h16)wf.w };
    const h16 k02 = (h16)0.2f;

    // per-lane f16 partial of the head dot-product
    auto edge_part = [&](half4v xv) -> h16 {
        half2v e0 = xv.xy + b0, e1 = xv.zw + b1;
        half2v l0 = __builtin_elementwise_max(e0, e0 * k02);
        half2v l1 = __builtin_elementwise_max(e1, e1 * k02);
        half2v qd = l0 * w0 + l1 * w1;
        return qd.x + qd.y;
    };

    // self-loop (scalar reduce, once)
    half4v av = *(const half4v*)(XL + (size_t)d * 256 + lane * 4);
    float p = (float)edge_part(av);
    p += __shfl_xor(p, 1, 64); p += __shfl_xor(p, 2, 64);
    p += __shfl_xor(p, 4, 64); p += __shfl_xor(p, 8, 64);
    float es = __expf(p);
    float l = es;
    float4 acc = { es * (float)av.x, es * (float)av.y, es * (float)av.z, es * (float)av.w };

    int start = rowstart[d], n = deg[d];
    for (int i = 0; i < n; i += 4) {
        int nm1 = n - 1;
        int s0 = csr_src[start + i];
        int s1 = csr_src[start + min(i + 1, nm1)];
        int s2 = csr_src[start + min(i + 2, nm1)];
        int s3 = csr_src[start + min(i + 3, nm1)];
        half4v x0 = *(const half4v*)(XL + (size_t)s0 * 256 + lane * 4);
        half4v x1 = *(const half4v*)(XL + (size_t)s1 * 256 + lane * 4);
        half4v x2 = *(const half4v*)(XL + (size_t)s2 * 256 + lane * 4);
        half4v x3 = *(const half4v*)(XL + (size_t)s3 * 256 + lane * 4);
        half2v p01 = { edge_part(x0), edge_part(x1) };
        half2v p23 = { edge_part(x2), edge_part(x3) };
#pragma unroll
        for (int s = 1; s < 16; s <<= 1) {
            p01 += shfl_xor_h2(p01, s);
            p23 += shfl_xor_h2(p23, s);
        }
        int rem = n - i;
        float e0 = __expf((float)p01.x);
        float e1 = (rem > 1) ? __expf((float)p01.y) : 0.f;
        float e2 = (rem > 2) ? __expf((float)p23.x) : 0.f;
        float e3 = (rem > 3) ? __expf((float)p23.y) : 0.f;
        l += (e0 + e1) + (e2 + e3);
        acc.x += e0 * (float)x0.x + e1 * (float)x1.x + e2 * (float)x2.x + e3 * (float)x3.x;
        acc.y += e0 * (float)x0.y + e1 * (float)x1.y + e2 * (float)x2.y + e3 * (float)x3.y;
        acc.z += e0 * (float)x0.z + e1 * (float)x1.z + e2 * (float)x2.z + e3 * (float)x3.z;
        acc.w += e0 * (float)x0.w + e1 * (float)x1.w + e2 * (float)x2.w + e3 * (float)x3.w;
    }
    float inv = 1.f / l;
    float4 g  = ((const float4*)gamma)[lane];
    float4 be = ((const float4*)beta)[lane];
    float4 mu = ((const float4*)mean)[lane];
    float4 va = ((const float4*)var)[lane];
    float4 bi = ((const float4*)bias)[lane];
    float4 sc4, sh4;
    sc4.x = g.x * rsqrtf(va.x + 1e-5f); sh4.x = (bi.x - mu.x) * sc4.x + be.x;
    sc4.y = g.y * rsqrtf(va.y + 1e-5f); sh4.y = (bi.y - mu.y) * sc4.y + be.y;
    sc4.z = g.z * rsqrtf(va.z + 1e-5f); sh4.z = (bi.z - mu.z) * sc4.z + be.z;
    sc4.w = g.w * rsqrtf(va.w + 1e-5f); sh4.w = (bi.w - mu.w) * sc4.w + be.w;
    float4 o;
    o.x = fmaxf(acc.x * inv * sc4.x + sh4.x, 0.f);
    o.y = fmaxf(acc.y * inv * sc4.y + sh4.y, 0.f);
    o.z = fmaxf(acc.z * inv * sc4.z + sh4.z, 0.f);
    o.w = fmaxf(acc.w * inv * sc4.w + sh4.w, 0.f);
    if (resid) {
        float4 rv = *(const float4*)(resid + (size_t)d * 256 + lane * 4);
        o.x += rv.x; o.y += rv.y; o.z += rv.z; o.w += rv.w;
    }
    *(float4*)(out + (size_t)d * 256 + lane * 4) = o;
    if (outb) {
        half4v ob = { (h16)o.x, (h16)o.y, (h16)o.z, (h16)o.w };
        *(half4v*)(outb + (size_t)d * 256 + lane * 4) = ob;
    }
}

// ---- layer 2 projections: 16 lanes per node; each lane covers 16 of K=256 ----
__global__ void gemm2_wave(const float* __restrict__ X, const float* __restrict__ Wl,
                           const float* __restrict__ Wr, float* __restrict__ xl2,
                           float* __restrict__ xr2, int N) {
    int t = blockIdx.x * blockDim.x + threadIdx.x;
    int n = t >> 4;
    int sl = t & 15;
    if (n >= N) return;
    const float4* Xr = (const float4*)(X + (size_t)n * 256);
    const float4* Wl4 = (const float4*)Wl;
    const float4* Wr4 = (const float4*)Wr;
    float l0 = 0.f, l1 = 0.f, r0 = 0.f, r1 = 0.f;
#pragma unroll
    for (int j = 0; j < 4; ++j) {
        int idx = sl + j * 16;
        float4 xv = Xr[idx];
        float4 wa = Wl4[idx * 2];
        float4 wb = Wl4[idx * 2 + 1];
        l0 += xv.x * wa.x + xv.y * wa.z + xv.z * wb.x + xv.w * wb.z;
        l1 += xv.x * wa.y + xv.y * wa.w + xv.z * wb.y + xv.w * wb.w;
        wa = Wr4[idx * 2]; wb = Wr4[idx * 2 + 1];
        r0 += xv.x * wa.x + xv.y * wa.z + xv.z * wb.x + xv.w * wb.z;
        r1 += xv.x * wa.y + xv.y * wa.w + xv.z * wb.y + xv.w * wb.w;
    }
#pragma unroll
    for (int off = 1; off < 16; off <<= 1) {
        l0 += __shfl_xor(l0, off, 64);
        l1 += __shfl_xor(l1, off, 64);
        r0 += __shfl_xor(r0, off, 64);
        r1 += __shfl_xor(r1, off, 64);
    }
    if (sl == 0) {
        xl2[n * 2] = l0; xl2[n * 2 + 1] = l1;
        xr2[n * 2] = r0; xr2[n * 2 + 1] = r1;
    }
}

// ---- fused layer-2 attention (1 head, C=2) + log_softmax, 16 lanes/dst ----
__global__ void attn1_16(int N, const float* __restrict__ xl2, const float* __restrict__ xr2,
                         const float* __restrict__ att, const float* __restrict__ bias,
                         const int* __restrict__ rowstart, const int* __restrict__ deg,
                         const int* __restrict__ csr_src, float* __restrict__ out) {
    int t = blockIdx.x * blockDim.x + threadIdx.x;
    int d = t >> 4, sl = t & 15;
    if (d >= N) return;
    float a0 = att[0], a1 = att[1];
    float2 xr = ((const float2*)xr2)[d];
    float b0 = xr.x, b1 = xr.y;
    float l = 0.f, ac0 = 0.f, ac1 = 0.f;
    int st = rowstart[d], n = deg[d];
    if (sl == 0) {
        float2 s = ((const float2*)xl2)[d];
        float p = lrelu(s.x + b0) * a0 + lrelu(s.y + b1) * a1;
        float e = __expf(p);
        l = e; ac0 = e * s.x; ac1 = e * s.y;
    }
    for (int i = sl; i < n; i += 16) {
        int s = csr_src[st + i];
        float2 xv = ((const float2*)xl2)[s];
        float q = lrelu(xv.x + b0) * a0 + lrelu(xv.y + b1) * a1;
        float e = __expf(q);
        l += e; ac0 += e * xv.x; ac1 += e * xv.y;
    }
#pragma unroll
    for (int off = 1; off < 16; off <<= 1) {
        l   += __shfl_xor(l, off, 64);
        ac0 += __shfl_xor(ac0, off, 64);
        ac1 += __shfl_xor(ac1, off, 64);
    }
    if (sl == 0) {
        float inv = 1.f / l;
        float v0 = ac0 * inv + bias[0];
        float v1 = ac1 * inv + bias[1];
        float mx = fmaxf(v0, v1);
        float lse = mx + logf(__expf(v0 - mx) + __expf(v1 - mx));
        out[d * 2] = v0 - lse;
        out[d * 2 + 1] = v1 - lse;
    }
}

extern "C" void kernel_launch(void* const* d_in, const int* in_sizes, int n_in,
                              void* d_out, int out_size, void* d_ws, size_t ws_size,
                              hipStream_t stream) {
    const float* x        = (const float*)d_in[0];
    const int*   ei       = (const int*)  d_in[1];
    const float* W_in     = (const float*)d_in[2];
    const float* b_in     = (const float*)d_in[3];
    const float* Wl0      = (const float*)d_in[4];
    const float* Wr0      = (const float*)d_in[5];
    const float* att0     = (const float*)d_in[6];
    const float* bias0    = (const float*)d_in[7];
    const float* Wl1      = (const float*)d_in[8];
    const float* Wr1      = (const float*)d_in[9];
    const float* att1     = (const float*)d_in[10];
    const float* bias1    = (const float*)d_in[11];
    const float* Wl2      = (const float*)d_in[12];
    const float* Wr2      = (const float*)d_in[13];
    const float* att2     = (const float*)d_in[14];
    const float* bias2    = (const float*)d_in[15];
    const float* bn_gamma = (const float*)d_in[16];
    const float* bn_beta  = (const float*)d_in[17];
    const float* bn_mean  = (const float*)d_in[18];
    const float* bn_var   = (const float*)d_in[19];

    const int N  = in_sizes[0] / 128;
    const int E  = in_sizes[1] / 2;
    const int NB = (N + 255) / 256;

    float* ws = (float*)d_ws;
    size_t off = 0;
    float* C    = ws + off; off += (size_t)N * 256;     // layer0 out / residual (f32)
    float* D    = ws + off; off += (size_t)N * 256;     // layer1 out (f32)
    float* XL2  = ws + off; off += (size_t)N * 2;
    float* XR2  = ws + off; off += (size_t)N * 2;
    h16* Ah   = (h16*)(ws + off); off += (size_t)N * 128;  // f16 xl [N,256]
    h16* Bh   = (h16*)(ws + off); off += (size_t)N * 128;  // f16 xr [N,256]
    h16* Ch   = (h16*)(ws + off); off += (size_t)N * 128;  // f16 copy of C
    h16* H0h  = (h16*)(ws + off); off += (size_t)N * 32;   // f16 h0 [N,64]
    h16* xh   = (h16*)(ws + off); off += (size_t)N * 64;   // f16 x  [N,128]
    h16* Wp_in = (h16*)(ws + off); off += 4096;    // 128*64
    h16* Wp_l0 = (h16*)(ws + off); off += 8192;    // 64*256
    h16* Wp_r0 = (h16*)(ws + off); off += 8192;
    h16* Wp_l1 = (h16*)(ws + off); off += 32768;   // 256*256
    h16* Wp_r1 = (h16*)(ws + off); off += 32768;
    int* ip = (int*)(ws + off);
    int* deg      = ip;              ip += N;
    int* rowstart = ip;              ip += N;
    int* cursor   = ip;              ip += N;
    int* bsum     = ip;              ip += NB;
    int* csr_src  = ip;              ip += E;

    // ---- CSR build (parallel scan) ----
    zero_int<<<(N + 255) / 256, 256, 0, stream>>>(deg, N);
    hist_dst<<<(E + 255) / 256, 256, 0, stream>>>(ei, E, deg);
    scan_blk<<<NB, 256, 0, stream>>>(deg, rowstart, bsum, N);
    scan_off<<<1, 256, 0, stream>>>(bsum, NB);
    add_off<<<NB, 256, 0, stream>>>(bsum, rowstart, cursor, N);
    scatter_src<<<(E + 255) / 256, 256, 0, stream>>>(ei, E, cursor, csr_src);

    // ---- weight packing + x conversion (one launch) ----
    pack_all<<<(172032 + N * 32 + 255) / 256, 256, 0, stream>>>(
        W_in, Wl0, Wr0, Wl1, Wr1, Wp_in, Wp_l0, Wp_r0, Wp_l1, Wp_r1,
        (const float4*)x, (half4v*)xh, N * 32);

    const int GBM = (N + 63) / 64;

    // h0 = relu(x @ W_in + b_in)  -> f16
    gemm_mfma<4, 4, true><<<GBM, 256, 0, stream>>>(xh, Wp_in, b_in, H0h, N);

    // -------- layer 0 --------
    gemm_mfma2<2, 16><<<dim3(GBM, 2), 256, 0, stream>>>(H0h, Wp_l0, Wp_r0, Ah, Bh, N);
    attn4_bn<<<(N + 3) / 4, 256, 0, stream>>>(N, Ah, Bh, att0, rowstart, deg, csr_src,
                                              bn_gamma, bn_beta, bn_mean, bn_var,
                                              bias0, nullptr, C, Ch);

    // -------- layer 1 (residual) --------
    gemm_mfma2<8, 16><<<dim3(GBM, 2), 256, 0, stream>>>(Ch, Wp_l1, Wp_r1, Ah, Bh, N);
    attn4_bn<<<(N + 3) / 4, 256, 0, stream>>>(N, Ah, Bh, att1, rowstart, deg, csr_src,
                                              bn_gamma + 256, bn_beta + 256, bn_mean + 256,
                                              bn_var + 256, bias1, C, D, nullptr);

    // -------- layer 2 (1 head, C=2) + log_softmax --------
    gemm2_wave<<<(N * 16 + 255) / 256, 256, 0, stream>>>(D, Wl2, Wr2, XL2, XR2, N);
    attn1_16<<<(N * 16 + 255) / 256, 256, 0, stream>>>(N, XL2, XR2, att2, bias2,
                                                       rowstart, deg, csr_src, (float*)d_out);
}

// Round 11
// 438.274 us; speedup vs baseline: 17.7257x; 1.2067x over previous
//
#include <hip/hip_runtime.h>
#include <hip/hip_bf16.h>
#include <math.h>

// ---------------------------------------------------------------------------
// GATv2 3-layer GNN. CSR-by-dst on-device (parallel scan); f16 MFMA GEMMs
// with double-buffered LDS staging of W (4-wave sharing, canonical §5
// anatomy); fused max-free-softmax attention (4-edge batched, packed-f16);
// BN/ReLU/residual epilogue fused.
// ---------------------------------------------------------------------------

using h16     = _Float16;
using half2v  = __attribute__((ext_vector_type(2))) h16;
using half4v  = __attribute__((ext_vector_type(4))) h16;
using half8   = __attribute__((ext_vector_type(8))) h16;
using floatx4 = __attribute__((ext_vector_type(4))) float;

__device__ __forceinline__ float lrelu(float x) { return x > 0.f ? x : 0.2f * x; }

__device__ __forceinline__ half2v shfl_xor_h2(half2v v, int mask) {
    float f = __builtin_bit_cast(float, v);
    f = __shfl_xor(f, mask, 64);
    return __builtin_bit_cast(half2v, f);
}

// ---------------- CSR build ----------------
__global__ void zero_int(int* __restrict__ p, int n) {
    int t = blockIdx.x * blockDim.x + threadIdx.x;
    if (t < n) p[t] = 0;
}

__global__ void hist_dst(const int* __restrict__ ei, int E, int* __restrict__ deg) {
    int e = blockIdx.x * blockDim.x + threadIdx.x;
    if (e < E) atomicAdd(&deg[ei[E + e]], 1);
}

__global__ __launch_bounds__(256) void scan_blk(const int* __restrict__ deg,
                                                int* __restrict__ rowstart,
                                                int* __restrict__ bsum, int N) {
    int t = blockIdx.x * 256 + threadIdx.x;
    int lane = threadIdx.x & 63, wid = threadIdx.x >> 6;
    int v = (t < N) ? deg[t] : 0;
    int x = v;
#pragma unroll
    for (int off = 1; off < 64; off <<= 1) {
        int y = __shfl_up(x, off, 64);
        if (lane >= off) x += y;
    }
    __shared__ int wsum[4];
    if (lane == 63) wsum[wid] = x;
    __syncthreads();
    int add = 0;
#pragma unroll
    for (int w = 0; w < 4; ++w) if (w < wid) add += wsum[w];
    int incl = x + add;
    if (t < N) rowstart[t] = incl - v;
    if (threadIdx.x == 255) bsum[blockIdx.x] = incl;
}

__global__ __launch_bounds__(256) void scan_off(int* __restrict__ bsum, int NB) {
    int t = threadIdx.x;
    int lane = t & 63, wid = t >> 6;
    int v = (t < NB) ? bsum[t] : 0;
    int x = v;
#pragma unroll
    for (int off = 1; off < 64; off <<= 1) {
        int y = __shfl_up(x, off, 64);
        if (lane >= off) x += y;
    }
    __shared__ int wsum[4];
    if (lane == 63) wsum[wid] = x;
    __syncthreads();
    int add = 0;
#pragma unroll
    for (int w = 0; w < 4; ++w) if (w < wid) add += wsum[w];
    if (t < NB) bsum[t] = x + add - v;
}

__global__ void add_off(const int* __restrict__ bsum, int* __restrict__ rowstart,
                        int* __restrict__ cursor, int N) {
    int t = blockIdx.x * 256 + threadIdx.x;
    if (t >= N) return;
    int r = rowstart[t] + bsum[blockIdx.x];
    rowstart[t] = r;
    cursor[t] = r;
}

__global__ void scatter_src(const int* __restrict__ ei, int E,
                            int* __restrict__ cursor, int* __restrict__ csr_src) {
    int e = blockIdx.x * blockDim.x + threadIdx.x;
    if (e >= E) return;
    int d = ei[E + e];
    int pos = atomicAdd(&cursor[d], 1);
    csr_src[pos] = ei[e];
}

// ---------------- weight packing + x conversion (one launch) ----------------
// New layout (LDS-chunk friendly): Wp[((kc*NT + nt)*64 + l)*8 + j]
//   = W[kc*32 + (l>>4)*8 + j][nt*16 + (l&15)],  NT = NC/16
__device__ __forceinline__ void pack_one(const float* __restrict__ W,
                                         h16* __restrict__ Wp,
                                         int t, int K, int NC) {
    int j = t & 7;
    int l = (t >> 3) & 63;
    int rest = t >> 9;
    int NT = NC >> 4;
    int nt = rest % NT;
    int kc = rest / NT;
    int row = kc * 32 + (l >> 4) * 8 + j;
    int col = nt * 16 + (l & 15);
    Wp[t] = (h16)W[(size_t)row * NC + col];
}

__global__ void pack_all(const float* __restrict__ W_in,
                         const float* __restrict__ Wl0, const float* __restrict__ Wr0,
                         const float* __restrict__ Wl1, const float* __restrict__ Wr1,
                         h16* __restrict__ P_in,
                         h16* __restrict__ P_l0, h16* __restrict__ P_r0,
                         h16* __restrict__ P_l1, h16* __restrict__ P_r1,
                         const float4* __restrict__ x, half4v* __restrict__ xh, int n4) {
    int t = blockIdx.x * blockDim.x + threadIdx.x;
    if (t < 8192)        pack_one(W_in, P_in, t, 128, 64);
    else if (t < 24576)  pack_one(Wl0, P_l0, t - 8192, 64, 256);
    else if (t < 40960)  pack_one(Wr0, P_r0, t - 24576, 64, 256);
    else if (t < 106496) pack_one(Wl1, P_l1, t - 40960, 256, 256);
    else if (t < 172032) pack_one(Wr1, P_r1, t - 106496, 256, 256);
    else {
        int u = t - 172032;
        if (u < n4) {
            float4 v = x[u];
            half4v o = { (h16)v.x, (h16)v.y, (h16)v.z, (h16)v.w };
            xh[u] = o;
        }
    }
}

// --------- MFMA GEMM, double-buffered LDS staging of W -----------------
// Block = 4 waves, 64 rows x NT*16 cols. W chunk per kc (32 k) = NT KB,
// staged to LDS once per block, shared by all 4 waves via ds_read_b128.
template<int KC, int NT, bool RELU, bool DUAL>
__global__ __launch_bounds__(256) void gemm_lds(
        const h16* __restrict__ Xh,
        const h16* __restrict__ Wp0, const h16* __restrict__ Wp1,
        const float* __restrict__ bias,
        h16* __restrict__ out0, h16* __restrict__ out1, int M) {
    constexpr int K = KC * 32;
    constexpr int ldo = NT * 16;
    constexpr int CHUNK8 = NT * 64;           // half8 elements per kc chunk
    constexpr int PER_THR = CHUNK8 / 256;     // half8 per thread per stage
    __shared__ half8 wbuf[2][CHUNK8];

    const h16* Wp = (DUAL && blockIdx.y) ? Wp1 : Wp0;
    h16* out = (DUAL && blockIdx.y) ? out1 : out0;
    const half8* WG = (const half8*)Wp;

    const int tid = threadIdx.x;
    const int wid = tid >> 6, lane = tid & 63;
    const int quad = lane >> 4, li = lane & 15;
    const int r0 = blockIdx.x * 64 + wid * 16;
    int arow = r0 + li; if (arow >= M) arow = M - 1;       // clamp; stores guarded
    const half8* A8 = (const half8*)Xh + (size_t)arow * (K / 8) + quad;

    floatx4 acc[NT];
#pragma unroll
    for (int t = 0; t < NT; ++t) acc[t] = (floatx4){0.f, 0.f, 0.f, 0.f};

    half8 st[PER_THR];
#pragma unroll
    for (int i = 0; i < PER_THR; ++i) st[i] = WG[i * 256 + tid];
#pragma unroll
    for (int i = 0; i < PER_THR; ++i) wbuf[0][i * 256 + tid] = st[i];
    __syncthreads();

#pragma unroll
    for (int kc = 0; kc < KC; ++kc) {
        int cur = kc & 1;
        if (kc + 1 < KC) {
#pragma unroll
            for (int i = 0; i < PER_THR; ++i)
                st[i] = WG[(size_t)(kc + 1) * CHUNK8 + i * 256 + tid];
        }
        half8 a = A8[kc * 4];
#pragma unroll
        for (int nt = 0; nt < NT; ++nt) {
            half8 b = wbuf[cur][nt * 64 + lane];
            acc[nt] = __builtin_amdgcn_mfma_f32_16x16x32_f16(a, b, acc[nt], 0, 0, 0);
        }
        if (kc + 1 < KC) {
#pragma unroll
            for (int i = 0; i < PER_THR; ++i) wbuf[cur ^ 1][i * 256 + tid] = st[i];
        }
        __syncthreads();
    }

#pragma unroll
    for (int nt = 0; nt < NT; ++nt) {
#pragma unroll
        for (int reg = 0; reg < 4; ++reg) {
            int rr = r0 + quad * 4 + reg;
            if (rr >= M) continue;
            float v = acc[nt][reg];
            if (RELU) v = fmaxf(v + bias[nt * 16 + li], 0.f);
            out[(size_t)rr * ldo + nt * 16 + li] = (h16)v;
        }
    }
}

// ---- fused 4-head attention + BN + ReLU (+residual), wave/dst, f16 in -----
__global__ void attn4_bn(int N, const h16* __restrict__ XL, const h16* __restrict__ XR,
                         const float* __restrict__ att,
                         const int* __restrict__ rowstart, const int* __restrict__ deg,
                         const int* __restrict__ csr_src,
                         const float* __restrict__ gamma, const float* __restrict__ beta,
                         const float* __restrict__ mean, const float* __restrict__ var,
                         const float* __restrict__ bias, const float* __restrict__ resid,
                         float* __restrict__ out, h16* __restrict__ outb) {
    int d = blockIdx.x * (blockDim.x >> 6) + (threadIdx.x >> 6);
    int lane = threadIdx.x & 63;
    if (d >= N) return;
    half4v bv = *(const half4v*)(XR + (size_t)d * 256 + lane * 4);
    float4 wf = ((const float4*)att)[lane];
    half2v b0 = bv.xy, b1 = bv.zw;
    half2v w0 = { (h16)wf.x, (h16)wf.y };
    half2v w1 = { (h16)wf.z, (h16)wf.w };
    const h16 k02 = (h16)0.2f;

    auto edge_part = [&](half4v xv) -> h16 {
        half2v e0 = xv.xy + b0, e1 = xv.zw + b1;
        half2v l0 = __builtin_elementwise_max(e0, e0 * k02);
        half2v l1 = __builtin_elementwise_max(e1, e1 * k02);
        half2v qd = l0 * w0 + l1 * w1;
        return qd.x + qd.y;
    };

    half4v av = *(const half4v*)(XL + (size_t)d * 256 + lane * 4);
    float p = (float)edge_part(av);
    p += __shfl_xor(p, 1, 64); p += __shfl_xor(p, 2, 64);
    p += __shfl_xor(p, 4, 64); p += __shfl_xor(p, 8, 64);
    float es = __expf(p);
    float l = es;
    float4 acc = { es * (float)av.x, es * (float)av.y, es * (float)av.z, es * (float)av.w };

    int start = rowstart[d], n = deg[d];
    for (int i = 0; i < n; i += 4) {
        int nm1 = n - 1;
        int s0 = csr_src[start + i];
        int s1 = csr_src[start + min(i + 1, nm1)];
        int s2 = csr_src[start + min(i + 2, nm1)];
        int s3 = csr_src[start + min(i + 3, nm1)];
        half4v x0 = *(const half4v*)(XL + (size_t)s0 * 256 + lane * 4);
        half4v x1 = *(const half4v*)(XL + (size_t)s1 * 256 + lane * 4);
        half4v x2 = *(const half4v*)(XL + (size_t)s2 * 256 + lane * 4);
        half4v x3 = *(const half4v*)(XL + (size_t)s3 * 256 + lane * 4);
        half2v p01 = { edge_part(x0), edge_part(x1) };
        half2v p23 = { edge_part(x2), edge_part(x3) };
#pragma unroll
        for (int s = 1; s < 16; s <<= 1) {
            p01 += shfl_xor_h2(p01, s);
            p23 += shfl_xor_h2(p23, s);
        }
        int rem = n - i;
        float e0 = __expf((float)p01.x);
        float e1 = (rem > 1) ? __expf((float)p01.y) : 0.f;
        float e2 = (rem > 2) ? __expf((float)p23.x) : 0.f;
        float e3 = (rem > 3) ? __expf((float)p23.y) : 0.f;
        l += (e0 + e1) + (e2 + e3);
        acc.x += e0 * (float)x0.x + e1 * (float)x1.x + e2 * (float)x2.x + e3 * (float)x3.x;
        acc.y += e0 * (float)x0.y + e1 * (float)x1.y + e2 * (float)x2.y + e3 * (float)x3.y;
        acc.z += e0 * (float)x0.z + e1 * (float)x1.z + e2 * (float)x2.z + e3 * (float)x3.z;
        acc.w += e0 * (float)x0.w + e1 * (float)x1.w + e2 * (float)x2.w + e3 * (float)x3.w;
    }
    float inv = 1.f / l;
    float4 g  = ((const float4*)gamma)[lane];
    float4 be = ((const float4*)beta)[lane];
    float4 mu = ((const float4*)mean)[lane];
    float4 va = ((const float4*)var)[lane];
    float4 bi = ((const float4*)bias)[lane];
    float4 sc4, sh4;
    sc4.x = g.x * rsqrtf(va.x + 1e-5f); sh4.x = (bi.x - mu.x) * sc4.x + be.x;
    sc4.y = g.y * rsqrtf(va.y + 1e-5f); sh4.y = (bi.y - mu.y) * sc4.y + be.y;
    sc4.z = g.z * rsqrtf(va.z + 1e-5f); sh4.z = (bi.z - mu.z) * sc4.z + be.z;
    sc4.w = g.w * rsqrtf(va.w + 1e-5f); sh4.w = (bi.w - mu.w) * sc4.w + be.w;
    float4 o;
    o.x = fmaxf(acc.x * inv * sc4.x + sh4.x, 0.f);
    o.y = fmaxf(acc.y * inv * sc4.y + sh4.y, 0.f);
    o.z = fmaxf(acc.z * inv * sc4.z + sh4.z, 0.f);
    o.w = fmaxf(acc.w * inv * sc4.w + sh4.w, 0.f);
    if (resid) {
        float4 rv = *(const float4*)(resid + (size_t)d * 256 + lane * 4);
        o.x += rv.x; o.y += rv.y; o.z += rv.z; o.w += rv.w;
    }
    *(float4*)(out + (size_t)d * 256 + lane * 4) = o;
    if (outb) {
        half4v ob = { (h16)o.x, (h16)o.y, (h16)o.z, (h16)o.w };
        *(half4v*)(outb + (size_t)d * 256 + lane * 4) = ob;
    }
}

// ---- layer 2 projections: 16 lanes per node; each lane covers 16 of K=256 ----
__global__ void gemm2_wave(const float* __restrict__ X, const float* __restrict__ Wl,
                           const float* __restrict__ Wr, float* __restrict__ xl2,
                           float* __restrict__ xr2, int N) {
    int t = blockIdx.x * blockDim.x + threadIdx.x;
    int n = t >> 4;
    int sl = t & 15;
    if (n >= N) return;
    const float4* Xr = (const float4*)(X + (size_t)n * 256);
    const float4* Wl4 = (const float4*)Wl;
    const float4* Wr4 = (const float4*)Wr;
    float l0 = 0.f, l1 = 0.f, r0 = 0.f, r1 = 0.f;
#pragma unroll
    for (int j = 0; j < 4; ++j) {
        int idx = sl + j * 16;
        float4 xv = Xr[idx];
        float4 wa = Wl4[idx * 2];
        float4 wb = Wl4[idx * 2 + 1];
        l0 += xv.x * wa.x + xv.y * wa.z + xv.z * wb.x + xv.w * wb.z;
        l1 += xv.x * wa.y + xv.y * wa.w + xv.z * wb.y + xv.w * wb.w;
        wa = Wr4[idx * 2]; wb = Wr4[idx * 2 + 1];
        r0 += xv.x * wa.x + xv.y * wa.z + xv.z * wb.x + xv.w * wb.z;
        r1 += xv.x * wa.y + xv.y * wa.w + xv.z * wb.y + xv.w * wb.w;
    }
#pragma unroll
    for (int off = 1; off < 16; off <<= 1) {
        l0 += __shfl_xor(l0, off, 64);
        l1 += __shfl_xor(l1, off, 64);
        r0 += __shfl_xor(r0, off, 64);
        r1 += __shfl_xor(r1, off, 64);
    }
    if (sl == 0) {
        xl2[n * 2] = l0; xl2[n * 2 + 1] = l1;
        xr2[n * 2] = r0; xr2[n * 2 + 1] = r1;
    }
}

// ---- fused layer-2 attention (1 head, C=2) + log_softmax, 16 lanes/dst ----
__global__ void attn1_16(int N, const float* __restrict__ xl2, const float* __restrict__ xr2,
                         const float* __restrict__ att, const float* __restrict__ bias,
                         const int* __restrict__ rowstart, const int* __restrict__ deg,
                         const int* __restrict__ csr_src, float* __restrict__ out) {
    int t = blockIdx.x * blockDim.x + threadIdx.x;
    int d = t >> 4, sl = t & 15;
    if (d >= N) return;
    float a0 = att[0], a1 = att[1];
    float2 xr = ((const float2*)xr2)[d];
    float b0 = xr.x, b1 = xr.y;
    float l = 0.f, ac0 = 0.f, ac1 = 0.f;
    int st = rowstart[d], n = deg[d];
    if (sl == 0) {
        float2 s = ((const float2*)xl2)[d];
        float p = lrelu(s.x + b0) * a0 + lrelu(s.y + b1) * a1;
        float e = __expf(p);
        l = e; ac0 = e * s.x; ac1 = e * s.y;
    }
    for (int i = sl; i < n; i += 16) {
        int s = csr_src[st + i];
        float2 xv = ((const float2*)xl2)[s];
        float q = lrelu(xv.x + b0) * a0 + lrelu(xv.y + b1) * a1;
        float e = __expf(q);
        l += e; ac0 += e * xv.x; ac1 += e * xv.y;
    }
#pragma unroll
    for (int off = 1; off < 16; off <<= 1) {
        l   += __shfl_xor(l, off, 64);
        ac0 += __shfl_xor(ac0, off, 64);
        ac1 += __shfl_xor(ac1, off, 64);
    }
    if (sl == 0) {
        float inv = 1.f / l;
        float v0 = ac0 * inv + bias[0];
        float v1 = ac1 * inv + bias[1];
        float mx = fmaxf(v0, v1);
        float lse = mx + logf(__expf(v0 - mx) + __expf(v1 - mx));
        out[d * 2] = v0 - lse;
        out[d * 2 + 1] = v1 - lse;
    }
}

extern "C" void kernel_launch(void* const* d_in, const int* in_sizes, int n_in,
                              void* d_out, int out_size, void* d_ws, size_t ws_size,
                              hipStream_t stream) {
    const float* x        = (const float*)d_in[0];
    const int*   ei       = (const int*)  d_in[1];
    const float* W_in     = (const float*)d_in[2];
    const float* b_in     = (const float*)d_in[3];
    const float* Wl0      = (const float*)d_in[4];
    const float* Wr0      = (const float*)d_in[5];
    const float* att0     = (const float*)d_in[6];
    const float* bias0    = (const float*)d_in[7];
    const float* Wl1      = (const float*)d_in[8];
    const float* Wr1      = (const float*)d_in[9];
    const float* att1     = (const float*)d_in[10];
    const float* bias1    = (const float*)d_in[11];
    const float* Wl2      = (const float*)d_in[12];
    const float* Wr2      = (const float*)d_in[13];
    const float* att2     = (const float*)d_in[14];
    const float* bias2    = (const float*)d_in[15];
    const float* bn_gamma = (const float*)d_in[16];
    const float* bn_beta  = (const float*)d_in[17];
    const float* bn_mean  = (const float*)d_in[18];
    const float* bn_var   = (const float*)d_in[19];

    const int N  = in_sizes[0] / 128;
    const int E  = in_sizes[1] / 2;
    const int NB = (N + 255) / 256;

    float* ws = (float*)d_ws;
    size_t off = 0;
    float* C    = ws + off; off += (size_t)N * 256;     // layer0 out / residual (f32)
    float* D    = ws + off; off += (size_t)N * 256;     // layer1 out (f32)
    float* XL2  = ws + off; off += (size_t)N * 2;
    float* XR2  = ws + off; off += (size_t)N * 2;
    h16* Ah   = (h16*)(ws + off); off += (size_t)N * 128;  // f16 xl [N,256]
    h16* Bh   = (h16*)(ws + off); off += (size_t)N * 128;  // f16 xr [N,256]
    h16* Ch   = (h16*)(ws + off); off += (size_t)N * 128;  // f16 copy of C
    h16* H0h  = (h16*)(ws + off); off += (size_t)N * 32;   // f16 h0 [N,64]
    h16* xh   = (h16*)(ws + off); off += (size_t)N * 64;   // f16 x  [N,128]
    h16* Wp_in = (h16*)(ws + off); off += 4096;    // 128*64
    h16* Wp_l0 = (h16*)(ws + off); off += 8192;    // 64*256
    h16* Wp_r0 = (h16*)(ws + off); off += 8192;
    h16* Wp_l1 = (h16*)(ws + off); off += 32768;   // 256*256
    h16* Wp_r1 = (h16*)(ws + off); off += 32768;
    int* ip = (int*)(ws + off);
    int* deg      = ip;              ip += N;
    int* rowstart = ip;              ip += N;
    int* cursor   = ip;              ip += N;
    int* bsum     = ip;              ip += NB;
    int* csr_src  = ip;              ip += E;

    // ---- CSR build (parallel scan) ----
    zero_int<<<(N + 255) / 256, 256, 0, stream>>>(deg, N);
    hist_dst<<<(E + 255) / 256, 256, 0, stream>>>(ei, E, deg);
    scan_blk<<<NB, 256, 0, stream>>>(deg, rowstart, bsum, N);
    scan_off<<<1, 256, 0, stream>>>(bsum, NB);
    add_off<<<NB, 256, 0, stream>>>(bsum, rowstart, cursor, N);
    scatter_src<<<(E + 255) / 256, 256, 0, stream>>>(ei, E, cursor, csr_src);

    // ---- weight packing + x conversion (one launch) ----
    pack_all<<<(172032 + N * 32 + 255) / 256, 256, 0, stream>>>(
        W_in, Wl0, Wr0, Wl1, Wr1, Wp_in, Wp_l0, Wp_r0, Wp_l1, Wp_r1,
        (const float4*)x, (half4v*)xh, N * 32);

    const int GBM = (N + 63) / 64;

    // h0 = relu(x @ W_in + b_in)  -> f16
    gemm_lds<4, 4, true, false><<<GBM, 256, 0, stream>>>(
        xh, Wp_in, nullptr, b_in, H0h, nullptr, N);

    // -------- layer 0 --------
    gemm_lds<2, 16, false, true><<<dim3(GBM, 2), 256, 0, stream>>>(
        H0h, Wp_l0, Wp_r0, nullptr, Ah, Bh, N);
    attn4_bn<<<(N + 3) / 4, 256, 0, stream>>>(N, Ah, Bh, att0, rowstart, deg, csr_src,
                                              bn_gamma, bn_beta, bn_mean, bn_var,
                                              bias0, nullptr, C, Ch);

    // -------- layer 1 (residual) --------
    gemm_lds<8, 16, false, true><<<dim3(GBM, 2), 256, 0, stream>>>(
        Ch, Wp_l1, Wp_r1, nullptr, Ah, Bh, N);
    attn4_bn<<<(N + 3) / 4, 256, 0, stream>>>(N, Ah, Bh, att1, rowstart, deg, csr_src,
                                              bn_gamma + 256, bn_beta + 256, bn_mean + 256,
                                              bn_var + 256, bias1, C, D, nullptr);

    // -------- layer 2 (1 head, C=2) + log_softmax --------
    gemm2_wave<<<(N * 16 + 255) / 256, 256, 0, stream>>>(D, Wl2, Wr2, XL2, XR2, N);
    attn1_16<<<(N * 16 + 255) / 256, 256, 0, stream>>>(N, XL2, XR2, att2, bias2,
                                                       rowstart, deg, csr_src, (float*)d_out);
}

// Round 12
// 418.937 us; speedup vs baseline: 18.5439x; 1.0462x over previous
//
#include <hip/hip_runtime.h>
#include <hip/hip_bf16.h>
#include <math.h>

// ---------------------------------------------------------------------------
// GATv2 3-layer GNN. CSR-by-dst on-device (parallel scan); f16 MFMA GEMMs
// with double-buffered LDS staging of W; fused max-free-softmax attention
// (4-edge batched, packed-f16 logits AND accumulator, index prefetch);
// BN/ReLU/residual epilogue fused. Layer-1 output kept f16-only.
// ---------------------------------------------------------------------------

using h16     = _Float16;
using half2v  = __attribute__((ext_vector_type(2))) h16;
using half4v  = __attribute__((ext_vector_type(4))) h16;
using half8   = __attribute__((ext_vector_type(8))) h16;
using floatx4 = __attribute__((ext_vector_type(4))) float;

__device__ __forceinline__ float lrelu(float x) { return x > 0.f ? x : 0.2f * x; }

__device__ __forceinline__ half2v shfl_xor_h2(half2v v, int mask) {
    float f = __builtin_bit_cast(float, v);
    f = __shfl_xor(f, mask, 64);
    return __builtin_bit_cast(half2v, f);
}

// ---------------- CSR build ----------------
__global__ void hist_dst(const int* __restrict__ ei, int E, int* __restrict__ deg) {
    int e = blockIdx.x * blockDim.x + threadIdx.x;
    if (e < E) atomicAdd(&deg[ei[E + e]], 1);
}

__global__ __launch_bounds__(256) void scan_blk(const int* __restrict__ deg,
                                                int* __restrict__ rowstart,
                                                int* __restrict__ bsum, int N) {
    int t = blockIdx.x * 256 + threadIdx.x;
    int lane = threadIdx.x & 63, wid = threadIdx.x >> 6;
    int v = (t < N) ? deg[t] : 0;
    int x = v;
#pragma unroll
    for (int off = 1; off < 64; off <<= 1) {
        int y = __shfl_up(x, off, 64);
        if (lane >= off) x += y;
    }
    __shared__ int wsum[4];
    if (lane == 63) wsum[wid] = x;
    __syncthreads();
    int add = 0;
#pragma unroll
    for (int w = 0; w < 4; ++w) if (w < wid) add += wsum[w];
    int incl = x + add;
    if (t < N) rowstart[t] = incl - v;
    if (threadIdx.x == 255) bsum[blockIdx.x] = incl;
}

__global__ __launch_bounds__(256) void scan_off(int* __restrict__ bsum, int NB) {
    int t = threadIdx.x;
    int lane = t & 63, wid = t >> 6;
    int v = (t < NB) ? bsum[t] : 0;
    int x = v;
#pragma unroll
    for (int off = 1; off < 64; off <<= 1) {
        int y = __shfl_up(x, off, 64);
        if (lane >= off) x += y;
    }
    __shared__ int wsum[4];
    if (lane == 63) wsum[wid] = x;
    __syncthreads();
    int add = 0;
#pragma unroll
    for (int w = 0; w < 4; ++w) if (w < wid) add += wsum[w];
    if (t < NB) bsum[t] = x + add - v;
}

__global__ void add_off(const int* __restrict__ bsum, int* __restrict__ rowstart,
                        int* __restrict__ cursor, int N) {
    int t = blockIdx.x * 256 + threadIdx.x;
    if (t >= N) return;
    int r = rowstart[t] + bsum[blockIdx.x];
    rowstart[t] = r;
    cursor[t] = r;
}

__global__ void scatter_src(const int* __restrict__ ei, int E,
                            int* __restrict__ cursor, int* __restrict__ csr_src) {
    int e = blockIdx.x * blockDim.x + threadIdx.x;
    if (e >= E) return;
    int d = ei[E + e];
    int pos = atomicAdd(&cursor[d], 1);
    csr_src[pos] = ei[e];
}

// ------- weight packing + x conversion + deg zeroing (one launch) ---------
// LDS-chunk-friendly layout: Wp[((kc*NT + nt)*64 + l)*8 + j]
//   = W[kc*32 + (l>>4)*8 + j][nt*16 + (l&15)],  NT = NC/16
__device__ __forceinline__ void pack_one(const float* __restrict__ W,
                                         h16* __restrict__ Wp,
                                         int t, int K, int NC) {
    int j = t & 7;
    int l = (t >> 3) & 63;
    int rest = t >> 9;
    int NT = NC >> 4;
    int nt = rest % NT;
    int kc = rest / NT;
    int row = kc * 32 + (l >> 4) * 8 + j;
    int col = nt * 16 + (l & 15);
    Wp[t] = (h16)W[(size_t)row * NC + col];
}

__global__ void pack_all(const float* __restrict__ W_in,
                         const float* __restrict__ Wl0, const float* __restrict__ Wr0,
                         const float* __restrict__ Wl1, const float* __restrict__ Wr1,
                         h16* __restrict__ P_in,
                         h16* __restrict__ P_l0, h16* __restrict__ P_r0,
                         h16* __restrict__ P_l1, h16* __restrict__ P_r1,
                         const float4* __restrict__ x, half4v* __restrict__ xh, int n4,
                         int* __restrict__ deg, int N) {
    int t = blockIdx.x * blockDim.x + threadIdx.x;
    if (t < 8192)        pack_one(W_in, P_in, t, 128, 64);
    else if (t < 24576)  pack_one(Wl0, P_l0, t - 8192, 64, 256);
    else if (t < 40960)  pack_one(Wr0, P_r0, t - 24576, 64, 256);
    else if (t < 106496) pack_one(Wl1, P_l1, t - 40960, 256, 256);
    else if (t < 172032) pack_one(Wr1, P_r1, t - 106496, 256, 256);
    else if (t < 172032 + n4) {
        int u = t - 172032;
        float4 v = x[u];
        half4v o = { (h16)v.x, (h16)v.y, (h16)v.z, (h16)v.w };
        xh[u] = o;
    } else {
        int u = t - 172032 - n4;
        if (u < N) deg[u] = 0;
    }
}

// --------- MFMA GEMM, double-buffered LDS staging of W -----------------
template<int KC, int NT, bool RELU, bool DUAL>
__global__ __launch_bounds__(256) void gemm_lds(
        const h16* __restrict__ Xh,
        const h16* __restrict__ Wp0, const h16* __restrict__ Wp1,
        const float* __restrict__ bias,
        h16* __restrict__ out0, h16* __restrict__ out1, int M) {
    constexpr int K = KC * 32;
    constexpr int ldo = NT * 16;
    constexpr int CHUNK8 = NT * 64;
    constexpr int PER_THR = CHUNK8 / 256;
    __shared__ half8 wbuf[2][CHUNK8];

    const h16* Wp = (DUAL && blockIdx.y) ? Wp1 : Wp0;
    h16* out = (DUAL && blockIdx.y) ? out1 : out0;
    const half8* WG = (const half8*)Wp;

    const int tid = threadIdx.x;
    const int wid = tid >> 6, lane = tid & 63;
    const int quad = lane >> 4, li = lane & 15;
    const int r0 = blockIdx.x * 64 + wid * 16;
    int arow = r0 + li; if (arow >= M) arow = M - 1;
    const half8* A8 = (const half8*)Xh + (size_t)arow * (K / 8) + quad;

    floatx4 acc[NT];
#pragma unroll
    for (int t = 0; t < NT; ++t) acc[t] = (floatx4){0.f, 0.f, 0.f, 0.f};

    half8 st[PER_THR];
#pragma unroll
    for (int i = 0; i < PER_THR; ++i) st[i] = WG[i * 256 + tid];
#pragma unroll
    for (int i = 0; i < PER_THR; ++i) wbuf[0][i * 256 + tid] = st[i];
    __syncthreads();

#pragma unroll
    for (int kc = 0; kc < KC; ++kc) {
        int cur = kc & 1;
        if (kc + 1 < KC) {
#pragma unroll
            for (int i = 0; i < PER_THR; ++i)
                st[i] = WG[(size_t)(kc + 1) * CHUNK8 + i * 256 + tid];
        }
        half8 a = A8[kc * 4];
#pragma unroll
        for (int nt = 0; nt < NT; ++nt) {
            half8 b = wbuf[cur][nt * 64 + lane];
            acc[nt] = __builtin_amdgcn_mfma_f32_16x16x32_f16(a, b, acc[nt], 0, 0, 0);
        }
        if (kc + 1 < KC) {
#pragma unroll
            for (int i = 0; i < PER_THR; ++i) wbuf[cur ^ 1][i * 256 + tid] = st[i];
        }
        __syncthreads();
    }

#pragma unroll
    for (int nt = 0; nt < NT; ++nt) {
#pragma unroll
        for (int reg = 0; reg < 4; ++reg) {
            int rr = r0 + quad * 4 + reg;
            if (rr >= M) continue;
            float v = acc[nt][reg];
            if (RELU) v = fmaxf(v + bias[nt * 16 + li], 0.f);
            out[(size_t)rr * ldo + nt * 16 + li] = (h16)v;
        }
    }
}

// ---- fused 4-head attention + BN + ReLU (+residual), wave/dst, f16 in -----
// Max-free softmax; 4-edge batch; f16 packed logits AND accumulator;
// next-batch index prefetch. out (f32) is optional; outb (f16) is optional.
__global__ void attn4_bn(int N, const h16* __restrict__ XL, const h16* __restrict__ XR,
                         const float* __restrict__ att,
                         const int* __restrict__ rowstart, const int* __restrict__ deg,
                         const int* __restrict__ csr_src,
                         const float* __restrict__ gamma, const float* __restrict__ beta,
                         const float* __restrict__ mean, const float* __restrict__ var,
                         const float* __restrict__ bias, const float* __restrict__ resid,
                         float* __restrict__ out, h16* __restrict__ outb) {
    int d = blockIdx.x * (blockDim.x >> 6) + (threadIdx.x >> 6);
    int lane = threadIdx.x & 63;
    if (d >= N) return;
    half4v bv = *(const half4v*)(XR + (size_t)d * 256 + lane * 4);
    float4 wf = ((const float4*)att)[lane];
    half2v b0 = bv.xy, b1 = bv.zw;
    half2v w0 = { (h16)wf.x, (h16)wf.y };
    half2v w1 = { (h16)wf.z, (h16)wf.w };
    const h16 k02 = (h16)0.2f;

    auto edge_part = [&](half4v xv) -> h16 {
        half2v e0 = xv.xy + b0, e1 = xv.zw + b1;
        half2v l0 = __builtin_elementwise_max(e0, e0 * k02);
        half2v l1 = __builtin_elementwise_max(e1, e1 * k02);
        half2v qd = l0 * w0 + l1 * w1;
        return qd.x + qd.y;
    };

    // self-loop
    half4v av = *(const half4v*)(XL + (size_t)d * 256 + lane * 4);
    float p = (float)edge_part(av);
    p += __shfl_xor(p, 1, 64); p += __shfl_xor(p, 2, 64);
    p += __shfl_xor(p, 4, 64); p += __shfl_xor(p, 8, 64);
    float es = __expf(p);
    float l = es;
    h16 eh = (h16)es;
    half2v ebc = { eh, eh };
    half2v acc0 = ebc * av.xy;       // channels 0,1 (f16 accumulator)
    half2v acc1 = ebc * av.zw;       // channels 2,3

    int start = rowstart[d], n = deg[d];
    int nm1 = n - 1;
    int t0 = 0, t1 = 0, t2 = 0, t3 = 0;
    if (n > 0) {
        t0 = csr_src[start];
        t1 = csr_src[start + min(1, nm1)];
        t2 = csr_src[start + min(2, nm1)];
        t3 = csr_src[start + min(3, nm1)];
    }
    for (int i = 0; i < n; i += 4) {
        int s0 = t0, s1 = t1, s2 = t2, s3 = t3;
        half4v x0 = *(const half4v*)(XL + (size_t)s0 * 256 + lane * 4);
        half4v x1 = *(const half4v*)(XL + (size_t)s1 * 256 + lane * 4);
        half4v x2 = *(const half4v*)(XL + (size_t)s2 * 256 + lane * 4);
        half4v x3 = *(const half4v*)(XL + (size_t)s3 * 256 + lane * 4);
        int j = i + 4;
        if (j < n) {                 // prefetch next batch's indices
            t0 = csr_src[start + j];
            t1 = csr_src[start + min(j + 1, nm1)];
            t2 = csr_src[start + min(j + 2, nm1)];
            t3 = csr_src[start + min(j + 3, nm1)];
        }
        half2v p01 = { edge_part(x0), edge_part(x1) };
        half2v p23 = { edge_part(x2), edge_part(x3) };
#pragma unroll
        for (int s = 1; s < 16; s <<= 1) {
            p01 += shfl_xor_h2(p01, s);
            p23 += shfl_xor_h2(p23, s);
        }
        int rem = n - i;
        float e0 = __expf((float)p01.x);
        float e1 = (rem > 1) ? __expf((float)p01.y) : 0.f;
        float e2 = (rem > 2) ? __expf((float)p23.x) : 0.f;
        float e3 = (rem > 3) ? __expf((float)p23.y) : 0.f;
        l += (e0 + e1) + (e2 + e3);
        h16 h0 = (h16)e0, h1 = (h16)e1, h2 = (h16)e2, h3 = (h16)e3;
        half2v eb0 = { h0, h0 }, eb1 = { h1, h1 }, eb2 = { h2, h2 }, eb3 = { h3, h3 };
        acc0 += eb0 * x0.xy; acc1 += eb0 * x0.zw;
        acc0 += eb1 * x1.xy; acc1 += eb1 * x1.zw;
        acc0 += eb2 * x2.xy; acc1 += eb2 * x2.zw;
        acc0 += eb3 * x3.xy; acc1 += eb3 * x3.zw;
    }
    float4 acc = { (float)acc0.x, (float)acc0.y, (float)acc1.x, (float)acc1.y };
    float inv = 1.f / l;
    float4 g  = ((const float4*)gamma)[lane];
    float4 be = ((const float4*)beta)[lane];
    float4 mu = ((const float4*)mean)[lane];
    float4 va = ((const float4*)var)[lane];
    float4 bi = ((const float4*)bias)[lane];
    float4 sc4, sh4;
    sc4.x = g.x * rsqrtf(va.x + 1e-5f); sh4.x = (bi.x - mu.x) * sc4.x + be.x;
    sc4.y = g.y * rsqrtf(va.y + 1e-5f); sh4.y = (bi.y - mu.y) * sc4.y + be.y;
    sc4.z = g.z * rsqrtf(va.z + 1e-5f); sh4.z = (bi.z - mu.z) * sc4.z + be.z;
    sc4.w = g.w * rsqrtf(va.w + 1e-5f); sh4.w = (bi.w - mu.w) * sc4.w + be.w;
    float4 o;
    o.x = fmaxf(acc.x * inv * sc4.x + sh4.x, 0.f);
    o.y = fmaxf(acc.y * inv * sc4.y + sh4.y, 0.f);
    o.z = fmaxf(acc.z * inv * sc4.z + sh4.z, 0.f);
    o.w = fmaxf(acc.w * inv * sc4.w + sh4.w, 0.f);
    if (resid) {
        float4 rv = *(const float4*)(resid + (size_t)d * 256 + lane * 4);
        o.x += rv.x; o.y += rv.y; o.z += rv.z; o.w += rv.w;
    }
    if (out) *(float4*)(out + (size_t)d * 256 + lane * 4) = o;
    if (outb) {
        half4v ob = { (h16)o.x, (h16)o.y, (h16)o.z, (h16)o.w };
        *(half4v*)(outb + (size_t)d * 256 + lane * 4) = ob;
    }
}

// ---- layer 2 projections from f16 input: 16 lanes/node, K=256 ----
__global__ void gemm2_wave(const h16* __restrict__ X, const float* __restrict__ Wl,
                           const float* __restrict__ Wr, float* __restrict__ xl2,
                           float* __restrict__ xr2, int N) {
    int t = blockIdx.x * blockDim.x + threadIdx.x;
    int n = t >> 4;
    int sl = t & 15;
    if (n >= N) return;
    const half4v* Xr = (const half4v*)(X + (size_t)n * 256);
    const float4* Wl4 = (const float4*)Wl;
    const float4* Wr4 = (const float4*)Wr;
    float l0 = 0.f, l1 = 0.f, r0 = 0.f, r1 = 0.f;
#pragma unroll
    for (int j = 0; j < 4; ++j) {
        int idx = sl + j * 16;
        half4v xh = Xr[idx];
        float4 xv = { (float)xh.x, (float)xh.y, (float)xh.z, (float)xh.w };
        float4 wa = Wl4[idx * 2];
        float4 wb = Wl4[idx * 2 + 1];
        l0 += xv.x * wa.x + xv.y * wa.z + xv.z * wb.x + xv.w * wb.z;
        l1 += xv.x * wa.y + xv.y * wa.w + xv.z * wb.y + xv.w * wb.w;
        wa = Wr4[idx * 2]; wb = Wr4[idx * 2 + 1];
        r0 += xv.x * wa.x + xv.y * wa.z + xv.z * wb.x + xv.w * wb.z;
        r1 += xv.x * wa.y + xv.y * wa.w + xv.z * wb.y + xv.w * wb.w;
    }
#pragma unroll
    for (int off = 1; off < 16; off <<= 1) {
        l0 += __shfl_xor(l0, off, 64);
        l1 += __shfl_xor(l1, off, 64);
        r0 += __shfl_xor(r0, off, 64);
        r1 += __shfl_xor(r1, off, 64);
    }
    if (sl == 0) {
        xl2[n * 2] = l0; xl2[n * 2 + 1] = l1;
        xr2[n * 2] = r0; xr2[n * 2 + 1] = r1;
    }
}

// ---- fused layer-2 attention (1 head, C=2) + log_softmax, 16 lanes/dst ----
__global__ void attn1_16(int N, const float* __restrict__ xl2, const float* __restrict__ xr2,
                         const float* __restrict__ att, const float* __restrict__ bias,
                         const int* __restrict__ rowstart, const int* __restrict__ deg,
                         const int* __restrict__ csr_src, float* __restrict__ out) {
    int t = blockIdx.x * blockDim.x + threadIdx.x;
    int d = t >> 4, sl = t & 15;
    if (d >= N) return;
    float a0 = att[0], a1 = att[1];
    float2 xr = ((const float2*)xr2)[d];
    float b0 = xr.x, b1 = xr.y;
    float l = 0.f, ac0 = 0.f, ac1 = 0.f;
    int st = rowstart[d], n = deg[d];
    if (sl == 0) {
        float2 s = ((const float2*)xl2)[d];
        float p = lrelu(s.x + b0) * a0 + lrelu(s.y + b1) * a1;
        float e = __expf(p);
        l = e; ac0 = e * s.x; ac1 = e * s.y;
    }
    for (int i = sl; i < n; i += 16) {
        int s = csr_src[st + i];
        float2 xv = ((const float2*)xl2)[s];
        float q = lrelu(xv.x + b0) * a0 + lrelu(xv.y + b1) * a1;
        float e = __expf(q);
        l += e; ac0 += e * xv.x; ac1 += e * xv.y;
    }
#pragma unroll
    for (int off = 1; off < 16; off <<= 1) {
        l   += __shfl_xor(l, off, 64);
        ac0 += __shfl_xor(ac0, off, 64);
        ac1 += __shfl_xor(ac1, off, 64);
    }
    if (sl == 0) {
        float inv = 1.f / l;
        float v0 = ac0 * inv + bias[0];
        float v1 = ac1 * inv + bias[1];
        float mx = fmaxf(v0, v1);
        float lse = mx + logf(__expf(v0 - mx) + __expf(v1 - mx));
        out[d * 2] = v0 - lse;
        out[d * 2 + 1] = v1 - lse;
    }
}

extern "C" void kernel_launch(void* const* d_in, const int* in_sizes, int n_in,
                              void* d_out, int out_size, void* d_ws, size_t ws_size,
                              hipStream_t stream) {
    const float* x        = (const float*)d_in[0];
    const int*   ei       = (const int*)  d_in[1];
    const float* W_in     = (const float*)d_in[2];
    const float* b_in     = (const float*)d_in[3];
    const float* Wl0      = (const float*)d_in[4];
    const float* Wr0      = (const float*)d_in[5];
    const float* att0     = (const float*)d_in[6];
    const float* bias0    = (const float*)d_in[7];
    const float* Wl1      = (const float*)d_in[8];
    const float* Wr1      = (const float*)d_in[9];
    const float* att1     = (const float*)d_in[10];
    const float* bias1    = (const float*)d_in[11];
    const float* Wl2      = (const float*)d_in[12];
    const float* Wr2      = (const float*)d_in[13];
    const float* att2     = (const float*)d_in[14];
    const float* bias2    = (const float*)d_in[15];
    const float* bn_gamma = (const float*)d_in[16];
    const float* bn_beta  = (const float*)d_in[17];
    const float* bn_mean  = (const float*)d_in[18];
    const float* bn_var   = (const float*)d_in[19];

    const int N  = in_sizes[0] / 128;
    const int E  = in_sizes[1] / 2;
    const int NB = (N + 255) / 256;

    float* ws = (float*)d_ws;
    size_t off = 0;
    float* C    = ws + off; off += (size_t)N * 256;     // layer0 out / residual (f32)
    float* XL2  = ws + off; off += (size_t)N * 2;
    float* XR2  = ws + off; off += (size_t)N * 2;
    h16* Ah   = (h16*)(ws + off); off += (size_t)N * 128;  // f16 xl [N,256]
    h16* Bh   = (h16*)(ws + off); off += (size_t)N * 128;  // f16 xr [N,256]
    h16* Ch   = (h16*)(ws + off); off += (size_t)N * 128;  // f16 copy of C
    h16* Dh   = (h16*)(ws + off); off += (size_t)N * 128;  // f16 layer1 out
    h16* H0h  = (h16*)(ws + off); off += (size_t)N * 32;   // f16 h0 [N,64]
    h16* xh   = (h16*)(ws + off); off += (size_t)N * 64;   // f16 x  [N,128]
    h16* Wp_in = (h16*)(ws + off); off += 4096;    // 128*64
    h16* Wp_l0 = (h16*)(ws + off); off += 8192;    // 64*256
    h16* Wp_r0 = (h16*)(ws + off); off += 8192;
    h16* Wp_l1 = (h16*)(ws + off); off += 32768;   // 256*256
    h16* Wp_r1 = (h16*)(ws + off); off += 32768;
    int* ip = (int*)(ws + off);
    int* deg      = ip;              ip += N;
    int* rowstart = ip;              ip += N;
    int* cursor   = ip;              ip += N;
    int* bsum     = ip;              ip += NB;
    int* csr_src  = ip;              ip += E;

    // ---- weight packing + x conversion + deg zeroing (one launch) ----
    const int PACK_T = 172032 + N * 32 + N;
    pack_all<<<(PACK_T + 255) / 256, 256, 0, stream>>>(
        W_in, Wl0, Wr0, Wl1, Wr1, Wp_in, Wp_l0, Wp_r0, Wp_l1, Wp_r1,
        (const float4*)x, (half4v*)xh, N * 32, deg, N);

    // ---- CSR build (parallel scan) ----
    hist_dst<<<(E + 255) / 256, 256, 0, stream>>>(ei, E, deg);
    scan_blk<<<NB, 256, 0, stream>>>(deg, rowstart, bsum, N);
    scan_off<<<1, 256, 0, stream>>>(bsum, NB);
    add_off<<<NB, 256, 0, stream>>>(bsum, rowstart, cursor, N);
    scatter_src<<<(E + 255) / 256, 256, 0, stream>>>(ei, E, cursor, csr_src);

    const int GBM = (N + 63) / 64;

    // h0 = relu(x @ W_in + b_in)  -> f16
    gemm_lds<4, 4, true, false><<<GBM, 256, 0, stream>>>(
        xh, Wp_in, nullptr, b_in, H0h, nullptr, N);

    // -------- layer 0 --------
    gemm_lds<2, 16, false, true><<<dim3(GBM, 2), 256, 0, stream>>>(
        H0h, Wp_l0, Wp_r0, nullptr, Ah, Bh, N);
    attn4_bn<<<(N + 3) / 4, 256, 0, stream>>>(N, Ah, Bh, att0, rowstart, deg, csr_src,
                                              bn_gamma, bn_beta, bn_mean, bn_var,
                                              bias0, nullptr, C, Ch);

    // -------- layer 1 (residual) --------
    gemm_lds<8, 16, false, true><<<dim3(GBM, 2), 256, 0, stream>>>(
        Ch, Wp_l1, Wp_r1, nullptr, Ah, Bh, N);
    attn4_bn<<<(N + 3) / 4, 256, 0, stream>>>(N, Ah, Bh, att1, rowstart, deg, csr_src,
                                              bn_gamma + 256, bn_beta + 256, bn_mean + 256,
                                              bn_var + 256, bias1, C, nullptr, Dh);

    // -------- layer 2 (1 head, C=2) + log_softmax --------
    gemm2_wave<<<(N * 16 + 255) / 256, 256, 0, stream>>>(Dh, Wl2, Wr2, XL2, XR2, N);
    attn1_16<<<(N * 16 + 255) / 256, 256, 0, stream>>>(N, XL2, XR2, att2, bias2,
                                                       rowstart, deg, csr_src, (float*)d_out);
}